// Round 1
// baseline (1313.986 us; speedup 1.0000x reference)
//
#include <hip/hip_runtime.h>
#include <math.h>

#define N_NODES 24576
#define NPV 8192
#define E_EDGES 393216
#define R_REL 6
#define B_BASES 8
#define HO_DIM 128
#define HEADS 4
#define NEG_SLOPE 0.2f

__device__ __forceinline__ float lrelu(float x) { return x >= 0.f ? x : NEG_SLOPE * x; }

// float atomic max via int/uint ordering trick; canonicalize -0.0 -> +0.0
__device__ __forceinline__ void atomicMaxF(float* addr, float v) {
  v += 0.0f;
  if (v >= 0.f) atomicMax((int*)addr, __float_as_int(v));
  else          atomicMin((unsigned int*)addr, __float_as_uint(v));
}

// ---------------------------------------------------------------------------
// Generic f32 GEMM: C[M,128] = act(A[M,K] @ W[128,K]^T + bias)
// block = 256 threads, tile BM=64 x 128, BK=16; thread computes 4x8.
// blockIdx.z batches over W/C (strideW/strideC in elements).
// ---------------------------------------------------------------------------
#define BM 64
#define BK 16
template <bool RELU, bool BIAS>
__global__ __launch_bounds__(256) void gemm_nt_128(
    const float* __restrict__ A, const float* __restrict__ W,
    const float* __restrict__ bias, float* __restrict__ C,
    int M, int K, long strideW, long strideC) {
  const float* Wz = W + (long)blockIdx.z * strideW;
  float* Cz = C + (long)blockIdx.z * strideC;
  __shared__ __align__(16) float As[BK][BM];
  __shared__ __align__(16) float Bs[BK][128];
  const int tid = threadIdx.x;
  const int ty = tid >> 4;          // 0..15 -> rows ty*4..ty*4+3
  const int col0 = (tid & 15) * 8;  // 0..120
  float acc[4][8];
#pragma unroll
  for (int i = 0; i < 4; ++i)
#pragma unroll
    for (int j = 0; j < 8; ++j) acc[i][j] = 0.f;

  for (int k0 = 0; k0 < K; k0 += BK) {
    // stage A tile: 64 rows x 16 k
    {
      int r = tid >> 2, kk = (tid & 3) * 4;
      int gk = k0 + kk;
      const float* ap = A + (long)(blockIdx.x * BM + r) * K + gk;
      float4 v = make_float4(0.f, 0.f, 0.f, 0.f);
      if (gk + 3 < K) {
        v = *reinterpret_cast<const float4*>(ap);
      } else {
        float t[4] = {0.f, 0.f, 0.f, 0.f};
        for (int j = 0; j < 4; ++j) if (gk + j < K) t[j] = ap[j];
        v = make_float4(t[0], t[1], t[2], t[3]);
      }
      As[kk + 0][r] = v.x; As[kk + 1][r] = v.y;
      As[kk + 2][r] = v.z; As[kk + 3][r] = v.w;
    }
    // stage W tile: 128 cols x 16 k
    {
      int c = tid >> 1, kk = (tid & 1) * 8;
      int gk = k0 + kk;
      const float* wp = Wz + (long)c * K + gk;
      float4 v0 = make_float4(0.f, 0.f, 0.f, 0.f), v1 = v0;
      if (gk + 7 < K) {
        v0 = *reinterpret_cast<const float4*>(wp);
        v1 = *reinterpret_cast<const float4*>(wp + 4);
      } else {
        float t[8] = {0.f, 0.f, 0.f, 0.f, 0.f, 0.f, 0.f, 0.f};
        for (int j = 0; j < 8; ++j) if (gk + j < K) t[j] = wp[j];
        v0 = make_float4(t[0], t[1], t[2], t[3]);
        v1 = make_float4(t[4], t[5], t[6], t[7]);
      }
      Bs[kk + 0][c] = v0.x; Bs[kk + 1][c] = v0.y;
      Bs[kk + 2][c] = v0.z; Bs[kk + 3][c] = v0.w;
      Bs[kk + 4][c] = v1.x; Bs[kk + 5][c] = v1.y;
      Bs[kk + 6][c] = v1.z; Bs[kk + 7][c] = v1.w;
    }
    __syncthreads();
#pragma unroll
    for (int kk = 0; kk < BK; ++kk) {
      float4 a4 = *reinterpret_cast<const float4*>(&As[kk][ty * 4]);
      float4 b0 = *reinterpret_cast<const float4*>(&Bs[kk][col0]);
      float4 b1 = *reinterpret_cast<const float4*>(&Bs[kk][col0 + 4]);
      float a[4] = {a4.x, a4.y, a4.z, a4.w};
      float b[8] = {b0.x, b0.y, b0.z, b0.w, b1.x, b1.y, b1.z, b1.w};
#pragma unroll
      for (int i = 0; i < 4; ++i)
#pragma unroll
        for (int j = 0; j < 8; ++j) acc[i][j] += a[i] * b[j];
    }
    __syncthreads();
  }
  const int rbase = blockIdx.x * BM + ty * 4;
#pragma unroll
  for (int i = 0; i < 4; ++i) {
    long off = (long)(rbase + i) * 128 + col0;
#pragma unroll
    for (int j = 0; j < 8; ++j) {
      float v = acc[i][j];
      if (BIAS) v += bias[col0 + j];
      if (RELU) v = v > 0.f ? v : 0.f;
      Cz[off + j] = v;
    }
  }
}

// wT[r,o,i] = sum_b comp[r,b] * basis[b,i,o]
__global__ void compute_wT(const float* __restrict__ comp,
                           const float* __restrict__ basis,
                           float* __restrict__ wT) {
  int idx = blockIdx.x * blockDim.x + threadIdx.x;
  if (idx >= R_REL * 128 * 128) return;
  int r = idx >> 14;
  int rem = idx & 16383;
  int o = rem >> 7;
  int i = rem & 127;
  float s = 0.f;
#pragma unroll
  for (int b = 0; b < B_BASES; ++b)
    s += comp[r * B_BASES + b] * basis[((b << 7) + i) * 128 + o];
  wT[((long)(r << 7) + o) * 128 + i] = s;
}

// ai[row,h] = xw[row,:] @ q[:,h];  aj[row,h] = xw[row,:] @ k[:,h]
__global__ void att_tables(const float* __restrict__ xw,
                           const float* __restrict__ q,
                           const float* __restrict__ k,
                           float* __restrict__ ai, float* __restrict__ aj,
                           int RN) {
  __shared__ float qs[128 * HEADS], ks[128 * HEADS];
  for (int t = threadIdx.x; t < 128 * HEADS; t += blockDim.x) {
    qs[t] = q[t];
    ks[t] = k[t];
  }
  __syncthreads();
  int row = blockIdx.x * blockDim.x + threadIdx.x;
  if (row >= RN) return;
  const float* xr = xw + (long)row * 128;
  float accq[4] = {0.f, 0.f, 0.f, 0.f}, acck[4] = {0.f, 0.f, 0.f, 0.f};
  for (int c = 0; c < 128; c += 4) {
    float4 xv = *reinterpret_cast<const float4*>(xr + c);
    float xs[4] = {xv.x, xv.y, xv.z, xv.w};
#pragma unroll
    for (int j = 0; j < 4; ++j)
#pragma unroll
      for (int h = 0; h < 4; ++h) {
        accq[h] += xs[j] * qs[(c + j) * 4 + h];
        acck[h] += xs[j] * ks[(c + j) * 4 + h];
      }
  }
  long base = (long)row * 4;
#pragma unroll
  for (int h = 0; h < 4; ++h) {
    ai[base + h] = accq[h];
    aj[base + h] = acck[h];
  }
}

__global__ void fill_f32(float* __restrict__ p, long n, float v) {
  long i = blockIdx.x * (long)blockDim.x + threadIdx.x;
  long stride = (long)gridDim.x * blockDim.x;
  for (; i < n; i += stride) p[i] = v;
}

__global__ void deg_kernel(const int* __restrict__ dst, float* __restrict__ deg,
                           int E) {
  int e = blockIdx.x * blockDim.x + threadIdx.x;
  if (e < E) atomicAdd(&deg[dst[e]], 1.0f);
}

__global__ void edge_alpha(const int* __restrict__ src, const int* __restrict__ dst,
                           const int* __restrict__ et,
                           const float* __restrict__ ai, const float* __restrict__ aj,
                           float* __restrict__ alpha, float* __restrict__ amax, int E) {
  int e = blockIdx.x * blockDim.x + threadIdx.x;
  if (e >= E) return;
  int s = src[e], d = dst[e], r = et[e];
  long si = ((long)r * N_NODES + d) * 4;
  long sj = ((long)r * N_NODES + s) * 4;
  float4 av = *reinterpret_cast<const float4*>(ai + si);
  float4 bv = *reinterpret_cast<const float4*>(aj + sj);
  float4 al;
  al.x = lrelu(av.x + bv.x);
  al.y = lrelu(av.y + bv.y);
  al.z = lrelu(av.z + bv.z);
  al.w = lrelu(av.w + bv.w);
  *reinterpret_cast<float4*>(alpha + (long)e * 4) = al;
  atomicMaxF(&amax[si + 0], al.x);
  atomicMaxF(&amax[si + 1], al.y);
  atomicMaxF(&amax[si + 2], al.z);
  atomicMaxF(&amax[si + 3], al.w);
}

__global__ void edge_exp(const int* __restrict__ dst, const int* __restrict__ et,
                         const float* __restrict__ amax, float* __restrict__ alpha,
                         float* __restrict__ den, int E) {
  int e = blockIdx.x * blockDim.x + threadIdx.x;
  if (e >= E) return;
  int d = dst[e], r = et[e];
  long si = ((long)r * N_NODES + d) * 4;
  float4 al = *reinterpret_cast<const float4*>(alpha + (long)e * 4);
  float4 m = *reinterpret_cast<const float4*>(amax + si);
  float4 ex;
  ex.x = expf(al.x - m.x);
  ex.y = expf(al.y - m.y);
  ex.z = expf(al.z - m.z);
  ex.w = expf(al.w - m.w);
  *reinterpret_cast<float4*>(alpha + (long)e * 4) = ex;
  atomicAdd(den + si + 0, ex.x);
  atomicAdd(den + si + 1, ex.y);
  atomicAdd(den + si + 2, ex.z);
  atomicAdd(den + si + 3, ex.w);
}

// one thread per (edge, channel): out[dst,c] += a[e, c/32] * xw[r, src, c]
__global__ void aggregate(const int* __restrict__ src, const int* __restrict__ dst,
                          const int* __restrict__ et,
                          const float* __restrict__ alpha, const float* __restrict__ den,
                          const float* __restrict__ deg, const float* __restrict__ xw,
                          float* __restrict__ out) {
  long gt = (long)blockIdx.x * blockDim.x + threadIdx.x;
  int e = (int)(gt >> 7);
  int c = (int)(gt & 127);
  if (e >= E_EDGES) return;
  int s = src[e], d = dst[e], r = et[e];
  int h = c >> 5;
  long si = ((long)r * N_NODES + d) * 4 + h;
  float a = alpha[(long)e * 4 + h] / (den[si] + 1e-16f) * deg[d];
  float v = a * xw[(((long)r * N_NODES + s) << 7) + c];
  atomicAdd(&out[((long)d << 7) + c], v);
}

// out[i,l] = bc[l] + sum_{v,c} x[v*8192+i, c] * Wc[l, v*128+c]
__global__ void final_linear(const float* __restrict__ x, const float* __restrict__ Wc,
                             const float* __restrict__ bc, float* __restrict__ out) {
  __shared__ float wcs[4 * 384];
  for (int t = threadIdx.x; t < 4 * 384; t += blockDim.x) wcs[t] = Wc[t];
  __syncthreads();
  int i = blockIdx.x * blockDim.x + threadIdx.x;
  if (i >= NPV) return;
  float acc[4] = {0.f, 0.f, 0.f, 0.f};
  for (int v = 0; v < 3; ++v) {
    const float* xr = x + ((long)v * NPV + i) * 128;
    for (int c = 0; c < 128; c += 4) {
      float4 xv = *reinterpret_cast<const float4*>(xr + c);
#pragma unroll
      for (int l = 0; l < 4; ++l) {
        const float* w = wcs + l * 384 + v * 128 + c;
        acc[l] += xv.x * w[0] + xv.y * w[1] + xv.z * w[2] + xv.w * w[3];
      }
    }
  }
#pragma unroll
  for (int l = 0; l < 4; ++l) out[(long)i * 4 + l] = acc[l] + bc[l];
}

// ---------------------------------------------------------------------------

static void run_layer(const float* xin, float* xout, const float* basis,
                      const float* comp, const float* q, const float* k,
                      float* xw, float* wT, float* ai, float* aj, float* amax,
                      float* den, const float* deg, float* alpha,
                      const int* src, const int* dst, const int* et,
                      hipStream_t stream) {
  const long RN = (long)R_REL * N_NODES;
  compute_wT<<<(R_REL * 128 * 128 + 255) / 256, 256, 0, stream>>>(comp, basis, wT);
  gemm_nt_128<false, false><<<dim3(N_NODES / BM, 1, R_REL), 256, 0, stream>>>(
      xin, wT, nullptr, xw, N_NODES, 128, 128 * 128, (long)N_NODES * 128);
  att_tables<<<(int)((RN + 255) / 256), 256, 0, stream>>>(xw, q, k, ai, aj, (int)RN);
  fill_f32<<<1024, 256, 0, stream>>>(amax, RN * 4, -INFINITY);
  fill_f32<<<1024, 256, 0, stream>>>(den, RN * 4, 0.f);
  fill_f32<<<2048, 256, 0, stream>>>(xout, (long)N_NODES * 128, 0.f);
  edge_alpha<<<(E_EDGES + 255) / 256, 256, 0, stream>>>(src, dst, et, ai, aj, alpha, amax, E_EDGES);
  edge_exp<<<(E_EDGES + 255) / 256, 256, 0, stream>>>(dst, et, amax, alpha, den, E_EDGES);
  long aggt = (long)E_EDGES * 128;
  aggregate<<<(int)(aggt / 256), 256, 0, stream>>>(src, dst, et, alpha, den, deg, xw, xout);
}

extern "C" void kernel_launch(void* const* d_in, const int* in_sizes, int n_in,
                              void* d_out, int out_size, void* d_ws, size_t ws_size,
                              hipStream_t stream) {
  const float* x0 = (const float*)d_in[0];
  const float* x1 = (const float*)d_in[1];
  const float* x2 = (const float*)d_in[2];
  const int* edge_index = (const int*)d_in[3];
  const int* edge_type = (const int*)d_in[4];
  const float* Wp0 = (const float*)d_in[5];
  const float* bp0 = (const float*)d_in[6];
  const float* Wp1 = (const float*)d_in[7];
  const float* bp1 = (const float*)d_in[8];
  const float* Wp2 = (const float*)d_in[9];
  const float* bp2 = (const float*)d_in[10];
  const float* basis0 = (const float*)d_in[11];
  const float* comp0 = (const float*)d_in[12];
  const float* q0 = (const float*)d_in[13];
  const float* k0 = (const float*)d_in[14];
  const float* basis1 = (const float*)d_in[15];
  const float* comp1 = (const float*)d_in[16];
  const float* q1 = (const float*)d_in[17];
  const float* k1 = (const float*)d_in[18];
  const float* Wc = (const float*)d_in[19];
  const float* bc = (const float*)d_in[20];

  const int* src = edge_index;
  const int* dst = edge_index + E_EDGES;

  float* bufA = (float*)d_ws;                            // N*128
  float* bufB = bufA + (long)N_NODES * 128;              // N*128
  float* xw   = bufB + (long)N_NODES * 128;              // R*N*128
  float* wT   = xw + (long)R_REL * N_NODES * 128;        // R*128*128
  float* ai   = wT + (long)R_REL * 128 * 128;            // R*N*4
  float* aj   = ai + (long)R_REL * N_NODES * 4;
  float* amax = aj + (long)R_REL * N_NODES * 4;
  float* den  = amax + (long)R_REL * N_NODES * 4;
  float* deg  = den + (long)R_REL * N_NODES * 4;         // N
  float* alpha = deg + N_NODES;                          // E*4

  // projections -> bufA[view*8192 .. ]
  gemm_nt_128<true, true><<<dim3(NPV / BM, 1, 1), 256, 0, stream>>>(
      x0, Wp0, bp0, bufA + 0L * NPV * 128, NPV, 2000, 0, 0);
  gemm_nt_128<true, true><<<dim3(NPV / BM, 1, 1), 256, 0, stream>>>(
      x1, Wp1, bp1, bufA + 1L * NPV * 128, NPV, 1500, 0, 0);
  gemm_nt_128<true, true><<<dim3(NPV / BM, 1, 1), 256, 0, stream>>>(
      x2, Wp2, bp2, bufA + 2L * NPV * 128, NPV, 500, 0, 0);

  // degree (shared by both layers)
  fill_f32<<<96, 256, 0, stream>>>(deg, N_NODES, 0.f);
  deg_kernel<<<(E_EDGES + 255) / 256, 256, 0, stream>>>(dst, deg, E_EDGES);

  // layer 0: bufA -> bufB
  run_layer(bufA, bufB, basis0, comp0, q0, k0, xw, wT, ai, aj, amax, den, deg,
            alpha, src, dst, edge_type, stream);
  // layer 1: bufB -> bufA
  run_layer(bufB, bufA, basis1, comp1, q1, k1, xw, wT, ai, aj, amax, den, deg,
            alpha, src, dst, edge_type, stream);

  final_linear<<<(NPV + 255) / 256, 256, 0, stream>>>(bufA, Wc, bc, (float*)d_out);
}

// Round 2
// 932.254 us; speedup vs baseline: 1.4095x; 1.4095x over previous
//
#include <hip/hip_runtime.h>
#include <hip/hip_bf16.h>
#include <math.h>

#define N_NODES 24576
#define NPV 8192
#define E_EDGES 393216
#define R_REL 6
#define B_BASES 8
#define HEADS 4
#define NEG_SLOPE 0.2f

typedef unsigned short ushort_t;
using short8 = __attribute__((ext_vector_type(8))) short;
using f32x4 = __attribute__((ext_vector_type(4))) float;

#define RN4 (R_REL * N_NODES * 4)          // 589824
#define NX  (N_NODES * 128)                // 3145728

__device__ __forceinline__ float lrelu(float x) { return x >= 0.f ? x : NEG_SLOPE * x; }
__device__ __forceinline__ float b2f(ushort_t u) {
  unsigned int v = ((unsigned int)u) << 16;
  float f;
  __builtin_memcpy(&f, &v, 4);
  return f;
}
__device__ __forceinline__ ushort_t f2b(float f) {
  __hip_bfloat16 h = __float2bfloat16(f);
  ushort_t u;
  __builtin_memcpy(&u, &h, 2);
  return u;
}

__device__ __forceinline__ void atomicMaxF(float* addr, float v) {
  v += 0.0f;
  if (v >= 0.f) atomicMax((int*)addr, __float_as_int(v));
  else          atomicMin((unsigned int*)addr, __float_as_uint(v));
}

// ---------------------------------------------------------------------------
// cvt_pad: f32 [M,K] -> bf16 [M,Kp], zero-padded. K % 4 == 0 assumed.
// ---------------------------------------------------------------------------
__global__ void cvt_pad_bf16(const float* __restrict__ in, ushort_t* __restrict__ out,
                             int M, int K, int Kp) {
  int kp8 = Kp >> 3;
  int total = M * kp8;
  for (int t = blockIdx.x * blockDim.x + threadIdx.x; t < total;
       t += gridDim.x * blockDim.x) {
    int row = t / kp8;
    int c0 = (t - row * kp8) * 8;
    short8 o;
    if (c0 + 7 < K) {
      const float4 a = *reinterpret_cast<const float4*>(in + (long)row * K + c0);
      const float4 b = *reinterpret_cast<const float4*>(in + (long)row * K + c0 + 4);
      o[0] = (short)f2b(a.x); o[1] = (short)f2b(a.y);
      o[2] = (short)f2b(a.z); o[3] = (short)f2b(a.w);
      o[4] = (short)f2b(b.x); o[5] = (short)f2b(b.y);
      o[6] = (short)f2b(b.z); o[7] = (short)f2b(b.w);
    } else {
#pragma unroll
      for (int j = 0; j < 8; ++j) {
        int c = c0 + j;
        float v = (c < K) ? in[(long)row * K + c] : 0.f;
        o[j] = (short)f2b(v);
      }
    }
    *reinterpret_cast<short8*>(out + (long)row * Kp + c0) = o;
  }
}

// ---------------------------------------------------------------------------
// MFMA GEMM: C[M,128] = A[M,Kp]bf16 @ W[128,Kp]bf16^T
// block 256 = 4 waves; tile BM=64 x BN=128, BK=64.
// grid: (M/64, splits, batch). SPLIT: atomic f32 accumulate; else bf16 store.
// LDS layout XOR-swizzled via pre-swizzled global source (linear LDS dest).
// ---------------------------------------------------------------------------
template <bool SPLIT>
__global__ __launch_bounds__(256) void mfma_gemm_nt(
    const ushort_t* __restrict__ A, const ushort_t* __restrict__ W,
    float* __restrict__ Cacc, ushort_t* __restrict__ Cb,
    int Kp, int kChunk, long strideW, long strideCz) {
  __shared__ __align__(16) ushort_t As[64 * 64];
  __shared__ __align__(16) ushort_t Ws[128 * 64];
  const int tid = threadIdx.x;
  const int wave = tid >> 6, lane = tid & 63;
  const int m0 = blockIdx.x * 64;
  const int kbase = blockIdx.y * kChunk;
  const ushort_t* Wz = W + (long)blockIdx.z * strideW;

  f32x4 acc[8];
#pragma unroll
  for (int n = 0; n < 8; ++n) acc[n] = (f32x4){0.f, 0.f, 0.f, 0.f};

  for (int k0 = kbase; k0 < kbase + kChunk; k0 += 64) {
    __syncthreads();  // previous iter's LDS reads complete
#pragma unroll
    for (int q = 0; q < 2; ++q) {
      int s = q * 256 + tid;
      int row = s >> 3, ch = s & 7;
      int sch = ch ^ (row & 7);
      const ushort_t* g = A + (long)(m0 + row) * Kp + k0 + sch * 8;
      __builtin_amdgcn_global_load_lds(
          (const __attribute__((address_space(1))) unsigned int*)g,
          (__attribute__((address_space(3))) unsigned int*)(As + s * 8), 16, 0, 0);
    }
#pragma unroll
    for (int q = 0; q < 4; ++q) {
      int s = q * 256 + tid;
      int row = s >> 3, ch = s & 7;
      int sch = ch ^ (row & 7);
      const ushort_t* g = Wz + (long)row * Kp + k0 + sch * 8;
      __builtin_amdgcn_global_load_lds(
          (const __attribute__((address_space(1))) unsigned int*)g,
          (__attribute__((address_space(3))) unsigned int*)(Ws + s * 8), 16, 0, 0);
    }
    __syncthreads();  // compiler drains vmcnt before barrier
#pragma unroll
    for (int kk = 0; kk < 2; ++kk) {
      const int arow = wave * 16 + (lane & 15);
      const int ach = (kk * 4 + (lane >> 4)) ^ (arow & 7);
      short8 afrag = *reinterpret_cast<const short8*>(As + arow * 64 + ach * 8);
#pragma unroll
      for (int n = 0; n < 8; ++n) {
        const int brow = n * 16 + (lane & 15);
        const int bch = (kk * 4 + (lane >> 4)) ^ (brow & 7);
        short8 bfrag = *reinterpret_cast<const short8*>(Ws + brow * 64 + bch * 8);
        acc[n] = __builtin_amdgcn_mfma_f32_16x16x32_bf16(afrag, bfrag, acc[n], 0, 0, 0);
      }
    }
  }
  const int rbase = m0 + wave * 16 + (lane >> 4) * 4;
  const int cb = lane & 15;
  if (SPLIT) {
#pragma unroll
    for (int n = 0; n < 8; ++n) {
      int col = n * 16 + cb;
#pragma unroll
      for (int r = 0; r < 4; ++r)
        atomicAdd(&Cacc[(long)(rbase + r) * 128 + col], acc[n][r]);
    }
  } else {
    ushort_t* Cz = Cb + (long)blockIdx.z * strideCz;
#pragma unroll
    for (int n = 0; n < 8; ++n) {
      int col = n * 16 + cb;
#pragma unroll
      for (int r = 0; r < 4; ++r)
        Cz[(long)(rbase + r) * 128 + col] = f2b(acc[n][r]);
    }
  }
}

// ---------------------------------------------------------------------------
__global__ void fill_f32(float* __restrict__ p, long n, float v) {
  long i = blockIdx.x * (long)blockDim.x + threadIdx.x;
  long stride = (long)gridDim.x * blockDim.x;
  for (; i < n; i += stride) p[i] = v;
}

// amax=-inf, den=0, out=0 in one launch
__global__ void fill_layer(float* __restrict__ amax, float* __restrict__ den,
                           float* __restrict__ out) {
  long i0 = blockIdx.x * (long)blockDim.x + threadIdx.x;
  long stride = (long)gridDim.x * blockDim.x;
  for (long i = i0; i < RN4; i += stride) { amax[i] = -INFINITY; den[i] = 0.f; }
  for (long i = i0; i < (long)NX; i += stride) out[i] = 0.f;
}

// x_bf16 = bf16(relu(Cacc + bias_view))
__global__ void bias_relu_cvt(const float* __restrict__ C, const float* __restrict__ b0,
                              const float* __restrict__ b1, const float* __restrict__ b2,
                              ushort_t* __restrict__ xb) {
  int t = blockIdx.x * blockDim.x + threadIdx.x;
  if (t >= N_NODES * 16) return;
  int row = t >> 4, c0 = (t & 15) * 8;
  const float* bp = row < NPV ? b0 : (row < 2 * NPV ? b1 : b2);
  const float4 v0 = *reinterpret_cast<const float4*>(C + (long)row * 128 + c0);
  const float4 v1 = *reinterpret_cast<const float4*>(C + (long)row * 128 + c0 + 4);
  float x[8] = {v0.x, v0.y, v0.z, v0.w, v1.x, v1.y, v1.z, v1.w};
  short8 o;
#pragma unroll
  for (int j = 0; j < 8; ++j) {
    float v = x[j] + bp[c0 + j];
    v = v > 0.f ? v : 0.f;
    o[j] = (short)f2b(v);
  }
  *reinterpret_cast<short8*>(xb + (long)row * 128 + c0) = o;
}

// wTb[r,o,i] = bf16( sum_b comp[r,b] * basis[b,i,o] )
__global__ void compute_wT_b(const float* __restrict__ comp,
                             const float* __restrict__ basis,
                             ushort_t* __restrict__ wTb) {
  int idx = blockIdx.x * blockDim.x + threadIdx.x;
  if (idx >= R_REL * 128 * 128) return;
  int r = idx >> 14;
  int rem = idx & 16383;
  int o = rem >> 7;
  int i = rem & 127;
  float s = 0.f;
#pragma unroll
  for (int b = 0; b < B_BASES; ++b)
    s += comp[r * B_BASES + b] * basis[((b << 7) + i) * 128 + o];
  wTb[((long)(r << 7) + o) * 128 + i] = f2b(s);
}

// ai[row,h] = xw[row,:] @ q[:,h]; aj likewise with k. One quarter-wave per row.
__global__ __launch_bounds__(256) void att_tables_b(
    const ushort_t* __restrict__ xwb, const float* __restrict__ q,
    const float* __restrict__ k, float* __restrict__ ai, float* __restrict__ aj) {
  __shared__ float qs[512], ks[512];
  for (int t = threadIdx.x; t < 512; t += blockDim.x) { qs[t] = q[t]; ks[t] = k[t]; }
  __syncthreads();
  const int lane = threadIdx.x & 63;
  const int sub = lane & 15;
  int wave_global = blockIdx.x * 4 + (threadIdx.x >> 6);
  int row = wave_global * 4 + (lane >> 4);
  if (row >= R_REL * N_NODES) return;
  short8 xv = *reinterpret_cast<const short8*>(xwb + (long)row * 128 + sub * 8);
  float aq[4] = {0.f, 0.f, 0.f, 0.f}, ak[4] = {0.f, 0.f, 0.f, 0.f};
#pragma unroll
  for (int j = 0; j < 8; ++j) {
    float x = b2f((ushort_t)xv[j]);
    int c = sub * 8 + j;
#pragma unroll
    for (int h = 0; h < 4; ++h) {
      aq[h] += x * qs[c * 4 + h];
      ak[h] += x * ks[c * 4 + h];
    }
  }
#pragma unroll
  for (int m = 8; m >= 1; m >>= 1) {
#pragma unroll
    for (int h = 0; h < 4; ++h) {
      aq[h] += __shfl_xor(aq[h], m);
      ak[h] += __shfl_xor(ak[h], m);
    }
  }
  if (sub < 4) ai[(long)row * 4 + sub] = aq[sub];
  else if (sub < 8) aj[(long)row * 4 + sub - 4] = ak[sub - 4];
}

__global__ void deg_kernel(const int* __restrict__ dst, float* __restrict__ deg, int E) {
  int e = blockIdx.x * blockDim.x + threadIdx.x;
  if (e < E) atomicAdd(&deg[dst[e]], 1.0f);
}

__global__ void edge_alpha(const int* __restrict__ src, const int* __restrict__ dst,
                           const int* __restrict__ et,
                           const float* __restrict__ ai, const float* __restrict__ aj,
                           float* __restrict__ alpha, float* __restrict__ amax, int E) {
  int e = blockIdx.x * blockDim.x + threadIdx.x;
  if (e >= E) return;
  int s = src[e], d = dst[e], r = et[e];
  long si = ((long)r * N_NODES + d) * 4;
  long sj = ((long)r * N_NODES + s) * 4;
  float4 av = *reinterpret_cast<const float4*>(ai + si);
  float4 bv = *reinterpret_cast<const float4*>(aj + sj);
  float4 al;
  al.x = lrelu(av.x + bv.x);
  al.y = lrelu(av.y + bv.y);
  al.z = lrelu(av.z + bv.z);
  al.w = lrelu(av.w + bv.w);
  *reinterpret_cast<float4*>(alpha + (long)e * 4) = al;
  atomicMaxF(&amax[si + 0], al.x);
  atomicMaxF(&amax[si + 1], al.y);
  atomicMaxF(&amax[si + 2], al.z);
  atomicMaxF(&amax[si + 3], al.w);
}

__global__ void edge_exp(const int* __restrict__ dst, const int* __restrict__ et,
                         const float* __restrict__ amax, float* __restrict__ alpha,
                         float* __restrict__ den, int E) {
  int e = blockIdx.x * blockDim.x + threadIdx.x;
  if (e >= E) return;
  int d = dst[e], r = et[e];
  long si = ((long)r * N_NODES + d) * 4;
  float4 al = *reinterpret_cast<const float4*>(alpha + (long)e * 4);
  float4 m = *reinterpret_cast<const float4*>(amax + si);
  float4 ex;
  ex.x = expf(al.x - m.x);
  ex.y = expf(al.y - m.y);
  ex.z = expf(al.z - m.z);
  ex.w = expf(al.w - m.w);
  *reinterpret_cast<float4*>(alpha + (long)e * 4) = ex;
  atomicAdd(den + si + 0, ex.x);
  atomicAdd(den + si + 1, ex.y);
  atomicAdd(den + si + 2, ex.z);
  atomicAdd(den + si + 3, ex.w);
}

// one thread per (edge, channel)
__global__ void aggregate(const int* __restrict__ src, const int* __restrict__ dst,
                          const int* __restrict__ et,
                          const float* __restrict__ alpha, const float* __restrict__ den,
                          const float* __restrict__ deg, const ushort_t* __restrict__ xwb,
                          float* __restrict__ out) {
  long gt = (long)blockIdx.x * blockDim.x + threadIdx.x;
  int e = (int)(gt >> 7);
  int c = (int)(gt & 127);
  if (e >= E_EDGES) return;
  int s = src[e], d = dst[e], r = et[e];
  int h = c >> 5;
  long si = ((long)r * N_NODES + d) * 4 + h;
  float a = alpha[(long)e * 4 + h] / (den[si] + 1e-16f) * deg[d];
  float v = a * b2f(xwb[(((long)r * N_NODES + s) << 7) + c]);
  atomicAdd(&out[((long)d << 7) + c], v);
}

__global__ void final_linear(const float* __restrict__ x, const float* __restrict__ Wc,
                             const float* __restrict__ bc, float* __restrict__ out) {
  __shared__ float wcs[4 * 384];
  for (int t = threadIdx.x; t < 4 * 384; t += blockDim.x) wcs[t] = Wc[t];
  __syncthreads();
  int i = blockIdx.x * blockDim.x + threadIdx.x;
  if (i >= NPV) return;
  float acc[4] = {0.f, 0.f, 0.f, 0.f};
  for (int v = 0; v < 3; ++v) {
    const float* xr = x + ((long)v * NPV + i) * 128;
    for (int c = 0; c < 128; c += 4) {
      float4 xv = *reinterpret_cast<const float4*>(xr + c);
#pragma unroll
      for (int l = 0; l < 4; ++l) {
        const float* w = wcs + l * 384 + v * 128 + c;
        acc[l] += xv.x * w[0] + xv.y * w[1] + xv.z * w[2] + xv.w * w[3];
      }
    }
  }
#pragma unroll
  for (int l = 0; l < 4; ++l) out[(long)i * 4 + l] = acc[l] + bc[l];
}

// ---------------------------------------------------------------------------
static void run_layer(const ushort_t* xb, float* xout, const float* basis,
                      const float* comp, const float* q, const float* k,
                      ushort_t* xwb, ushort_t* wTb, float* ai, float* aj,
                      float* amax, float* den, const float* deg, float* alpha,
                      const int* src, const int* dst, const int* et,
                      hipStream_t stream) {
  compute_wT_b<<<(R_REL * 128 * 128 + 255) / 256, 256, 0, stream>>>(comp, basis, wTb);
  mfma_gemm_nt<false><<<dim3(N_NODES / 64, 1, R_REL), 256, 0, stream>>>(
      xb, wTb, nullptr, xwb, 128, 128, 128 * 128, (long)N_NODES * 128);
  att_tables_b<<<(R_REL * N_NODES) / 16, 256, 0, stream>>>(xwb, q, k, ai, aj);
  fill_layer<<<2048, 256, 0, stream>>>(amax, den, xout);
  edge_alpha<<<E_EDGES / 256, 256, 0, stream>>>(src, dst, et, ai, aj, alpha, amax, E_EDGES);
  edge_exp<<<E_EDGES / 256, 256, 0, stream>>>(dst, et, amax, alpha, den, E_EDGES);
  aggregate<<<(int)(((long)E_EDGES * 128) / 256), 256, 0, stream>>>(
      src, dst, et, alpha, den, deg, xwb, xout);
}

extern "C" void kernel_launch(void* const* d_in, const int* in_sizes, int n_in,
                              void* d_out, int out_size, void* d_ws, size_t ws_size,
                              hipStream_t stream) {
  const float* x0 = (const float*)d_in[0];
  const float* x1 = (const float*)d_in[1];
  const float* x2 = (const float*)d_in[2];
  const int* edge_index = (const int*)d_in[3];
  const int* edge_type = (const int*)d_in[4];
  const float* Wp0 = (const float*)d_in[5];
  const float* bp0 = (const float*)d_in[6];
  const float* Wp1 = (const float*)d_in[7];
  const float* bp1 = (const float*)d_in[8];
  const float* Wp2 = (const float*)d_in[9];
  const float* bp2 = (const float*)d_in[10];
  const float* basis0 = (const float*)d_in[11];
  const float* comp0 = (const float*)d_in[12];
  const float* q0 = (const float*)d_in[13];
  const float* k0 = (const float*)d_in[14];
  const float* basis1 = (const float*)d_in[15];
  const float* comp1 = (const float*)d_in[16];
  const float* q1 = (const float*)d_in[17];
  const float* k1 = (const float*)d_in[18];
  const float* Wc = (const float*)d_in[19];
  const float* bc = (const float*)d_in[20];

  const int* src = edge_index;
  const int* dst = edge_index + E_EDGES;

  // ---- workspace layout (bytes) ----
  char* w = (char*)d_ws;
  ushort_t* padX = (ushort_t*)w;                     w += (long)NPV * 2048 * 2;   // 33.5MB
  ushort_t* padW = (ushort_t*)w;                     w += 128L * 2048 * 2;        // 0.5MB
  ushort_t* xb   = (ushort_t*)w;                     w += (long)N_NODES * 128 * 2;
  ushort_t* xwb  = (ushort_t*)w;                     w += (long)R_REL * N_NODES * 128 * 2;
  ushort_t* wTb  = (ushort_t*)w;                     w += (long)R_REL * 128 * 128 * 2;
  float* Cacc    = (float*)w;                        w += (long)NX * 4;           // also layer-1 out
  float* outA    = (float*)w;                        w += (long)NX * 4;           // layer-0 out
  float* deg     = (float*)w;                        w += (long)N_NODES * 4;
  // edge-phase scratch aliases padX (only used after projections are done)
  float* ai    = (float*)padX;
  float* aj    = ai + (long)R_REL * N_NODES * 4;
  float* amax  = aj + (long)R_REL * N_NODES * 4;
  float* den   = amax + (long)R_REL * N_NODES * 4;
  float* alpha = den + (long)R_REL * N_NODES * 4;

  // ---- projections: Cacc = x @ Wp^T (split-K atomics), then bias+relu -> xb
  fill_f32<<<2048, 256, 0, stream>>>(Cacc, NX, 0.f);

  const float* xs[3] = {x0, x1, x2};
  const float* Ws_[3] = {Wp0, Wp1, Wp2};
  const int Ks[3] = {2000, 1500, 500};
  const int Kps[3] = {2048, 1536, 512};
  const int splits[3] = {4, 3, 2};
  for (int v = 0; v < 3; ++v) {
    int K = Ks[v], Kp = Kps[v];
    cvt_pad_bf16<<<2048, 256, 0, stream>>>(xs[v], padX, NPV, K, Kp);
    cvt_pad_bf16<<<128, 256, 0, stream>>>(Ws_[v], padW, 128, K, Kp);
    mfma_gemm_nt<true><<<dim3(NPV / 64, splits[v], 1), 256, 0, stream>>>(
        padX, padW, Cacc + (long)v * NPV * 128, nullptr, Kp, Kp / splits[v], 0, 0);
  }
  bias_relu_cvt<<<(N_NODES * 16 + 255) / 256, 256, 0, stream>>>(Cacc, bp0, bp1, bp2, xb);

  // ---- degree (shared by both layers)
  fill_f32<<<96, 256, 0, stream>>>(deg, N_NODES, 0.f);
  deg_kernel<<<E_EDGES / 256, 256, 0, stream>>>(dst, deg, E_EDGES);

  // ---- layer 0: xb -> outA
  run_layer(xb, outA, basis0, comp0, q0, k0, xwb, wTb, ai, aj, amax, den, deg,
            alpha, src, dst, edge_type, stream);
  // layer-1 input: cvt outA -> xb
  {
    int total = NX / 8;
    // reuse cvt_pad with K==Kp==128
    cvt_pad_bf16<<<2048, 256, 0, stream>>>(outA, xb, N_NODES, 128, 128);
  }
  // ---- layer 1: xb -> Cacc (reused as layer-1 out)
  run_layer(xb, Cacc, basis1, comp1, q1, k1, xwb, wTb, ai, aj, amax, den, deg,
            alpha, src, dst, edge_type, stream);

  final_linear<<<(NPV + 255) / 256, 256, 0, stream>>>(Cacc, Wc, bc, (float*)d_out);
}

// Round 3
// 508.064 us; speedup vs baseline: 2.5863x; 1.8349x over previous
//
#include <hip/hip_runtime.h>
#include <hip/hip_bf16.h>
#include <math.h>

#define N_NODES 24576
#define NPV 8192
#define E_EDGES 393216
#define R_REL 6
#define B_BASES 8
#define HEADS 4
#define NEG_SLOPE 0.2f
#define NX (N_NODES * 128)

typedef unsigned short ushort_t;
using short8 = __attribute__((ext_vector_type(8))) short;
using f32x4 = __attribute__((ext_vector_type(4))) float;

__device__ __forceinline__ float lrelu(float x) { return x >= 0.f ? x : NEG_SLOPE * x; }
__device__ __forceinline__ float b2f(ushort_t u) {
  unsigned int v = ((unsigned int)u) << 16;
  float f;
  __builtin_memcpy(&f, &v, 4);
  return f;
}
__device__ __forceinline__ ushort_t f2b(float f) {
  __hip_bfloat16 h = __float2bfloat16(f);
  ushort_t u;
  __builtin_memcpy(&u, &h, 2);
  return u;
}

// ---------------------------------------------------------------------------
// cvt_pad: f32 [M,K] -> bf16 [M,Kp], zero-padded.
// ---------------------------------------------------------------------------
__global__ void cvt_pad_bf16(const float* __restrict__ in, ushort_t* __restrict__ out,
                             int M, int K, int Kp) {
  int kp8 = Kp >> 3;
  int total = M * kp8;
  for (int t = blockIdx.x * blockDim.x + threadIdx.x; t < total;
       t += gridDim.x * blockDim.x) {
    int row = t / kp8;
    int c0 = (t - row * kp8) * 8;
    short8 o;
    if (c0 + 7 < K) {
      const float4 a = *reinterpret_cast<const float4*>(in + (long)row * K + c0);
      const float4 b = *reinterpret_cast<const float4*>(in + (long)row * K + c0 + 4);
      o[0] = (short)f2b(a.x); o[1] = (short)f2b(a.y);
      o[2] = (short)f2b(a.z); o[3] = (short)f2b(a.w);
      o[4] = (short)f2b(b.x); o[5] = (short)f2b(b.y);
      o[6] = (short)f2b(b.z); o[7] = (short)f2b(b.w);
    } else {
#pragma unroll
      for (int j = 0; j < 8; ++j) {
        int c = c0 + j;
        float v = (c < K) ? in[(long)row * K + c] : 0.f;
        o[j] = (short)f2b(v);
      }
    }
    *reinterpret_cast<short8*>(out + (long)row * Kp + c0) = o;
  }
}

// ---------------------------------------------------------------------------
// MFMA GEMM: C[M,128] = A[M,Kp]bf16 @ W[128,Kp]bf16^T  (as round 2)
// ---------------------------------------------------------------------------
template <bool SPLIT>
__global__ __launch_bounds__(256) void mfma_gemm_nt(
    const ushort_t* __restrict__ A, const ushort_t* __restrict__ W,
    float* __restrict__ Cacc, ushort_t* __restrict__ Cb,
    int Kp, int kChunk, long strideW, long strideCz) {
  __shared__ __align__(16) ushort_t As[64 * 64];
  __shared__ __align__(16) ushort_t Ws[128 * 64];
  const int tid = threadIdx.x;
  const int wave = tid >> 6, lane = tid & 63;
  const int m0 = blockIdx.x * 64;
  const int kbase = blockIdx.y * kChunk;
  const ushort_t* Wz = W + (long)blockIdx.z * strideW;

  f32x4 acc[8];
#pragma unroll
  for (int n = 0; n < 8; ++n) acc[n] = (f32x4){0.f, 0.f, 0.f, 0.f};

  for (int k0 = kbase; k0 < kbase + kChunk; k0 += 64) {
    __syncthreads();
#pragma unroll
    for (int q = 0; q < 2; ++q) {
      int s = q * 256 + tid;
      int row = s >> 3, ch = s & 7;
      int sch = ch ^ (row & 7);
      const ushort_t* g = A + (long)(m0 + row) * Kp + k0 + sch * 8;
      __builtin_amdgcn_global_load_lds(
          (const __attribute__((address_space(1))) unsigned int*)g,
          (__attribute__((address_space(3))) unsigned int*)(As + s * 8), 16, 0, 0);
    }
#pragma unroll
    for (int q = 0; q < 4; ++q) {
      int s = q * 256 + tid;
      int row = s >> 3, ch = s & 7;
      int sch = ch ^ (row & 7);
      const ushort_t* g = Wz + (long)row * Kp + k0 + sch * 8;
      __builtin_amdgcn_global_load_lds(
          (const __attribute__((address_space(1))) unsigned int*)g,
          (__attribute__((address_space(3))) unsigned int*)(Ws + s * 8), 16, 0, 0);
    }
    __syncthreads();
#pragma unroll
    for (int kk = 0; kk < 2; ++kk) {
      const int arow = wave * 16 + (lane & 15);
      const int ach = (kk * 4 + (lane >> 4)) ^ (arow & 7);
      short8 afrag = *reinterpret_cast<const short8*>(As + arow * 64 + ach * 8);
#pragma unroll
      for (int n = 0; n < 8; ++n) {
        const int brow = n * 16 + (lane & 15);
        const int bch = (kk * 4 + (lane >> 4)) ^ (brow & 7);
        short8 bfrag = *reinterpret_cast<const short8*>(Ws + brow * 64 + bch * 8);
        acc[n] = __builtin_amdgcn_mfma_f32_16x16x32_bf16(afrag, bfrag, acc[n], 0, 0, 0);
      }
    }
  }
  const int rbase = m0 + wave * 16 + (lane >> 4) * 4;
  const int cb = lane & 15;
  if (SPLIT) {
#pragma unroll
    for (int n = 0; n < 8; ++n) {
      int col = n * 16 + cb;
#pragma unroll
      for (int r = 0; r < 4; ++r)
        atomicAdd(&Cacc[(long)(rbase + r) * 128 + col], acc[n][r]);
    }
  } else {
    ushort_t* Cz = Cb + (long)blockIdx.z * strideCz;
#pragma unroll
    for (int n = 0; n < 8; ++n) {
      int col = n * 16 + cb;
#pragma unroll
      for (int r = 0; r < 4; ++r)
        Cz[(long)(rbase + r) * 128 + col] = f2b(acc[n][r]);
    }
  }
}

// ---------------------------------------------------------------------------
__global__ void fill_f32(float* __restrict__ p, long n, float v) {
  long i = blockIdx.x * (long)blockDim.x + threadIdx.x;
  long stride = (long)gridDim.x * blockDim.x;
  for (; i < n; i += stride) p[i] = v;
}

__global__ void bias_relu_cvt(const float* __restrict__ C, const float* __restrict__ b0,
                              const float* __restrict__ b1, const float* __restrict__ b2,
                              ushort_t* __restrict__ xb) {
  int t = blockIdx.x * blockDim.x + threadIdx.x;
  if (t >= N_NODES * 16) return;
  int row = t >> 4, c0 = (t & 15) * 8;
  const float* bp = row < NPV ? b0 : (row < 2 * NPV ? b1 : b2);
  const float4 v0 = *reinterpret_cast<const float4*>(C + (long)row * 128 + c0);
  const float4 v1 = *reinterpret_cast<const float4*>(C + (long)row * 128 + c0 + 4);
  float x[8] = {v0.x, v0.y, v0.z, v0.w, v1.x, v1.y, v1.z, v1.w};
  short8 o;
#pragma unroll
  for (int j = 0; j < 8; ++j) {
    float v = x[j] + bp[c0 + j];
    v = v > 0.f ? v : 0.f;
    o[j] = (short)f2b(v);
  }
  *reinterpret_cast<short8*>(xb + (long)row * 128 + c0) = o;
}

__global__ void compute_wT_b(const float* __restrict__ comp,
                             const float* __restrict__ basis,
                             ushort_t* __restrict__ wTb) {
  int idx = blockIdx.x * blockDim.x + threadIdx.x;
  if (idx >= R_REL * 128 * 128) return;
  int r = idx >> 14;
  int rem = idx & 16383;
  int o = rem >> 7;
  int i = rem & 127;
  float s = 0.f;
#pragma unroll
  for (int b = 0; b < B_BASES; ++b)
    s += comp[r * B_BASES + b] * basis[((b << 7) + i) * 128 + o];
  wTb[((long)(r << 7) + o) * 128 + i] = f2b(s);
}

__global__ __launch_bounds__(256) void att_tables_b(
    const ushort_t* __restrict__ xwb, const float* __restrict__ q,
    const float* __restrict__ k, float* __restrict__ ai, float* __restrict__ aj) {
  __shared__ float qs[512], ks[512];
  for (int t = threadIdx.x; t < 512; t += blockDim.x) { qs[t] = q[t]; ks[t] = k[t]; }
  __syncthreads();
  const int lane = threadIdx.x & 63;
  const int sub = lane & 15;
  int wave_global = blockIdx.x * 4 + (threadIdx.x >> 6);
  int row = wave_global * 4 + (lane >> 4);
  if (row >= R_REL * N_NODES) return;
  short8 xv = *reinterpret_cast<const short8*>(xwb + (long)row * 128 + sub * 8);
  float aq[4] = {0.f, 0.f, 0.f, 0.f}, ak[4] = {0.f, 0.f, 0.f, 0.f};
#pragma unroll
  for (int j = 0; j < 8; ++j) {
    float x = b2f((ushort_t)xv[j]);
    int c = sub * 8 + j;
#pragma unroll
    for (int h = 0; h < 4; ++h) {
      aq[h] += x * qs[c * 4 + h];
      ak[h] += x * ks[c * 4 + h];
    }
  }
#pragma unroll
  for (int m = 8; m >= 1; m >>= 1) {
#pragma unroll
    for (int h = 0; h < 4; ++h) {
      aq[h] += __shfl_xor(aq[h], m);
      ak[h] += __shfl_xor(ak[h], m);
    }
  }
  if (sub < 4) ai[(long)row * 4 + sub] = aq[sub];
  else if (sub < 8) aj[(long)row * 4 + sub - 4] = ak[sub - 4];
}

// ---------------------------------------------------------------------------
// CSR build: count -> scan -> scatter. recs[pos] = src | (rel<<16)
// ---------------------------------------------------------------------------
__global__ void count_dst(const int* __restrict__ dst, int* __restrict__ cnt, int E) {
  int e = blockIdx.x * blockDim.x + threadIdx.x;
  if (e < E) atomicAdd(&cnt[dst[e]], 1);
}

__global__ __launch_bounds__(1024) void scan_start(const int* __restrict__ cnt,
                                                   int* __restrict__ start) {
  __shared__ int partial[1024];
  const int t = threadIdx.x;
  int local[24];
  int s = 0;
#pragma unroll
  for (int i = 0; i < 24; ++i) { local[i] = cnt[t * 24 + i]; s += local[i]; }
  partial[t] = s;
  __syncthreads();
  for (int off = 1; off < 1024; off <<= 1) {
    int v = (t >= off) ? partial[t - off] : 0;
    __syncthreads();
    partial[t] += v;
    __syncthreads();
  }
  int run = (t > 0) ? partial[t - 1] : 0;
#pragma unroll
  for (int i = 0; i < 24; ++i) { start[t * 24 + i] = run; run += local[i]; }
  if (t == 1023) start[N_NODES] = run;
}

__global__ void scatter_edges(const int* __restrict__ src, const int* __restrict__ dst,
                              const int* __restrict__ et, const int* __restrict__ start,
                              int* __restrict__ cursor, int* __restrict__ recs, int E) {
  int e = blockIdx.x * blockDim.x + threadIdx.x;
  if (e >= E) return;
  int d = dst[e];
  int pos = start[d] + atomicAdd(&cursor[d], 1);
  recs[pos] = src[e] | (et[e] << 16);
}

// ---------------------------------------------------------------------------
// Fused per-dst softmax + aggregation. One wave per node; no atomics, no LDS.
// ---------------------------------------------------------------------------
__global__ __launch_bounds__(256) void fused_agg(
    const int* __restrict__ start, const int* __restrict__ recs,
    const float* __restrict__ ai, const float* __restrict__ aj,
    const ushort_t* __restrict__ xwb, ushort_t* __restrict__ xb_out,
    float* __restrict__ fout) {
  const int wave = threadIdx.x >> 6, lane = threadIdx.x & 63;
  const int d = blockIdx.x * 4 + wave;
  const int s0 = start[d], s1 = start[d + 1];
  const float degf = (float)(s1 - s0);
  const int hsel = lane >> 4;  // head for channels 2*lane, 2*lane+1

  float m[R_REL][4], dsum[R_REL][4];
#pragma unroll
  for (int ri = 0; ri < R_REL; ++ri)
#pragma unroll
    for (int h = 0; h < 4; ++h) { m[ri][h] = -INFINITY; dsum[ri][h] = 0.f; }

  // pass 1: per-(relation,head) max over this node's edges
  for (int c0 = s0; c0 < s1; c0 += 64) {
    int idx = c0 + lane;
    bool valid = idx < s1;
    int rec = valid ? recs[idx] : 0;
    int s = rec & 0xFFFF, r = (rec >> 16) & 7;
    float al[4] = {0.f, 0.f, 0.f, 0.f};
    if (valid) {
      float4 av = *reinterpret_cast<const float4*>(ai + ((long)r * N_NODES + d) * 4);
      float4 bv = *reinterpret_cast<const float4*>(aj + ((long)r * N_NODES + s) * 4);
      al[0] = lrelu(av.x + bv.x); al[1] = lrelu(av.y + bv.y);
      al[2] = lrelu(av.z + bv.z); al[3] = lrelu(av.w + bv.w);
    }
#pragma unroll
    for (int ri = 0; ri < R_REL; ++ri) {
      float v[4];
#pragma unroll
      for (int h = 0; h < 4; ++h) v[h] = (valid && r == ri) ? al[h] : -INFINITY;
#pragma unroll
      for (int mk = 32; mk >= 1; mk >>= 1)
#pragma unroll
        for (int h = 0; h < 4; ++h) v[h] = fmaxf(v[h], __shfl_xor(v[h], mk));
#pragma unroll
      for (int h = 0; h < 4; ++h) m[ri][h] = fmaxf(m[ri][h], v[h]);
    }
  }
  // pass 2: denominators
  for (int c0 = s0; c0 < s1; c0 += 64) {
    int idx = c0 + lane;
    bool valid = idx < s1;
    int rec = valid ? recs[idx] : 0;
    int s = rec & 0xFFFF, r = (rec >> 16) & 7;
    float al[4] = {0.f, 0.f, 0.f, 0.f};
    if (valid) {
      float4 av = *reinterpret_cast<const float4*>(ai + ((long)r * N_NODES + d) * 4);
      float4 bv = *reinterpret_cast<const float4*>(aj + ((long)r * N_NODES + s) * 4);
      al[0] = lrelu(av.x + bv.x); al[1] = lrelu(av.y + bv.y);
      al[2] = lrelu(av.z + bv.z); al[3] = lrelu(av.w + bv.w);
    }
#pragma unroll
    for (int ri = 0; ri < R_REL; ++ri) {
      float v[4];
#pragma unroll
      for (int h = 0; h < 4; ++h)
        v[h] = (valid && r == ri) ? __expf(al[h] - m[ri][h]) : 0.f;
#pragma unroll
      for (int mk = 32; mk >= 1; mk >>= 1)
#pragma unroll
        for (int h = 0; h < 4; ++h) v[h] += __shfl_xor(v[h], mk);
#pragma unroll
      for (int h = 0; h < 4; ++h) dsum[ri][h] += v[h];
    }
  }
  // pass 3: coefficients + channel-parallel aggregation
  float acc0 = 0.f, acc1 = 0.f;
  for (int c0 = s0; c0 < s1; c0 += 64) {
    int idx = c0 + lane;
    bool valid = idx < s1;
    int rec = valid ? recs[idx] : 0;
    int s = rec & 0xFFFF, r = (rec >> 16) & 7;
    float al[4] = {0.f, 0.f, 0.f, 0.f};
    if (valid) {
      float4 av = *reinterpret_cast<const float4*>(ai + ((long)r * N_NODES + d) * 4);
      float4 bv = *reinterpret_cast<const float4*>(aj + ((long)r * N_NODES + s) * 4);
      al[0] = lrelu(av.x + bv.x); al[1] = lrelu(av.y + bv.y);
      al[2] = lrelu(av.z + bv.z); al[3] = lrelu(av.w + bv.w);
    }
    float aco[4] = {0.f, 0.f, 0.f, 0.f};
#pragma unroll
    for (int ri = 0; ri < R_REL; ++ri)
#pragma unroll
      for (int h = 0; h < 4; ++h) {
        float v = __expf(al[h] - m[ri][h]) / (dsum[ri][h] + 1e-16f) * degf;
        aco[h] = (valid && r == ri) ? v : aco[h];
      }
    int cvalid = s1 - c0;
    if (cvalid > 64) cvalid = 64;
    for (int j = 0; j < cvalid; ++j) {
      int rj = __shfl(rec, j);
      float a0 = __shfl(aco[0], j), a1 = __shfl(aco[1], j);
      float a2 = __shfl(aco[2], j), a3 = __shfl(aco[3], j);
      float aval = hsel == 0 ? a0 : (hsel == 1 ? a1 : (hsel == 2 ? a2 : a3));
      int sj = rj & 0xFFFF, rr = (rj >> 16) & 7;
      unsigned int pk = *reinterpret_cast<const unsigned int*>(
          xwb + (((long)rr * N_NODES + sj) << 7) + 2 * lane);
      acc0 += aval * b2f((ushort_t)(pk & 0xFFFF));
      acc1 += aval * b2f((ushort_t)(pk >> 16));
    }
  }
  unsigned int po = ((unsigned int)f2b(acc1) << 16) | (unsigned int)f2b(acc0);
  *reinterpret_cast<unsigned int*>(xb_out + ((long)d << 7) + 2 * lane) = po;
  if (fout) {
    *reinterpret_cast<float2*>(fout + ((long)d << 7) + 2 * lane) =
        make_float2(acc0, acc1);
  }
}

__global__ void final_linear(const float* __restrict__ x, const float* __restrict__ Wc,
                             const float* __restrict__ bc, float* __restrict__ out) {
  __shared__ float wcs[4 * 384];
  for (int t = threadIdx.x; t < 4 * 384; t += blockDim.x) wcs[t] = Wc[t];
  __syncthreads();
  int i = blockIdx.x * blockDim.x + threadIdx.x;
  if (i >= NPV) return;
  float acc[4] = {0.f, 0.f, 0.f, 0.f};
  for (int v = 0; v < 3; ++v) {
    const float* xr = x + ((long)v * NPV + i) * 128;
    for (int c = 0; c < 128; c += 4) {
      float4 xv = *reinterpret_cast<const float4*>(xr + c);
#pragma unroll
      for (int l = 0; l < 4; ++l) {
        const float* w = wcs + l * 384 + v * 128 + c;
        acc[l] += xv.x * w[0] + xv.y * w[1] + xv.z * w[2] + xv.w * w[3];
      }
    }
  }
#pragma unroll
  for (int l = 0; l < 4; ++l) out[(long)i * 4 + l] = acc[l] + bc[l];
}

// ---------------------------------------------------------------------------
static void run_layer(const ushort_t* xb_in, ushort_t* xb_out, float* fout,
                      const float* basis, const float* comp, const float* q,
                      const float* k, ushort_t* xwb, ushort_t* wTb, float* ai,
                      float* aj, const int* startb, const int* recs,
                      hipStream_t stream) {
  compute_wT_b<<<(R_REL * 128 * 128 + 255) / 256, 256, 0, stream>>>(comp, basis, wTb);
  mfma_gemm_nt<false><<<dim3(N_NODES / 64, 1, R_REL), 256, 0, stream>>>(
      xb_in, wTb, nullptr, xwb, 128, 128, 128 * 128, (long)N_NODES * 128);
  att_tables_b<<<(R_REL * N_NODES) / 16, 256, 0, stream>>>(xwb, q, k, ai, aj);
  fused_agg<<<N_NODES / 4, 256, 0, stream>>>(startb, recs, ai, aj, xwb, xb_out, fout);
}

extern "C" void kernel_launch(void* const* d_in, const int* in_sizes, int n_in,
                              void* d_out, int out_size, void* d_ws, size_t ws_size,
                              hipStream_t stream) {
  const float* x0 = (const float*)d_in[0];
  const float* x1 = (const float*)d_in[1];
  const float* x2 = (const float*)d_in[2];
  const int* edge_index = (const int*)d_in[3];
  const int* edge_type = (const int*)d_in[4];
  const float* Wp0 = (const float*)d_in[5];
  const float* bp0 = (const float*)d_in[6];
  const float* Wp1 = (const float*)d_in[7];
  const float* bp1 = (const float*)d_in[8];
  const float* Wp2 = (const float*)d_in[9];
  const float* bp2 = (const float*)d_in[10];
  const float* basis0 = (const float*)d_in[11];
  const float* comp0 = (const float*)d_in[12];
  const float* q0 = (const float*)d_in[13];
  const float* k0 = (const float*)d_in[14];
  const float* basis1 = (const float*)d_in[15];
  const float* comp1 = (const float*)d_in[16];
  const float* q1 = (const float*)d_in[17];
  const float* k1 = (const float*)d_in[18];
  const float* Wc = (const float*)d_in[19];
  const float* bc = (const float*)d_in[20];

  const int* src = edge_index;
  const int* dst = edge_index + E_EDGES;

  // ---- workspace layout ----
  char* w = (char*)d_ws;
  auto alloc = [&](long bytes) {
    char* p = w;
    w += (bytes + 255) & ~255L;
    return p;
  };
  ushort_t* padX = (ushort_t*)alloc((long)NPV * 2048 * 2);
  ushort_t* padW = (ushort_t*)alloc(128L * 2048 * 2);
  ushort_t* xbA  = (ushort_t*)alloc((long)NX * 2);
  ushort_t* xbB  = (ushort_t*)alloc((long)NX * 2);
  ushort_t* xwb  = (ushort_t*)alloc((long)R_REL * NX * 2);
  ushort_t* wTb  = (ushort_t*)alloc((long)R_REL * 128 * 128 * 2);
  float* Cacc    = (float*)alloc((long)NX * 4);
  float* ai      = (float*)alloc((long)R_REL * N_NODES * 4 * 4);
  float* aj      = (float*)alloc((long)R_REL * N_NODES * 4 * 4);
  int* cnt       = (int*)alloc((long)N_NODES * 4);
  int* cursor    = (int*)alloc((long)N_NODES * 4);
  int* startb    = (int*)alloc((long)(N_NODES + 1) * 4);
  int* recs      = (int*)alloc((long)E_EDGES * 4);

  // ---- projections: Cacc = x @ Wp^T (split-K atomics), then bias+relu -> xbA
  fill_f32<<<2048, 256, 0, stream>>>(Cacc, NX, 0.f);

  const float* xs[3] = {x0, x1, x2};
  const float* Ws_[3] = {Wp0, Wp1, Wp2};
  const int Ks[3] = {2000, 1500, 500};
  const int Kps[3] = {2048, 1536, 512};
  const int splits[3] = {4, 3, 2};
  for (int v = 0; v < 3; ++v) {
    int K = Ks[v], Kp = Kps[v];
    cvt_pad_bf16<<<2048, 256, 0, stream>>>(xs[v], padX, NPV, K, Kp);
    cvt_pad_bf16<<<128, 256, 0, stream>>>(Ws_[v], padW, 128, K, Kp);
    mfma_gemm_nt<true><<<dim3(NPV / 64, splits[v], 1), 256, 0, stream>>>(
        padX, padW, Cacc + (long)v * NPV * 128, nullptr, Kp, Kp / splits[v], 0, 0);
  }
  bias_relu_cvt<<<(N_NODES * 16 + 255) / 256, 256, 0, stream>>>(Cacc, bp0, bp1, bp2, xbA);

  // ---- CSR build (once; shared by both layers)
  fill_f32<<<96, 256, 0, stream>>>((float*)cnt, 2L * N_NODES, 0.f);  // cnt+cursor adjacent
  count_dst<<<E_EDGES / 256, 256, 0, stream>>>(dst, cnt, E_EDGES);
  scan_start<<<1, 1024, 0, stream>>>(cnt, startb);
  scatter_edges<<<E_EDGES / 256, 256, 0, stream>>>(src, dst, edge_type, startb,
                                                   cursor, recs, E_EDGES);

  // ---- layer 0: xbA -> xbB (bf16)
  run_layer(xbA, xbB, nullptr, basis0, comp0, q0, k0, xwb, wTb, ai, aj,
            startb, recs, stream);
  // ---- layer 1: xbB -> (xbA dummy bf16, Cacc f32)
  run_layer(xbB, xbA, Cacc, basis1, comp1, q1, k1, xwb, wTb, ai, aj,
            startb, recs, stream);

  final_linear<<<(NPV + 255) / 256, 256, 0, stream>>>(Cacc, Wc, bc, (float*)d_out);
}

// Round 4
// 424.130 us; speedup vs baseline: 3.0981x; 1.1979x over previous
//
#include <hip/hip_runtime.h>
#include <hip/hip_bf16.h>
#include <math.h>

#define N_NODES 24576
#define NPV 8192
#define E_EDGES 393216
#define R_REL 6
#define B_BASES 8
#define HEADS 4
#define NEG_SLOPE 0.2f
#define NX (N_NODES * 128)
#define NK (N_NODES * R_REL)

typedef unsigned short ushort_t;
using short8 = __attribute__((ext_vector_type(8))) short;
using f32x4 = __attribute__((ext_vector_type(4))) float;

__device__ __forceinline__ float lrelu(float x) { return x >= 0.f ? x : NEG_SLOPE * x; }
__device__ __forceinline__ float b2f(ushort_t u) {
  unsigned int v = ((unsigned int)u) << 16;
  float f;
  __builtin_memcpy(&f, &v, 4);
  return f;
}
__device__ __forceinline__ ushort_t f2b(float f) {
  __hip_bfloat16 h = __float2bfloat16(f);
  ushort_t u;
  __builtin_memcpy(&u, &h, 2);
  return u;
}

// ---------------------------------------------------------------------------
// cvt_pad: f32 [M,K] -> bf16 [M,Kp], zero-padded.
// ---------------------------------------------------------------------------
__global__ void cvt_pad_bf16(const float* __restrict__ in, ushort_t* __restrict__ out,
                             int M, int K, int Kp) {
  int kp8 = Kp >> 3;
  int total = M * kp8;
  for (int t = blockIdx.x * blockDim.x + threadIdx.x; t < total;
       t += gridDim.x * blockDim.x) {
    int row = t / kp8;
    int c0 = (t - row * kp8) * 8;
    short8 o;
    if (c0 + 7 < K) {
      const float4 a = *reinterpret_cast<const float4*>(in + (long)row * K + c0);
      const float4 b = *reinterpret_cast<const float4*>(in + (long)row * K + c0 + 4);
      o[0] = (short)f2b(a.x); o[1] = (short)f2b(a.y);
      o[2] = (short)f2b(a.z); o[3] = (short)f2b(a.w);
      o[4] = (short)f2b(b.x); o[5] = (short)f2b(b.y);
      o[6] = (short)f2b(b.z); o[7] = (short)f2b(b.w);
    } else {
#pragma unroll
      for (int j = 0; j < 8; ++j) {
        int c = c0 + j;
        float v = (c < K) ? in[(long)row * K + c] : 0.f;
        o[j] = (short)f2b(v);
      }
    }
    *reinterpret_cast<short8*>(out + (long)row * Kp + c0) = o;
  }
}

// ---------------------------------------------------------------------------
// MFMA GEMM: C[M,128] = A[M,Kp]bf16 @ W[128,Kp]bf16^T
// ---------------------------------------------------------------------------
template <bool SPLIT>
__global__ __launch_bounds__(256) void mfma_gemm_nt(
    const ushort_t* __restrict__ A, const ushort_t* __restrict__ W,
    float* __restrict__ Cacc, ushort_t* __restrict__ Cb,
    int Kp, int kChunk, long strideW, long strideCz) {
  __shared__ __align__(16) ushort_t As[64 * 64];
  __shared__ __align__(16) ushort_t Ws[128 * 64];
  const int tid = threadIdx.x;
  const int wave = tid >> 6, lane = tid & 63;
  const int m0 = blockIdx.x * 64;
  const int kbase = blockIdx.y * kChunk;
  const ushort_t* Wz = W + (long)blockIdx.z * strideW;

  f32x4 acc[8];
#pragma unroll
  for (int n = 0; n < 8; ++n) acc[n] = (f32x4){0.f, 0.f, 0.f, 0.f};

  for (int k0 = kbase; k0 < kbase + kChunk; k0 += 64) {
    __syncthreads();
#pragma unroll
    for (int q = 0; q < 2; ++q) {
      int s = q * 256 + tid;
      int row = s >> 3, ch = s & 7;
      int sch = ch ^ (row & 7);
      const ushort_t* g = A + (long)(m0 + row) * Kp + k0 + sch * 8;
      __builtin_amdgcn_global_load_lds(
          (const __attribute__((address_space(1))) unsigned int*)g,
          (__attribute__((address_space(3))) unsigned int*)(As + s * 8), 16, 0, 0);
    }
#pragma unroll
    for (int q = 0; q < 4; ++q) {
      int s = q * 256 + tid;
      int row = s >> 3, ch = s & 7;
      int sch = ch ^ (row & 7);
      const ushort_t* g = Wz + (long)row * Kp + k0 + sch * 8;
      __builtin_amdgcn_global_load_lds(
          (const __attribute__((address_space(1))) unsigned int*)g,
          (__attribute__((address_space(3))) unsigned int*)(Ws + s * 8), 16, 0, 0);
    }
    __syncthreads();
#pragma unroll
    for (int kk = 0; kk < 2; ++kk) {
      const int arow = wave * 16 + (lane & 15);
      const int ach = (kk * 4 + (lane >> 4)) ^ (arow & 7);
      short8 afrag = *reinterpret_cast<const short8*>(As + arow * 64 + ach * 8);
#pragma unroll
      for (int n = 0; n < 8; ++n) {
        const int brow = n * 16 + (lane & 15);
        const int bch = (kk * 4 + (lane >> 4)) ^ (brow & 7);
        short8 bfrag = *reinterpret_cast<const short8*>(Ws + brow * 64 + bch * 8);
        acc[n] = __builtin_amdgcn_mfma_f32_16x16x32_bf16(afrag, bfrag, acc[n], 0, 0, 0);
      }
    }
  }
  const int rbase = m0 + wave * 16 + (lane >> 4) * 4;
  const int cb = lane & 15;
  if (SPLIT) {
#pragma unroll
    for (int n = 0; n < 8; ++n) {
      int col = n * 16 + cb;
#pragma unroll
      for (int r = 0; r < 4; ++r)
        atomicAdd(&Cacc[(long)(rbase + r) * 128 + col], acc[n][r]);
    }
  } else {
    ushort_t* Cz = Cb + (long)blockIdx.z * strideCz;
#pragma unroll
    for (int n = 0; n < 8; ++n) {
      int col = n * 16 + cb;
#pragma unroll
      for (int r = 0; r < 4; ++r)
        Cz[(long)(rbase + r) * 128 + col] = f2b(acc[n][r]);
    }
  }
}

// ---------------------------------------------------------------------------
__global__ void fill_f32(float* __restrict__ p, long n, float v) {
  long i = blockIdx.x * (long)blockDim.x + threadIdx.x;
  long stride = (long)gridDim.x * blockDim.x;
  for (; i < n; i += stride) p[i] = v;
}

__global__ void bias_relu_cvt(const float* __restrict__ C, const float* __restrict__ b0,
                              const float* __restrict__ b1, const float* __restrict__ b2,
                              ushort_t* __restrict__ xb) {
  int t = blockIdx.x * blockDim.x + threadIdx.x;
  if (t >= N_NODES * 16) return;
  int row = t >> 4, c0 = (t & 15) * 8;
  const float* bp = row < NPV ? b0 : (row < 2 * NPV ? b1 : b2);
  const float4 v0 = *reinterpret_cast<const float4*>(C + (long)row * 128 + c0);
  const float4 v1 = *reinterpret_cast<const float4*>(C + (long)row * 128 + c0 + 4);
  float x[8] = {v0.x, v0.y, v0.z, v0.w, v1.x, v1.y, v1.z, v1.w};
  short8 o;
#pragma unroll
  for (int j = 0; j < 8; ++j) {
    float v = x[j] + bp[c0 + j];
    v = v > 0.f ? v : 0.f;
    o[j] = (short)f2b(v);
  }
  *reinterpret_cast<short8*>(xb + (long)row * 128 + c0) = o;
}

__global__ void compute_wT_b(const float* __restrict__ comp,
                             const float* __restrict__ basis,
                             ushort_t* __restrict__ wTb) {
  int idx = blockIdx.x * blockDim.x + threadIdx.x;
  if (idx >= R_REL * 128 * 128) return;
  int r = idx >> 14;
  int rem = idx & 16383;
  int o = rem >> 7;
  int i = rem & 127;
  float s = 0.f;
#pragma unroll
  for (int b = 0; b < B_BASES; ++b)
    s += comp[r * B_BASES + b] * basis[((b << 7) + i) * 128 + o];
  wTb[((long)(r << 7) + o) * 128 + i] = f2b(s);
}

__global__ __launch_bounds__(256) void att_tables_b(
    const ushort_t* __restrict__ xwb, const float* __restrict__ q,
    const float* __restrict__ k, float* __restrict__ ai, float* __restrict__ aj) {
  __shared__ float qs[512], ks[512];
  for (int t = threadIdx.x; t < 512; t += blockDim.x) { qs[t] = q[t]; ks[t] = k[t]; }
  __syncthreads();
  const int lane = threadIdx.x & 63;
  const int sub = lane & 15;
  int wave_global = blockIdx.x * 4 + (threadIdx.x >> 6);
  int row = wave_global * 4 + (lane >> 4);
  if (row >= R_REL * N_NODES) return;
  short8 xv = *reinterpret_cast<const short8*>(xwb + (long)row * 128 + sub * 8);
  float aq[4] = {0.f, 0.f, 0.f, 0.f}, ak[4] = {0.f, 0.f, 0.f, 0.f};
#pragma unroll
  for (int j = 0; j < 8; ++j) {
    float x = b2f((ushort_t)xv[j]);
    int c = sub * 8 + j;
#pragma unroll
    for (int h = 0; h < 4; ++h) {
      aq[h] += x * qs[c * 4 + h];
      ak[h] += x * ks[c * 4 + h];
    }
  }
#pragma unroll
  for (int m = 8; m >= 1; m >>= 1) {
#pragma unroll
    for (int h = 0; h < 4; ++h) {
      aq[h] += __shfl_xor(aq[h], m);
      ak[h] += __shfl_xor(ak[h], m);
    }
  }
  if (sub < 4) ai[(long)row * 4 + sub] = aq[sub];
  else if (sub < 8) aj[(long)row * 4 + sub - 4] = ak[sub - 4];
}

// ---------------------------------------------------------------------------
// CSR build keyed by (dst*6 + rel): count -> scan -> scatter.
// recs[pos] = src | (rel<<16)
// ---------------------------------------------------------------------------
__global__ void count_key(const int* __restrict__ dst, const int* __restrict__ et,
                          int* __restrict__ cnt, int E) {
  int e = blockIdx.x * blockDim.x + threadIdx.x;
  if (e < E) atomicAdd(&cnt[dst[e] * R_REL + et[e]], 1);
}

__global__ __launch_bounds__(1024) void scan_start(const int* __restrict__ cnt,
                                                   int* __restrict__ start) {
  __shared__ int partial[1024];
  const int t = threadIdx.x;
  const int CH = NK / 1024;  // 144
  int s = 0;
  for (int i = 0; i < CH; ++i) s += cnt[t * CH + i];
  partial[t] = s;
  __syncthreads();
  for (int off = 1; off < 1024; off <<= 1) {
    int v = (t >= off) ? partial[t - off] : 0;
    __syncthreads();
    partial[t] += v;
    __syncthreads();
  }
  int run = (t > 0) ? partial[t - 1] : 0;
  for (int i = 0; i < CH; ++i) { start[t * CH + i] = run; run += cnt[t * CH + i]; }
  if (t == 1023) start[NK] = run;
}

__global__ void scatter_edges(const int* __restrict__ src, const int* __restrict__ dst,
                              const int* __restrict__ et, const int* __restrict__ start,
                              int* __restrict__ cursor, int* __restrict__ recs, int E) {
  int e = blockIdx.x * blockDim.x + threadIdx.x;
  if (e >= E) return;
  int key = dst[e] * R_REL + et[e];
  int pos = start[key] + atomicAdd(&cursor[key], 1);
  recs[pos] = src[e] | (et[e] << 16);
}

// ---------------------------------------------------------------------------
// seg_softmax: one thread per (dst,rel) segment. Online max/sum over the
// segment's edges, then writes per-edge coefficients coef[h*E + pos].
// ---------------------------------------------------------------------------
__global__ __launch_bounds__(256) void seg_softmax(
    const int* __restrict__ rstart, const int* __restrict__ recs,
    const float* __restrict__ ai, const float* __restrict__ aj,
    float* __restrict__ coef) {
  int seg = blockIdx.x * blockDim.x + threadIdx.x;
  if (seg >= NK) return;
  int p0 = rstart[seg], p1 = rstart[seg + 1];
  if (p0 == p1) return;
  int d = seg / R_REL, r = seg - d * R_REL;
  float4 av = *reinterpret_cast<const float4*>(ai + ((long)r * N_NODES + d) * 4);
  float degf = (float)(rstart[(d + 1) * R_REL] - rstart[d * R_REL]);
  float m[4] = {-INFINITY, -INFINITY, -INFINITY, -INFINITY};
  float sum[4] = {0.f, 0.f, 0.f, 0.f};
  for (int p = p0; p < p1; ++p) {
    int s = recs[p] & 0xFFFF;
    float4 bv = *reinterpret_cast<const float4*>(aj + ((long)r * N_NODES + s) * 4);
    float al[4] = {lrelu(av.x + bv.x), lrelu(av.y + bv.y),
                   lrelu(av.z + bv.z), lrelu(av.w + bv.w)};
#pragma unroll
    for (int h = 0; h < 4; ++h) {
      float nm = fmaxf(m[h], al[h]);
      sum[h] = sum[h] * __expf(m[h] - nm) + __expf(al[h] - nm);
      m[h] = nm;
    }
  }
  float rs[4];
#pragma unroll
  for (int h = 0; h < 4; ++h) rs[h] = degf / (sum[h] + 1e-16f);
  for (int p = p0; p < p1; ++p) {
    int s = recs[p] & 0xFFFF;
    float4 bv = *reinterpret_cast<const float4*>(aj + ((long)r * N_NODES + s) * 4);
    float al[4] = {lrelu(av.x + bv.x), lrelu(av.y + bv.y),
                   lrelu(av.z + bv.z), lrelu(av.w + bv.w)};
#pragma unroll
    for (int h = 0; h < 4; ++h)
      coef[(long)h * E_EDGES + p] = __expf(al[h] - m[h]) * rs[h];
  }
}

// ---------------------------------------------------------------------------
// fused_agg: one wave per dst node; pure gather-accumulate, no shuffles.
// lane handles channels {2*lane, 2*lane+1}; head = lane>>4.
// ---------------------------------------------------------------------------
__global__ __launch_bounds__(256) void fused_agg(
    const int* __restrict__ rstart, const int* __restrict__ recs,
    const float* __restrict__ coef, const ushort_t* __restrict__ xwb,
    ushort_t* __restrict__ xb_out, float* __restrict__ fout) {
  const int wave = threadIdx.x >> 6, lane = threadIdx.x & 63;
  const int d = blockIdx.x * 4 + wave;
  const int s0 = rstart[d * R_REL], s1 = rstart[(d + 1) * R_REL];
  const float* cfp = coef + (long)(lane >> 4) * E_EDGES;
  float acc0 = 0.f, acc1 = 0.f;
#pragma unroll 4
  for (int pos = s0; pos < s1; ++pos) {
    int rec = recs[pos];
    float cf = cfp[pos];
    int s = rec & 0xFFFF, r = rec >> 16;
    unsigned int pk = *reinterpret_cast<const unsigned int*>(
        xwb + (((long)r * N_NODES + s) << 7) + 2 * lane);
    acc0 += cf * b2f((ushort_t)(pk & 0xFFFF));
    acc1 += cf * b2f((ushort_t)(pk >> 16));
  }
  if (xb_out) {
    unsigned int po = ((unsigned int)f2b(acc1) << 16) | (unsigned int)f2b(acc0);
    *reinterpret_cast<unsigned int*>(xb_out + ((long)d << 7) + 2 * lane) = po;
  }
  if (fout) {
    *reinterpret_cast<float2*>(fout + ((long)d << 7) + 2 * lane) =
        make_float2(acc0, acc1);
  }
}

__global__ void final_linear(const float* __restrict__ x, const float* __restrict__ Wc,
                             const float* __restrict__ bc, float* __restrict__ out) {
  __shared__ float wcs[4 * 384];
  for (int t = threadIdx.x; t < 4 * 384; t += blockDim.x) wcs[t] = Wc[t];
  __syncthreads();
  int i = blockIdx.x * blockDim.x + threadIdx.x;
  if (i >= NPV) return;
  float acc[4] = {0.f, 0.f, 0.f, 0.f};
  for (int v = 0; v < 3; ++v) {
    const float* xr = x + ((long)v * NPV + i) * 128;
    for (int c = 0; c < 128; c += 4) {
      float4 xv = *reinterpret_cast<const float4*>(xr + c);
#pragma unroll
      for (int l = 0; l < 4; ++l) {
        const float* w = wcs + l * 384 + v * 128 + c;
        acc[l] += xv.x * w[0] + xv.y * w[1] + xv.z * w[2] + xv.w * w[3];
      }
    }
  }
#pragma unroll
  for (int l = 0; l < 4; ++l) out[(long)i * 4 + l] = acc[l] + bc[l];
}

// ---------------------------------------------------------------------------
static void run_layer(const ushort_t* xb_in, ushort_t* xb_out, float* fout,
                      const float* basis, const float* comp, const float* q,
                      const float* k, ushort_t* xwb, ushort_t* wTb, float* ai,
                      float* aj, float* coef, const int* rstart, const int* recs,
                      hipStream_t stream) {
  compute_wT_b<<<(R_REL * 128 * 128 + 255) / 256, 256, 0, stream>>>(comp, basis, wTb);
  mfma_gemm_nt<false><<<dim3(N_NODES / 64, 1, R_REL), 256, 0, stream>>>(
      xb_in, wTb, nullptr, xwb, 128, 128, 128 * 128, (long)N_NODES * 128);
  att_tables_b<<<(R_REL * N_NODES) / 16, 256, 0, stream>>>(xwb, q, k, ai, aj);
  seg_softmax<<<(NK + 255) / 256, 256, 0, stream>>>(rstart, recs, ai, aj, coef);
  fused_agg<<<N_NODES / 4, 256, 0, stream>>>(rstart, recs, coef, xwb, xb_out, fout);
}

extern "C" void kernel_launch(void* const* d_in, const int* in_sizes, int n_in,
                              void* d_out, int out_size, void* d_ws, size_t ws_size,
                              hipStream_t stream) {
  const float* x0 = (const float*)d_in[0];
  const float* x1 = (const float*)d_in[1];
  const float* x2 = (const float*)d_in[2];
  const int* edge_index = (const int*)d_in[3];
  const int* edge_type = (const int*)d_in[4];
  const float* Wp0 = (const float*)d_in[5];
  const float* bp0 = (const float*)d_in[6];
  const float* Wp1 = (const float*)d_in[7];
  const float* bp1 = (const float*)d_in[8];
  const float* Wp2 = (const float*)d_in[9];
  const float* bp2 = (const float*)d_in[10];
  const float* basis0 = (const float*)d_in[11];
  const float* comp0 = (const float*)d_in[12];
  const float* q0 = (const float*)d_in[13];
  const float* k0 = (const float*)d_in[14];
  const float* basis1 = (const float*)d_in[15];
  const float* comp1 = (const float*)d_in[16];
  const float* q1 = (const float*)d_in[17];
  const float* k1 = (const float*)d_in[18];
  const float* Wc = (const float*)d_in[19];
  const float* bc = (const float*)d_in[20];

  const int* src = edge_index;
  const int* dst = edge_index + E_EDGES;

  // ---- workspace layout ----
  char* w = (char*)d_ws;
  auto alloc = [&](long bytes) {
    char* p = w;
    w += (bytes + 255) & ~255L;
    return p;
  };
  ushort_t* padX = (ushort_t*)alloc((long)NPV * 2048 * 2);
  ushort_t* padW = (ushort_t*)alloc(128L * 2048 * 2);
  ushort_t* xbA  = (ushort_t*)alloc((long)NX * 2);
  ushort_t* xbB  = (ushort_t*)alloc((long)NX * 2);
  ushort_t* xwb  = (ushort_t*)alloc((long)R_REL * NX * 2);
  ushort_t* wTb  = (ushort_t*)alloc((long)R_REL * 128 * 128 * 2);
  float* Cacc    = (float*)alloc((long)NX * 4);
  float* ai      = (float*)alloc((long)R_REL * N_NODES * 4 * 4);
  float* aj      = (float*)alloc((long)R_REL * N_NODES * 4 * 4);
  float* coef    = (float*)alloc((long)HEADS * E_EDGES * 4);
  int* cnt       = (int*)alloc((long)NK * 4);
  int* cursor    = (int*)alloc((long)NK * 4);
  int* rstart    = (int*)alloc((long)(NK + 1) * 4);
  int* recs      = (int*)alloc((long)E_EDGES * 4);

  // ---- projections: Cacc = x @ Wp^T (split-K atomics), then bias+relu -> xbA
  fill_f32<<<2048, 256, 0, stream>>>(Cacc, NX, 0.f);

  const float* xs[3] = {x0, x1, x2};
  const float* Ws_[3] = {Wp0, Wp1, Wp2};
  const int Ks[3] = {2000, 1500, 500};
  const int Kps[3] = {2048, 1536, 512};
  const int splits[3] = {4, 3, 2};
  for (int v = 0; v < 3; ++v) {
    int K = Ks[v], Kp = Kps[v];
    cvt_pad_bf16<<<2048, 256, 0, stream>>>(xs[v], padX, NPV, K, Kp);
    cvt_pad_bf16<<<128, 256, 0, stream>>>(Ws_[v], padW, 128, K, Kp);
    mfma_gemm_nt<true><<<dim3(NPV / 64, splits[v], 1), 256, 0, stream>>>(
        padX, padW, Cacc + (long)v * NPV * 128, nullptr, Kp, Kp / splits[v], 0, 0);
  }
  bias_relu_cvt<<<(N_NODES * 16 + 255) / 256, 256, 0, stream>>>(Cacc, bp0, bp1, bp2, xbA);

  // ---- CSR build keyed by (dst,rel) (once; shared by both layers)
  fill_f32<<<96, 256, 0, stream>>>((float*)cnt, 2L * NK, 0.f);  // cnt+cursor adjacent
  count_key<<<E_EDGES / 256, 256, 0, stream>>>(dst, edge_type, cnt, E_EDGES);
  scan_start<<<1, 1024, 0, stream>>>(cnt, rstart);
  scatter_edges<<<E_EDGES / 256, 256, 0, stream>>>(src, dst, edge_type, rstart,
                                                   cursor, recs, E_EDGES);

  // ---- layer 0: xbA -> xbB (bf16)
  run_layer(xbA, xbB, nullptr, basis0, comp0, q0, k0, xwb, wTb, ai, aj, coef,
            rstart, recs, stream);
  // ---- layer 1: xbB -> Cacc (f32 only)
  run_layer(xbB, nullptr, Cacc, basis1, comp1, q1, k1, xwb, wTb, ai, aj, coef,
            rstart, recs, stream);

  final_linear<<<(NPV + 255) / 256, 256, 0, stream>>>(Cacc, Wc, bc, (float*)d_out);
}

// Round 5
// 377.176 us; speedup vs baseline: 3.4837x; 1.1245x over previous
//
#include <hip/hip_runtime.h>
#include <hip/hip_bf16.h>
#include <math.h>

#define N_NODES 24576
#define NPV 8192
#define E_EDGES 393216
#define R_REL 6
#define B_BASES 8
#define HEADS 4
#define NEG_SLOPE 0.2f
#define NX (N_NODES * 128)
#define NK (N_NODES * R_REL)
#define SCAN_BLOCKS (NK / 256)  // 576

typedef unsigned short ushort_t;
using short8 = __attribute__((ext_vector_type(8))) short;
using f32x4 = __attribute__((ext_vector_type(4))) float;

__device__ __forceinline__ float lrelu(float x) { return x >= 0.f ? x : NEG_SLOPE * x; }
__device__ __forceinline__ float b2f(ushort_t u) {
  unsigned int v = ((unsigned int)u) << 16;
  float f;
  __builtin_memcpy(&f, &v, 4);
  return f;
}
__device__ __forceinline__ ushort_t f2b(float f) {
  __hip_bfloat16 h = __float2bfloat16(f);
  ushort_t u;
  __builtin_memcpy(&u, &h, 2);
  return u;
}

// ---------------------------------------------------------------------------
// cvt_pad: f32 [M,K] -> bf16 [M,Kp], zero-padded.
// ---------------------------------------------------------------------------
__global__ void cvt_pad_bf16(const float* __restrict__ in, ushort_t* __restrict__ out,
                             int M, int K, int Kp) {
  int kp8 = Kp >> 3;
  int total = M * kp8;
  for (int t = blockIdx.x * blockDim.x + threadIdx.x; t < total;
       t += gridDim.x * blockDim.x) {
    int row = t / kp8;
    int c0 = (t - row * kp8) * 8;
    short8 o;
    if (c0 + 7 < K) {
      const float4 a = *reinterpret_cast<const float4*>(in + (long)row * K + c0);
      const float4 b = *reinterpret_cast<const float4*>(in + (long)row * K + c0 + 4);
      o[0] = (short)f2b(a.x); o[1] = (short)f2b(a.y);
      o[2] = (short)f2b(a.z); o[3] = (short)f2b(a.w);
      o[4] = (short)f2b(b.x); o[5] = (short)f2b(b.y);
      o[6] = (short)f2b(b.z); o[7] = (short)f2b(b.w);
    } else {
#pragma unroll
      for (int j = 0; j < 8; ++j) {
        int c = c0 + j;
        float v = (c < K) ? in[(long)row * K + c] : 0.f;
        o[j] = (short)f2b(v);
      }
    }
    *reinterpret_cast<short8*>(out + (long)row * Kp + c0) = o;
  }
}

// ---------------------------------------------------------------------------
// MFMA GEMM: C[M,128] = A[M,Kp]bf16 @ W[128,Kp]bf16^T
// ---------------------------------------------------------------------------
template <bool SPLIT>
__global__ __launch_bounds__(256) void mfma_gemm_nt(
    const ushort_t* __restrict__ A, const ushort_t* __restrict__ W,
    float* __restrict__ Cacc, ushort_t* __restrict__ Cb,
    int Kp, int kChunk, long strideW, long strideCz) {
  __shared__ __align__(16) ushort_t As[64 * 64];
  __shared__ __align__(16) ushort_t Ws[128 * 64];
  const int tid = threadIdx.x;
  const int wave = tid >> 6, lane = tid & 63;
  const int m0 = blockIdx.x * 64;
  const int kbase = blockIdx.y * kChunk;
  const ushort_t* Wz = W + (long)blockIdx.z * strideW;

  f32x4 acc[8];
#pragma unroll
  for (int n = 0; n < 8; ++n) acc[n] = (f32x4){0.f, 0.f, 0.f, 0.f};

  for (int k0 = kbase; k0 < kbase + kChunk; k0 += 64) {
    __syncthreads();
#pragma unroll
    for (int q = 0; q < 2; ++q) {
      int s = q * 256 + tid;
      int row = s >> 3, ch = s & 7;
      int sch = ch ^ (row & 7);
      const ushort_t* g = A + (long)(m0 + row) * Kp + k0 + sch * 8;
      __builtin_amdgcn_global_load_lds(
          (const __attribute__((address_space(1))) unsigned int*)g,
          (__attribute__((address_space(3))) unsigned int*)(As + s * 8), 16, 0, 0);
    }
#pragma unroll
    for (int q = 0; q < 4; ++q) {
      int s = q * 256 + tid;
      int row = s >> 3, ch = s & 7;
      int sch = ch ^ (row & 7);
      const ushort_t* g = Wz + (long)row * Kp + k0 + sch * 8;
      __builtin_amdgcn_global_load_lds(
          (const __attribute__((address_space(1))) unsigned int*)g,
          (__attribute__((address_space(3))) unsigned int*)(Ws + s * 8), 16, 0, 0);
    }
    __syncthreads();
#pragma unroll
    for (int kk = 0; kk < 2; ++kk) {
      const int arow = wave * 16 + (lane & 15);
      const int ach = (kk * 4 + (lane >> 4)) ^ (arow & 7);
      short8 afrag = *reinterpret_cast<const short8*>(As + arow * 64 + ach * 8);
#pragma unroll
      for (int n = 0; n < 8; ++n) {
        const int brow = n * 16 + (lane & 15);
        const int bch = (kk * 4 + (lane >> 4)) ^ (brow & 7);
        short8 bfrag = *reinterpret_cast<const short8*>(Ws + brow * 64 + bch * 8);
        acc[n] = __builtin_amdgcn_mfma_f32_16x16x32_bf16(afrag, bfrag, acc[n], 0, 0, 0);
      }
    }
  }
  const int rbase = m0 + wave * 16 + (lane >> 4) * 4;
  const int cb = lane & 15;
  if (SPLIT) {
#pragma unroll
    for (int n = 0; n < 8; ++n) {
      int col = n * 16 + cb;
#pragma unroll
      for (int r = 0; r < 4; ++r)
        atomicAdd(&Cacc[(long)(rbase + r) * 128 + col], acc[n][r]);
    }
  } else {
    ushort_t* Cz = Cb + (long)blockIdx.z * strideCz;
#pragma unroll
    for (int n = 0; n < 8; ++n) {
      int col = n * 16 + cb;
#pragma unroll
      for (int r = 0; r < 4; ++r)
        Cz[(long)(rbase + r) * 128 + col] = f2b(acc[n][r]);
    }
  }
}

// ---------------------------------------------------------------------------
__global__ void fill_f32(float* __restrict__ p, long n, float v) {
  long i = blockIdx.x * (long)blockDim.x + threadIdx.x;
  long stride = (long)gridDim.x * blockDim.x;
  for (; i < n; i += stride) p[i] = v;
}

__global__ void bias_relu_cvt(const float* __restrict__ C, const float* __restrict__ b0,
                              const float* __restrict__ b1, const float* __restrict__ b2,
                              ushort_t* __restrict__ xb) {
  int t = blockIdx.x * blockDim.x + threadIdx.x;
  if (t >= N_NODES * 16) return;
  int row = t >> 4, c0 = (t & 15) * 8;
  const float* bp = row < NPV ? b0 : (row < 2 * NPV ? b1 : b2);
  const float4 v0 = *reinterpret_cast<const float4*>(C + (long)row * 128 + c0);
  const float4 v1 = *reinterpret_cast<const float4*>(C + (long)row * 128 + c0 + 4);
  float x[8] = {v0.x, v0.y, v0.z, v0.w, v1.x, v1.y, v1.z, v1.w};
  short8 o;
#pragma unroll
  for (int j = 0; j < 8; ++j) {
    float v = x[j] + bp[c0 + j];
    v = v > 0.f ? v : 0.f;
    o[j] = (short)f2b(v);
  }
  *reinterpret_cast<short8*>(xb + (long)row * 128 + c0) = o;
}

__global__ void compute_wT_b(const float* __restrict__ comp,
                             const float* __restrict__ basis,
                             ushort_t* __restrict__ wTb) {
  int idx = blockIdx.x * blockDim.x + threadIdx.x;
  if (idx >= R_REL * 128 * 128) return;
  int r = idx >> 14;
  int rem = idx & 16383;
  int o = rem >> 7;
  int i = rem & 127;
  float s = 0.f;
#pragma unroll
  for (int b = 0; b < B_BASES; ++b)
    s += comp[r * B_BASES + b] * basis[((b << 7) + i) * 128 + o];
  wTb[((long)(r << 7) + o) * 128 + i] = f2b(s);
}

__global__ __launch_bounds__(256) void att_tables_b(
    const ushort_t* __restrict__ xwb, const float* __restrict__ q,
    const float* __restrict__ k, float* __restrict__ ai, float* __restrict__ aj) {
  __shared__ float qs[512], ks[512];
  for (int t = threadIdx.x; t < 512; t += blockDim.x) { qs[t] = q[t]; ks[t] = k[t]; }
  __syncthreads();
  const int lane = threadIdx.x & 63;
  const int sub = lane & 15;
  int wave_global = blockIdx.x * 4 + (threadIdx.x >> 6);
  int row = wave_global * 4 + (lane >> 4);
  if (row >= R_REL * N_NODES) return;
  short8 xv = *reinterpret_cast<const short8*>(xwb + (long)row * 128 + sub * 8);
  float aq[4] = {0.f, 0.f, 0.f, 0.f}, ak[4] = {0.f, 0.f, 0.f, 0.f};
#pragma unroll
  for (int j = 0; j < 8; ++j) {
    float x = b2f((ushort_t)xv[j]);
    int c = sub * 8 + j;
#pragma unroll
    for (int h = 0; h < 4; ++h) {
      aq[h] += x * qs[c * 4 + h];
      ak[h] += x * ks[c * 4 + h];
    }
  }
#pragma unroll
  for (int m = 8; m >= 1; m >>= 1) {
#pragma unroll
    for (int h = 0; h < 4; ++h) {
      aq[h] += __shfl_xor(aq[h], m);
      ak[h] += __shfl_xor(ak[h], m);
    }
  }
  if (sub < 4) ai[(long)row * 4 + sub] = aq[sub];
  else if (sub < 8) aj[(long)row * 4 + sub - 4] = ak[sub - 4];
}

// ---------------------------------------------------------------------------
// CSR build keyed by (dst*6 + rel): count -> hierarchical scan -> scatter.
// recs[pos] = src | (rel<<16)
// ---------------------------------------------------------------------------
__global__ void count_key(const int* __restrict__ dst, const int* __restrict__ et,
                          int* __restrict__ cnt, int E) {
  int e = blockIdx.x * blockDim.x + threadIdx.x;
  if (e < E) atomicAdd(&cnt[dst[e] * R_REL + et[e]], 1);
}

// phase 1: per-block (256-wide) exclusive scan + block sums
__global__ __launch_bounds__(256) void scan_block(const int* __restrict__ cnt,
                                                  int* __restrict__ start,
                                                  int* __restrict__ blockSums) {
  __shared__ int sm[256];
  const int t = threadIdx.x;
  const int i = blockIdx.x * 256 + t;
  int v = cnt[i];
  sm[t] = v;
  __syncthreads();
  for (int off = 1; off < 256; off <<= 1) {
    int u = (t >= off) ? sm[t - off] : 0;
    __syncthreads();
    sm[t] += u;
    __syncthreads();
  }
  start[i] = sm[t] - v;  // exclusive
  if (t == 255) blockSums[blockIdx.x] = sm[255];
}

// phase 2: one block scans the 576 block sums in place (-> exclusive offsets)
__global__ __launch_bounds__(SCAN_BLOCKS) void scan_sums(int* __restrict__ blockSums) {
  __shared__ int sm[SCAN_BLOCKS];
  const int t = threadIdx.x;
  int v = blockSums[t];
  sm[t] = v;
  __syncthreads();
  for (int off = 1; off < SCAN_BLOCKS; off <<= 1) {
    int u = (t >= off) ? sm[t - off] : 0;
    __syncthreads();
    sm[t] += u;
    __syncthreads();
  }
  blockSums[t] = sm[t] - v;  // exclusive
}

// phase 3: add block offsets; start[NK] is the known total E_EDGES
__global__ __launch_bounds__(256) void add_offsets(int* __restrict__ start,
                                                   const int* __restrict__ blockSums) {
  int i = blockIdx.x * 256 + threadIdx.x;
  start[i] += blockSums[blockIdx.x];
  if (i == 0) start[NK] = E_EDGES;
}

__global__ void scatter_edges(const int* __restrict__ src, const int* __restrict__ dst,
                              const int* __restrict__ et, const int* __restrict__ start,
                              int* __restrict__ cursor, int* __restrict__ recs, int E) {
  int e = blockIdx.x * blockDim.x + threadIdx.x;
  if (e >= E) return;
  int key = dst[e] * R_REL + et[e];
  int pos = start[key] + atomicAdd(&cursor[key], 1);
  recs[pos] = src[e] | (et[e] << 16);
}

// ---------------------------------------------------------------------------
// seg_softmax: one thread per (dst,rel) segment. Online max/sum over the
// segment's edges, then writes per-edge coefficients coef[h*E + pos].
// ---------------------------------------------------------------------------
__global__ __launch_bounds__(256) void seg_softmax(
    const int* __restrict__ rstart, const int* __restrict__ recs,
    const float* __restrict__ ai, const float* __restrict__ aj,
    float* __restrict__ coef) {
  int seg = blockIdx.x * blockDim.x + threadIdx.x;
  if (seg >= NK) return;
  int p0 = rstart[seg], p1 = rstart[seg + 1];
  if (p0 == p1) return;
  int d = seg / R_REL, r = seg - d * R_REL;
  float4 av = *reinterpret_cast<const float4*>(ai + ((long)r * N_NODES + d) * 4);
  float degf = (float)(rstart[(d + 1) * R_REL] - rstart[d * R_REL]);
  float m[4] = {-INFINITY, -INFINITY, -INFINITY, -INFINITY};
  float sum[4] = {0.f, 0.f, 0.f, 0.f};
  for (int p = p0; p < p1; ++p) {
    int s = recs[p] & 0xFFFF;
    float4 bv = *reinterpret_cast<const float4*>(aj + ((long)r * N_NODES + s) * 4);
    float al[4] = {lrelu(av.x + bv.x), lrelu(av.y + bv.y),
                   lrelu(av.z + bv.z), lrelu(av.w + bv.w)};
#pragma unroll
    for (int h = 0; h < 4; ++h) {
      float nm = fmaxf(m[h], al[h]);
      sum[h] = sum[h] * __expf(m[h] - nm) + __expf(al[h] - nm);
      m[h] = nm;
    }
  }
  float rs[4];
#pragma unroll
  for (int h = 0; h < 4; ++h) rs[h] = degf / (sum[h] + 1e-16f);
  for (int p = p0; p < p1; ++p) {
    int s = recs[p] & 0xFFFF;
    float4 bv = *reinterpret_cast<const float4*>(aj + ((long)r * N_NODES + s) * 4);
    float al[4] = {lrelu(av.x + bv.x), lrelu(av.y + bv.y),
                   lrelu(av.z + bv.z), lrelu(av.w + bv.w)};
#pragma unroll
    for (int h = 0; h < 4; ++h)
      coef[(long)h * E_EDGES + p] = __expf(al[h] - m[h]) * rs[h];
  }
}

// ---------------------------------------------------------------------------
// fused_agg: one wave per dst node; pure gather-accumulate, no shuffles.
// lane handles channels {2*lane, 2*lane+1}; head = lane>>4.
// ---------------------------------------------------------------------------
__global__ __launch_bounds__(256) void fused_agg(
    const int* __restrict__ rstart, const int* __restrict__ recs,
    const float* __restrict__ coef, const ushort_t* __restrict__ xwb,
    ushort_t* __restrict__ xb_out, float* __restrict__ fout) {
  const int wave = threadIdx.x >> 6, lane = threadIdx.x & 63;
  const int d = blockIdx.x * 4 + wave;
  const int s0 = rstart[d * R_REL], s1 = rstart[(d + 1) * R_REL];
  const float* cfp = coef + (long)(lane >> 4) * E_EDGES;
  float acc0 = 0.f, acc1 = 0.f;
#pragma unroll 4
  for (int pos = s0; pos < s1; ++pos) {
    int rec = recs[pos];
    float cf = cfp[pos];
    int s = rec & 0xFFFF, r = rec >> 16;
    unsigned int pk = *reinterpret_cast<const unsigned int*>(
        xwb + (((long)r * N_NODES + s) << 7) + 2 * lane);
    acc0 += cf * b2f((ushort_t)(pk & 0xFFFF));
    acc1 += cf * b2f((ushort_t)(pk >> 16));
  }
  if (xb_out) {
    unsigned int po = ((unsigned int)f2b(acc1) << 16) | (unsigned int)f2b(acc0);
    *reinterpret_cast<unsigned int*>(xb_out + ((long)d << 7) + 2 * lane) = po;
  }
  if (fout) {
    *reinterpret_cast<float2*>(fout + ((long)d << 7) + 2 * lane) =
        make_float2(acc0, acc1);
  }
}

__global__ void final_linear(const float* __restrict__ x, const float* __restrict__ Wc,
                             const float* __restrict__ bc, float* __restrict__ out) {
  __shared__ float wcs[4 * 384];
  for (int t = threadIdx.x; t < 4 * 384; t += blockDim.x) wcs[t] = Wc[t];
  __syncthreads();
  int i = blockIdx.x * blockDim.x + threadIdx.x;
  if (i >= NPV) return;
  float acc[4] = {0.f, 0.f, 0.f, 0.f};
  for (int v = 0; v < 3; ++v) {
    const float* xr = x + ((long)v * NPV + i) * 128;
    for (int c = 0; c < 128; c += 4) {
      float4 xv = *reinterpret_cast<const float4*>(xr + c);
#pragma unroll
      for (int l = 0; l < 4; ++l) {
        const float* w = wcs + l * 384 + v * 128 + c;
        acc[l] += xv.x * w[0] + xv.y * w[1] + xv.z * w[2] + xv.w * w[3];
      }
    }
  }
#pragma unroll
  for (int l = 0; l < 4; ++l) out[(long)i * 4 + l] = acc[l] + bc[l];
}

// ---------------------------------------------------------------------------
static void run_layer(const ushort_t* xb_in, ushort_t* xb_out, float* fout,
                      const float* basis, const float* comp, const float* q,
                      const float* k, ushort_t* xwb, ushort_t* wTb, float* ai,
                      float* aj, float* coef, const int* rstart, const int* recs,
                      hipStream_t stream) {
  compute_wT_b<<<(R_REL * 128 * 128 + 255) / 256, 256, 0, stream>>>(comp, basis, wTb);
  mfma_gemm_nt<false><<<dim3(N_NODES / 64, 1, R_REL), 256, 0, stream>>>(
      xb_in, wTb, nullptr, xwb, 128, 128, 128 * 128, (long)N_NODES * 128);
  att_tables_b<<<(R_REL * N_NODES) / 16, 256, 0, stream>>>(xwb, q, k, ai, aj);
  seg_softmax<<<(NK + 255) / 256, 256, 0, stream>>>(rstart, recs, ai, aj, coef);
  fused_agg<<<N_NODES / 4, 256, 0, stream>>>(rstart, recs, coef, xwb, xb_out, fout);
}

extern "C" void kernel_launch(void* const* d_in, const int* in_sizes, int n_in,
                              void* d_out, int out_size, void* d_ws, size_t ws_size,
                              hipStream_t stream) {
  const float* x0 = (const float*)d_in[0];
  const float* x1 = (const float*)d_in[1];
  const float* x2 = (const float*)d_in[2];
  const int* edge_index = (const int*)d_in[3];
  const int* edge_type = (const int*)d_in[4];
  const float* Wp0 = (const float*)d_in[5];
  const float* bp0 = (const float*)d_in[6];
  const float* Wp1 = (const float*)d_in[7];
  const float* bp1 = (const float*)d_in[8];
  const float* Wp2 = (const float*)d_in[9];
  const float* bp2 = (const float*)d_in[10];
  const float* basis0 = (const float*)d_in[11];
  const float* comp0 = (const float*)d_in[12];
  const float* q0 = (const float*)d_in[13];
  const float* k0 = (const float*)d_in[14];
  const float* basis1 = (const float*)d_in[15];
  const float* comp1 = (const float*)d_in[16];
  const float* q1 = (const float*)d_in[17];
  const float* k1 = (const float*)d_in[18];
  const float* Wc = (const float*)d_in[19];
  const float* bc = (const float*)d_in[20];

  const int* src = edge_index;
  const int* dst = edge_index + E_EDGES;

  // ---- workspace layout ----
  char* w = (char*)d_ws;
  auto alloc = [&](long bytes) {
    char* p = w;
    w += (bytes + 255) & ~255L;
    return p;
  };
  ushort_t* padX = (ushort_t*)alloc((long)NPV * 2048 * 2);
  ushort_t* padW = (ushort_t*)alloc(128L * 2048 * 2);
  ushort_t* xbA  = (ushort_t*)alloc((long)NX * 2);
  ushort_t* xbB  = (ushort_t*)alloc((long)NX * 2);
  ushort_t* xwb  = (ushort_t*)alloc((long)R_REL * NX * 2);
  ushort_t* wTb  = (ushort_t*)alloc((long)R_REL * 128 * 128 * 2);
  float* Cacc    = (float*)alloc((long)NX * 4);
  float* ai      = (float*)alloc((long)R_REL * N_NODES * 4 * 4);
  float* aj      = (float*)alloc((long)R_REL * N_NODES * 4 * 4);
  float* coef    = (float*)alloc((long)HEADS * E_EDGES * 4);
  int* cnt       = (int*)alloc((long)NK * 4);
  int* cursor    = (int*)alloc((long)NK * 4);
  int* rstart    = (int*)alloc((long)(NK + 1) * 4);
  int* recs      = (int*)alloc((long)E_EDGES * 4);
  int* blockSums = (int*)alloc((long)SCAN_BLOCKS * 4);

  // ---- projections: Cacc = x @ Wp^T (split-K atomics), then bias+relu -> xbA
  fill_f32<<<2048, 256, 0, stream>>>(Cacc, NX, 0.f);

  const float* xs[3] = {x0, x1, x2};
  const float* Ws_[3] = {Wp0, Wp1, Wp2};
  const int Ks[3] = {2000, 1500, 500};
  const int Kps[3] = {2048, 1536, 512};
  const int splits[3] = {4, 3, 2};
  for (int v = 0; v < 3; ++v) {
    int K = Ks[v], Kp = Kps[v];
    cvt_pad_bf16<<<2048, 256, 0, stream>>>(xs[v], padX, NPV, K, Kp);
    cvt_pad_bf16<<<128, 256, 0, stream>>>(Ws_[v], padW, 128, K, Kp);
    mfma_gemm_nt<true><<<dim3(NPV / 64, splits[v], 1), 256, 0, stream>>>(
        padX, padW, Cacc + (long)v * NPV * 128, nullptr, Kp, Kp / splits[v], 0, 0);
  }
  bias_relu_cvt<<<(N_NODES * 16 + 255) / 256, 256, 0, stream>>>(Cacc, bp0, bp1, bp2, xbA);

  // ---- CSR build keyed by (dst,rel) (once; shared by both layers)
  fill_f32<<<96, 256, 0, stream>>>((float*)cnt, 2L * NK, 0.f);  // cnt+cursor adjacent
  count_key<<<E_EDGES / 256, 256, 0, stream>>>(dst, edge_type, cnt, E_EDGES);
  scan_block<<<SCAN_BLOCKS, 256, 0, stream>>>(cnt, rstart, blockSums);
  scan_sums<<<1, SCAN_BLOCKS, 0, stream>>>(blockSums);
  add_offsets<<<SCAN_BLOCKS, 256, 0, stream>>>(rstart, blockSums);
  scatter_edges<<<E_EDGES / 256, 256, 0, stream>>>(src, dst, edge_type, rstart,
                                                   cursor, recs, E_EDGES);

  // ---- layer 0: xbA -> xbB (bf16)
  run_layer(xbA, xbB, nullptr, basis0, comp0, q0, k0, xwb, wTb, ai, aj, coef,
            rstart, recs, stream);
  // ---- layer 1: xbB -> Cacc (f32 only)
  run_layer(xbB, nullptr, Cacc, basis1, comp1, q1, k1, xwb, wTb, ai, aj, coef,
            rstart, recs, stream);

  final_linear<<<(NPV + 255) / 256, 256, 0, stream>>>(Cacc, Wc, bc, (float*)d_out);
}

// Round 6
// 342.768 us; speedup vs baseline: 3.8335x; 1.1004x over previous
//
#include <hip/hip_runtime.h>
#include <hip/hip_bf16.h>
#include <math.h>

#define N_NODES 24576
#define NPV 8192
#define E_EDGES 393216
#define R_REL 6
#define B_BASES 8
#define HEADS 4
#define NEG_SLOPE 0.2f
#define NX (N_NODES * 128)
#define NK (N_NODES * R_REL)
#define SCAN_BLOCKS (NK / 256)  // 576

typedef unsigned short ushort_t;
using short8 = __attribute__((ext_vector_type(8))) short;
using f32x4 = __attribute__((ext_vector_type(4))) float;

__device__ __forceinline__ float lrelu(float x) { return x >= 0.f ? x : NEG_SLOPE * x; }
__device__ __forceinline__ float b2f(ushort_t u) {
  unsigned int v = ((unsigned int)u) << 16;
  float f;
  __builtin_memcpy(&f, &v, 4);
  return f;
}
__device__ __forceinline__ ushort_t f2b(float f) {
  __hip_bfloat16 h = __float2bfloat16(f);
  ushort_t u;
  __builtin_memcpy(&u, &h, 2);
  return u;
}

// ---------------------------------------------------------------------------
// cvt_pad: f32 [M,K] -> bf16 [M,Kp], zero-padded.
// ---------------------------------------------------------------------------
__global__ void cvt_pad_bf16(const float* __restrict__ in, ushort_t* __restrict__ out,
                             int M, int K, int Kp) {
  int kp8 = Kp >> 3;
  int total = M * kp8;
  for (int t = blockIdx.x * blockDim.x + threadIdx.x; t < total;
       t += gridDim.x * blockDim.x) {
    int row = t / kp8;
    int c0 = (t - row * kp8) * 8;
    short8 o;
    if (c0 + 7 < K) {
      const float4 a = *reinterpret_cast<const float4*>(in + (long)row * K + c0);
      const float4 b = *reinterpret_cast<const float4*>(in + (long)row * K + c0 + 4);
      o[0] = (short)f2b(a.x); o[1] = (short)f2b(a.y);
      o[2] = (short)f2b(a.z); o[3] = (short)f2b(a.w);
      o[4] = (short)f2b(b.x); o[5] = (short)f2b(b.y);
      o[6] = (short)f2b(b.z); o[7] = (short)f2b(b.w);
    } else {
#pragma unroll
      for (int j = 0; j < 8; ++j) {
        int c = c0 + j;
        float v = (c < K) ? in[(long)row * K + c] : 0.f;
        o[j] = (short)f2b(v);
      }
    }
    *reinterpret_cast<short8*>(out + (long)row * Kp + c0) = o;
  }
}

// ---------------------------------------------------------------------------
// MFMA GEMM: C[M,128] = A[M,Kp]bf16 @ W[128,Kp]bf16^T
// TABLES: additionally ai/aj tables = C @ q / C @ k fused in the epilogue.
// ---------------------------------------------------------------------------
template <bool SPLIT, bool TABLES>
__global__ __launch_bounds__(256) void mfma_gemm_nt(
    const ushort_t* __restrict__ A, const ushort_t* __restrict__ W,
    float* __restrict__ Cacc, ushort_t* __restrict__ Cb,
    int Kp, int kChunk, long strideW, long strideCz,
    const float* __restrict__ qt, const float* __restrict__ kt,
    float* __restrict__ ai, float* __restrict__ aj) {
  __shared__ __align__(16) ushort_t As[64 * 64];
  __shared__ __align__(16) ushort_t Ws[128 * 64];
  const int tid = threadIdx.x;
  const int wave = tid >> 6, lane = tid & 63;
  const int m0 = blockIdx.x * 64;
  const int kbase = blockIdx.y * kChunk;
  const ushort_t* Wz = W + (long)blockIdx.z * strideW;

  f32x4 acc[8];
#pragma unroll
  for (int n = 0; n < 8; ++n) acc[n] = (f32x4){0.f, 0.f, 0.f, 0.f};

  for (int k0 = kbase; k0 < kbase + kChunk; k0 += 64) {
    __syncthreads();
#pragma unroll
    for (int q = 0; q < 2; ++q) {
      int s = q * 256 + tid;
      int row = s >> 3, ch = s & 7;
      int sch = ch ^ (row & 7);
      const ushort_t* g = A + (long)(m0 + row) * Kp + k0 + sch * 8;
      __builtin_amdgcn_global_load_lds(
          (const __attribute__((address_space(1))) unsigned int*)g,
          (__attribute__((address_space(3))) unsigned int*)(As + s * 8), 16, 0, 0);
    }
#pragma unroll
    for (int q = 0; q < 4; ++q) {
      int s = q * 256 + tid;
      int row = s >> 3, ch = s & 7;
      int sch = ch ^ (row & 7);
      const ushort_t* g = Wz + (long)row * Kp + k0 + sch * 8;
      __builtin_amdgcn_global_load_lds(
          (const __attribute__((address_space(1))) unsigned int*)g,
          (__attribute__((address_space(3))) unsigned int*)(Ws + s * 8), 16, 0, 0);
    }
    __syncthreads();
#pragma unroll
    for (int kk = 0; kk < 2; ++kk) {
      const int arow = wave * 16 + (lane & 15);
      const int ach = (kk * 4 + (lane >> 4)) ^ (arow & 7);
      short8 afrag = *reinterpret_cast<const short8*>(As + arow * 64 + ach * 8);
#pragma unroll
      for (int n = 0; n < 8; ++n) {
        const int brow = n * 16 + (lane & 15);
        const int bch = (kk * 4 + (lane >> 4)) ^ (brow & 7);
        short8 bfrag = *reinterpret_cast<const short8*>(Ws + brow * 64 + bch * 8);
        acc[n] = __builtin_amdgcn_mfma_f32_16x16x32_bf16(afrag, bfrag, acc[n], 0, 0, 0);
      }
    }
  }
  const int rbase = m0 + wave * 16 + (lane >> 4) * 4;
  const int cb = lane & 15;
  if (SPLIT) {
#pragma unroll
    for (int n = 0; n < 8; ++n) {
      int col = n * 16 + cb;
#pragma unroll
      for (int r = 0; r < 4; ++r)
        atomicAdd(&Cacc[(long)(rbase + r) * 128 + col], acc[n][r]);
    }
  } else {
    ushort_t* Cz = Cb + (long)blockIdx.z * strideCz;
#pragma unroll
    for (int n = 0; n < 8; ++n) {
      int col = n * 16 + cb;
#pragma unroll
      for (int r = 0; r < 4; ++r)
        Cz[(long)(rbase + r) * 128 + col] = f2b(acc[n][r]);
    }
  }
  if (TABLES) {
    // aq[r][h] = sum over this thread's 8 columns of acc * q[col][h]
    float aq[4][4], ak[4][4];
#pragma unroll
    for (int r = 0; r < 4; ++r)
#pragma unroll
      for (int h = 0; h < 4; ++h) { aq[r][h] = 0.f; ak[r][h] = 0.f; }
#pragma unroll
    for (int n = 0; n < 8; ++n) {
      int col = n * 16 + cb;
      float4 qv = *reinterpret_cast<const float4*>(qt + (long)col * 4);
      float4 kv = *reinterpret_cast<const float4*>(kt + (long)col * 4);
#pragma unroll
      for (int r = 0; r < 4; ++r) {
        float x = acc[n][r];
        aq[r][0] += x * qv.x; aq[r][1] += x * qv.y;
        aq[r][2] += x * qv.z; aq[r][3] += x * qv.w;
        ak[r][0] += x * kv.x; ak[r][1] += x * kv.y;
        ak[r][2] += x * kv.z; ak[r][3] += x * kv.w;
      }
    }
    // reduce across the 16 lanes of the column group
#pragma unroll
    for (int mk = 1; mk < 16; mk <<= 1) {
#pragma unroll
      for (int r = 0; r < 4; ++r)
#pragma unroll
        for (int h = 0; h < 4; ++h) {
          aq[r][h] += __shfl_xor(aq[r][h], mk);
          ak[r][h] += __shfl_xor(ak[r][h], mk);
        }
    }
    int rr = cb >> 2, hh = cb & 3;
    long row = (long)blockIdx.z * N_NODES + rbase + rr;
    ai[row * 4 + hh] = aq[rr][hh];
    aj[row * 4 + hh] = ak[rr][hh];
  }
}

// ---------------------------------------------------------------------------
__global__ void fill_f32(float* __restrict__ p, long n, float v) {
  long i = blockIdx.x * (long)blockDim.x + threadIdx.x;
  long stride = (long)gridDim.x * blockDim.x;
  for (; i < n; i += stride) p[i] = v;
}

__global__ void bias_relu_cvt(const float* __restrict__ C, const float* __restrict__ b0,
                              const float* __restrict__ b1, const float* __restrict__ b2,
                              ushort_t* __restrict__ xb) {
  int t = blockIdx.x * blockDim.x + threadIdx.x;
  if (t >= N_NODES * 16) return;
  int row = t >> 4, c0 = (t & 15) * 8;
  const float* bp = row < NPV ? b0 : (row < 2 * NPV ? b1 : b2);
  const float4 v0 = *reinterpret_cast<const float4*>(C + (long)row * 128 + c0);
  const float4 v1 = *reinterpret_cast<const float4*>(C + (long)row * 128 + c0 + 4);
  float x[8] = {v0.x, v0.y, v0.z, v0.w, v1.x, v1.y, v1.z, v1.w};
  short8 o;
#pragma unroll
  for (int j = 0; j < 8; ++j) {
    float v = x[j] + bp[c0 + j];
    v = v > 0.f ? v : 0.f;
    o[j] = (short)f2b(v);
  }
  *reinterpret_cast<short8*>(xb + (long)row * 128 + c0) = o;
}

__global__ void compute_wT_b(const float* __restrict__ comp,
                             const float* __restrict__ basis,
                             ushort_t* __restrict__ wTb) {
  int idx = blockIdx.x * blockDim.x + threadIdx.x;
  if (idx >= R_REL * 128 * 128) return;
  int r = idx >> 14;
  int rem = idx & 16383;
  int o = rem >> 7;
  int i = rem & 127;
  float s = 0.f;
#pragma unroll
  for (int b = 0; b < B_BASES; ++b)
    s += comp[r * B_BASES + b] * basis[((b << 7) + i) * 128 + o];
  wTb[((long)(r << 7) + o) * 128 + i] = f2b(s);
}

// ---------------------------------------------------------------------------
// CSR build keyed by (dst*6 + rel): count -> hierarchical scan -> scatter.
// recs[pos] = src | (rel<<16)
// ---------------------------------------------------------------------------
__global__ void count_key(const int* __restrict__ dst, const int* __restrict__ et,
                          int* __restrict__ cnt, int E) {
  int e = blockIdx.x * blockDim.x + threadIdx.x;
  if (e < E) atomicAdd(&cnt[dst[e] * R_REL + et[e]], 1);
}

__global__ __launch_bounds__(256) void scan_block(const int* __restrict__ cnt,
                                                  int* __restrict__ start,
                                                  int* __restrict__ blockSums) {
  __shared__ int sm[256];
  const int t = threadIdx.x;
  const int i = blockIdx.x * 256 + t;
  int v = cnt[i];
  sm[t] = v;
  __syncthreads();
  for (int off = 1; off < 256; off <<= 1) {
    int u = (t >= off) ? sm[t - off] : 0;
    __syncthreads();
    sm[t] += u;
    __syncthreads();
  }
  start[i] = sm[t] - v;  // exclusive
  if (t == 255) blockSums[blockIdx.x] = sm[255];
}

__global__ __launch_bounds__(SCAN_BLOCKS) void scan_sums(int* __restrict__ blockSums) {
  __shared__ int sm[SCAN_BLOCKS];
  const int t = threadIdx.x;
  int v = blockSums[t];
  sm[t] = v;
  __syncthreads();
  for (int off = 1; off < SCAN_BLOCKS; off <<= 1) {
    int u = (t >= off) ? sm[t - off] : 0;
    __syncthreads();
    sm[t] += u;
    __syncthreads();
  }
  blockSums[t] = sm[t] - v;  // exclusive
}

__global__ __launch_bounds__(256) void add_offsets(int* __restrict__ start,
                                                   const int* __restrict__ blockSums) {
  int i = blockIdx.x * 256 + threadIdx.x;
  start[i] += blockSums[blockIdx.x];
  if (i == 0) start[NK] = E_EDGES;
}

__global__ void scatter_edges(const int* __restrict__ src, const int* __restrict__ dst,
                              const int* __restrict__ et, const int* __restrict__ start,
                              int* __restrict__ cursor, int* __restrict__ recs, int E) {
  int e = blockIdx.x * blockDim.x + threadIdx.x;
  if (e >= E) return;
  int key = dst[e] * R_REL + et[e];
  int pos = start[key] + atomicAdd(&cursor[key], 1);
  recs[pos] = src[e] | (et[e] << 16);
}

// ---------------------------------------------------------------------------
// seg_softmax: one thread per (dst,rel) segment -> per-edge coef[h*E + pos].
// ---------------------------------------------------------------------------
__global__ __launch_bounds__(256) void seg_softmax(
    const int* __restrict__ rstart, const int* __restrict__ recs,
    const float* __restrict__ ai, const float* __restrict__ aj,
    float* __restrict__ coef) {
  int seg = blockIdx.x * blockDim.x + threadIdx.x;
  if (seg >= NK) return;
  int p0 = rstart[seg], p1 = rstart[seg + 1];
  if (p0 == p1) return;
  int d = seg / R_REL, r = seg - d * R_REL;
  float4 av = *reinterpret_cast<const float4*>(ai + ((long)r * N_NODES + d) * 4);
  float degf = (float)(rstart[(d + 1) * R_REL] - rstart[d * R_REL]);
  float m[4] = {-INFINITY, -INFINITY, -INFINITY, -INFINITY};
  float sum[4] = {0.f, 0.f, 0.f, 0.f};
  for (int p = p0; p < p1; ++p) {
    int s = recs[p] & 0xFFFF;
    float4 bv = *reinterpret_cast<const float4*>(aj + ((long)r * N_NODES + s) * 4);
    float al[4] = {lrelu(av.x + bv.x), lrelu(av.y + bv.y),
                   lrelu(av.z + bv.z), lrelu(av.w + bv.w)};
#pragma unroll
    for (int h = 0; h < 4; ++h) {
      float nm = fmaxf(m[h], al[h]);
      sum[h] = sum[h] * __expf(m[h] - nm) + __expf(al[h] - nm);
      m[h] = nm;
    }
  }
  float rs[4];
#pragma unroll
  for (int h = 0; h < 4; ++h) rs[h] = degf / (sum[h] + 1e-16f);
  for (int p = p0; p < p1; ++p) {
    int s = recs[p] & 0xFFFF;
    float4 bv = *reinterpret_cast<const float4*>(aj + ((long)r * N_NODES + s) * 4);
    float al[4] = {lrelu(av.x + bv.x), lrelu(av.y + bv.y),
                   lrelu(av.z + bv.z), lrelu(av.w + bv.w)};
#pragma unroll
    for (int h = 0; h < 4; ++h)
      coef[(long)h * E_EDGES + p] = __expf(al[h] - m[h]) * rs[h];
  }
}

// ---------------------------------------------------------------------------
// fused_agg: one wave per dst node; pure gather-accumulate.
// ---------------------------------------------------------------------------
__global__ __launch_bounds__(256) void fused_agg(
    const int* __restrict__ rstart, const int* __restrict__ recs,
    const float* __restrict__ coef, const ushort_t* __restrict__ xwb,
    ushort_t* __restrict__ xb_out, float* __restrict__ fout) {
  const int wave = threadIdx.x >> 6, lane = threadIdx.x & 63;
  const int d = blockIdx.x * 4 + wave;
  const int s0 = rstart[d * R_REL], s1 = rstart[(d + 1) * R_REL];
  const float* cfp = coef + (long)(lane >> 4) * E_EDGES;
  float acc0 = 0.f, acc1 = 0.f;
#pragma unroll 4
  for (int pos = s0; pos < s1; ++pos) {
    int rec = recs[pos];
    float cf = cfp[pos];
    int s = rec & 0xFFFF, r = rec >> 16;
    unsigned int pk = *reinterpret_cast<const unsigned int*>(
        xwb + (((long)r * N_NODES + s) << 7) + 2 * lane);
    acc0 += cf * b2f((ushort_t)(pk & 0xFFFF));
    acc1 += cf * b2f((ushort_t)(pk >> 16));
  }
  if (xb_out) {
    unsigned int po = ((unsigned int)f2b(acc1) << 16) | (unsigned int)f2b(acc0);
    *reinterpret_cast<unsigned int*>(xb_out + ((long)d << 7) + 2 * lane) = po;
  }
  if (fout) {
    *reinterpret_cast<float2*>(fout + ((long)d << 7) + 2 * lane) =
        make_float2(acc0, acc1);
  }
}

__global__ void final_linear(const float* __restrict__ x, const float* __restrict__ Wc,
                             const float* __restrict__ bc, float* __restrict__ out) {
  __shared__ float wcs[4 * 384];
  for (int t = threadIdx.x; t < 4 * 384; t += blockDim.x) wcs[t] = Wc[t];
  __syncthreads();
  int i = blockIdx.x * blockDim.x + threadIdx.x;
  if (i >= NPV) return;
  float acc[4] = {0.f, 0.f, 0.f, 0.f};
  for (int v = 0; v < 3; ++v) {
    const float* xr = x + ((long)v * NPV + i) * 128;
    for (int c = 0; c < 128; c += 4) {
      float4 xv = *reinterpret_cast<const float4*>(xr + c);
#pragma unroll
      for (int l = 0; l < 4; ++l) {
        const float* w = wcs + l * 384 + v * 128 + c;
        acc[l] += xv.x * w[0] + xv.y * w[1] + xv.z * w[2] + xv.w * w[3];
      }
    }
  }
#pragma unroll
  for (int l = 0; l < 4; ++l) out[(long)i * 4 + l] = acc[l] + bc[l];
}

// ---------------------------------------------------------------------------
static void run_layer(const ushort_t* xb_in, ushort_t* xb_out, float* fout,
                      const float* basis, const float* comp, const float* q,
                      const float* k, ushort_t* xwb, ushort_t* wTb, float* ai,
                      float* aj, float* coef, const int* rstart, const int* recs,
                      hipStream_t stream) {
  compute_wT_b<<<(R_REL * 128 * 128 + 255) / 256, 256, 0, stream>>>(comp, basis, wTb);
  mfma_gemm_nt<false, true><<<dim3(N_NODES / 64, 1, R_REL), 256, 0, stream>>>(
      xb_in, wTb, nullptr, xwb, 128, 128, 128 * 128, (long)N_NODES * 128,
      q, k, ai, aj);
  seg_softmax<<<(NK + 255) / 256, 256, 0, stream>>>(rstart, recs, ai, aj, coef);
  fused_agg<<<N_NODES / 4, 256, 0, stream>>>(rstart, recs, coef, xwb, xb_out, fout);
}

extern "C" void kernel_launch(void* const* d_in, const int* in_sizes, int n_in,
                              void* d_out, int out_size, void* d_ws, size_t ws_size,
                              hipStream_t stream) {
  const float* x0 = (const float*)d_in[0];
  const float* x1 = (const float*)d_in[1];
  const float* x2 = (const float*)d_in[2];
  const int* edge_index = (const int*)d_in[3];
  const int* edge_type = (const int*)d_in[4];
  const float* Wp0 = (const float*)d_in[5];
  const float* bp0 = (const float*)d_in[6];
  const float* Wp1 = (const float*)d_in[7];
  const float* bp1 = (const float*)d_in[8];
  const float* Wp2 = (const float*)d_in[9];
  const float* bp2 = (const float*)d_in[10];
  const float* basis0 = (const float*)d_in[11];
  const float* comp0 = (const float*)d_in[12];
  const float* q0 = (const float*)d_in[13];
  const float* k0 = (const float*)d_in[14];
  const float* basis1 = (const float*)d_in[15];
  const float* comp1 = (const float*)d_in[16];
  const float* q1 = (const float*)d_in[17];
  const float* k1 = (const float*)d_in[18];
  const float* Wc = (const float*)d_in[19];
  const float* bc = (const float*)d_in[20];

  const int* src = edge_index;
  const int* dst = edge_index + E_EDGES;

  // ---- workspace layout ----
  char* w = (char*)d_ws;
  auto alloc = [&](long bytes) {
    char* p = w;
    w += (bytes + 255) & ~255L;
    return p;
  };
  ushort_t* padX = (ushort_t*)alloc((long)NPV * 2048 * 2);
  ushort_t* padW = (ushort_t*)alloc(128L * 2048 * 2);
  ushort_t* xbA  = (ushort_t*)alloc((long)NX * 2);
  ushort_t* xbB  = (ushort_t*)alloc((long)NX * 2);
  ushort_t* xwb  = (ushort_t*)alloc((long)R_REL * NX * 2);
  ushort_t* wTb  = (ushort_t*)alloc((long)R_REL * 128 * 128 * 2);
  float* Cacc    = (float*)alloc((long)NX * 4);
  float* ai      = (float*)alloc((long)R_REL * N_NODES * 4 * 4);
  float* aj      = (float*)alloc((long)R_REL * N_NODES * 4 * 4);
  float* coef    = (float*)alloc((long)HEADS * E_EDGES * 4);
  int* cnt       = (int*)alloc((long)NK * 4);
  int* cursor    = (int*)alloc((long)NK * 4);
  int* rstart    = (int*)alloc((long)(NK + 1) * 4);
  int* recs      = (int*)alloc((long)E_EDGES * 4);
  int* blockSums = (int*)alloc((long)SCAN_BLOCKS * 4);

  // ---- projections: Cacc = x @ Wp^T (split-K atomics), then bias+relu -> xbA
  fill_f32<<<2048, 256, 0, stream>>>(Cacc, NX, 0.f);

  const float* xs[3] = {x0, x1, x2};
  const float* Ws_[3] = {Wp0, Wp1, Wp2};
  const int Ks[3] = {2000, 1500, 500};
  const int Kps[3] = {2048, 1536, 512};
  const int splits[3] = {4, 3, 2};
  for (int v = 0; v < 3; ++v) {
    int K = Ks[v], Kp = Kps[v];
    cvt_pad_bf16<<<2048, 256, 0, stream>>>(xs[v], padX, NPV, K, Kp);
    cvt_pad_bf16<<<128, 256, 0, stream>>>(Ws_[v], padW, 128, K, Kp);
    mfma_gemm_nt<true, false><<<dim3(NPV / 64, splits[v], 1), 256, 0, stream>>>(
        padX, padW, Cacc + (long)v * NPV * 128, nullptr, Kp, Kp / splits[v], 0, 0,
        nullptr, nullptr, nullptr, nullptr);
  }
  bias_relu_cvt<<<(N_NODES * 16 + 255) / 256, 256, 0, stream>>>(Cacc, bp0, bp1, bp2, xbA);

  // ---- CSR build keyed by (dst,rel) (once; shared by both layers)
  fill_f32<<<96, 256, 0, stream>>>((float*)cnt, 2L * NK, 0.f);  // cnt+cursor adjacent
  count_key<<<E_EDGES / 256, 256, 0, stream>>>(dst, edge_type, cnt, E_EDGES);
  scan_block<<<SCAN_BLOCKS, 256, 0, stream>>>(cnt, rstart, blockSums);
  scan_sums<<<1, SCAN_BLOCKS, 0, stream>>>(blockSums);
  add_offsets<<<SCAN_BLOCKS, 256, 0, stream>>>(rstart, blockSums);
  scatter_edges<<<E_EDGES / 256, 256, 0, stream>>>(src, dst, edge_type, rstart,
                                                   cursor, recs, E_EDGES);

  // ---- layer 0: xbA -> xbB (bf16)
  run_layer(xbA, xbB, nullptr, basis0, comp0, q0, k0, xwb, wTb, ai, aj, coef,
            rstart, recs, stream);
  // ---- layer 1: xbB -> Cacc (f32 only)
  run_layer(xbB, nullptr, Cacc, basis1, comp1, q1, k1, xwb, wTb, ai, aj, coef,
            rstart, recs, stream);

  final_linear<<<(NPV + 255) / 256, 256, 0, stream>>>(Cacc, Wc, bc, (float*)d_out);
}

// Round 8
// 315.793 us; speedup vs baseline: 4.1609x; 1.0854x over previous
//
#include <hip/hip_runtime.h>
#include <hip/hip_bf16.h>
#include <math.h>

#define N_NODES 24576
#define NPV 8192
#define E_EDGES 393216
#define R_REL 6
#define B_BASES 8
#define HEADS 4
#define NEG_SLOPE 0.2f
#define NX (N_NODES * 128)
#define NK (N_NODES * R_REL)
#define SCAN_BLOCKS (NK / 256)  // 576

typedef unsigned short ushort_t;
using short8 = __attribute__((ext_vector_type(8))) short;
using f32x4 = __attribute__((ext_vector_type(4))) float;

__device__ __forceinline__ float lrelu(float x) { return x >= 0.f ? x : NEG_SLOPE * x; }
__device__ __forceinline__ float b2f(ushort_t u) {
  unsigned int v = ((unsigned int)u) << 16;
  float f;
  __builtin_memcpy(&f, &v, 4);
  return f;
}
__device__ __forceinline__ ushort_t f2b(float f) {
  __hip_bfloat16 h = __float2bfloat16(f);
  ushort_t u;
  __builtin_memcpy(&u, &h, 2);
  return u;
}

// ---------------------------------------------------------------------------
// gemm_proj: xb[v*NPV + m, col] = bf16(relu(x_v[m,:K] @ W_v[col,:K]^T + b_v))
// Fused f32->bf16 conversion in reg-staging (no padded copies, no split-K
// atomics, no separate bias pass). grid (NPV/64, 3 views), 256 threads.
// ---------------------------------------------------------------------------
__global__ __launch_bounds__(256) void gemm_proj(
    const float* __restrict__ x0, const float* __restrict__ x1,
    const float* __restrict__ x2, const float* __restrict__ w0,
    const float* __restrict__ w1, const float* __restrict__ w2,
    const float* __restrict__ b0, const float* __restrict__ b1,
    const float* __restrict__ b2, ushort_t* __restrict__ xb) {
  __shared__ __align__(16) ushort_t As[64 * 64];
  __shared__ __align__(16) ushort_t Ws[128 * 64];
  const int v = blockIdx.y;
  const float* A;
  const float* W;
  const float* bias;
  int K;
  if (v == 0) { A = x0; W = w0; bias = b0; K = 2000; }
  else if (v == 1) { A = x1; W = w1; bias = b1; K = 1500; }
  else { A = x2; W = w2; bias = b2; K = 500; }
  const int tid = threadIdx.x;
  const int wave = tid >> 6, lane = tid & 63;
  const int m0 = blockIdx.x * 64;

  f32x4 acc[8];
#pragma unroll
  for (int n = 0; n < 8; ++n) acc[n] = (f32x4){0.f, 0.f, 0.f, 0.f};

  const int nsteps = (K + 63) >> 6;
  for (int step = 0; step < nsteps; ++step) {
    const int k0 = step << 6;
    __syncthreads();
    // stage A tile (64 rows x 64 k), XOR-swizzled chunk on the source side
#pragma unroll
    for (int q = 0; q < 2; ++q) {
      int s = q * 256 + tid;
      int row = s >> 3, ch = s & 7;
      int gk = k0 + ((ch ^ (row & 7)) << 3);
      const float* gp = A + (long)(m0 + row) * K + gk;
      short8 o;
      if (gk + 8 <= K) {
        float4 a = *reinterpret_cast<const float4*>(gp);
        float4 b = *reinterpret_cast<const float4*>(gp + 4);
        o[0] = (short)f2b(a.x); o[1] = (short)f2b(a.y);
        o[2] = (short)f2b(a.z); o[3] = (short)f2b(a.w);
        o[4] = (short)f2b(b.x); o[5] = (short)f2b(b.y);
        o[6] = (short)f2b(b.z); o[7] = (short)f2b(b.w);
      } else {
#pragma unroll
        for (int j = 0; j < 8; ++j)
          o[j] = (gk + j < K) ? (short)f2b(gp[j]) : (short)0;
      }
      *reinterpret_cast<short8*>(As + s * 8) = o;
    }
    // stage W tile (128 rows x 64 k)
#pragma unroll
    for (int q = 0; q < 4; ++q) {
      int s = q * 256 + tid;
      int row = s >> 3, ch = s & 7;
      int gk = k0 + ((ch ^ (row & 7)) << 3);
      const float* gp = W + (long)row * K + gk;
      short8 o;
      if (gk + 8 <= K) {
        float4 a = *reinterpret_cast<const float4*>(gp);
        float4 b = *reinterpret_cast<const float4*>(gp + 4);
        o[0] = (short)f2b(a.x); o[1] = (short)f2b(a.y);
        o[2] = (short)f2b(a.z); o[3] = (short)f2b(a.w);
        o[4] = (short)f2b(b.x); o[5] = (short)f2b(b.y);
        o[6] = (short)f2b(b.z); o[7] = (short)f2b(b.w);
      } else {
#pragma unroll
        for (int j = 0; j < 8; ++j)
          o[j] = (gk + j < K) ? (short)f2b(gp[j]) : (short)0;
      }
      *reinterpret_cast<short8*>(Ws + s * 8) = o;
    }
    __syncthreads();
#pragma unroll
    for (int kk = 0; kk < 2; ++kk) {
      const int arow = wave * 16 + (lane & 15);
      const int ach = (kk * 4 + (lane >> 4)) ^ (arow & 7);
      short8 afrag = *reinterpret_cast<const short8*>(As + arow * 64 + ach * 8);
#pragma unroll
      for (int n = 0; n < 8; ++n) {
        const int brow = n * 16 + (lane & 15);
        const int bch = (kk * 4 + (lane >> 4)) ^ (brow & 7);
        short8 bfrag = *reinterpret_cast<const short8*>(Ws + brow * 64 + bch * 8);
        acc[n] = __builtin_amdgcn_mfma_f32_16x16x32_bf16(afrag, bfrag, acc[n], 0, 0, 0);
      }
    }
  }
  const int rbase = m0 + wave * 16 + (lane >> 4) * 4;
  const int cb = lane & 15;
  ushort_t* out = xb + (long)v * NPV * 128;
#pragma unroll
  for (int n = 0; n < 8; ++n) {
    int col = n * 16 + cb;
    float bz = bias[col];
#pragma unroll
    for (int r = 0; r < 4; ++r) {
      float val = acc[n][r] + bz;
      val = val > 0.f ? val : 0.f;
      out[(long)(rbase + r) * 128 + col] = f2b(val);
    }
  }
}

// ---------------------------------------------------------------------------
// xw GEMM: xwb[r][M,128] = bf16(xb[M,128] @ w_r[128,128]^T), plus fused
// attention tables ai/aj = (xb@w_r) @ q / @ k from the f32 accumulators.
// (proven round-6 kernel, TABLES path only)
// ---------------------------------------------------------------------------
template <bool SPLIT, bool TABLES>
__global__ __launch_bounds__(256) void mfma_gemm_nt(
    const ushort_t* __restrict__ A, const ushort_t* __restrict__ W,
    float* __restrict__ Cacc, ushort_t* __restrict__ Cb,
    int Kp, int kChunk, long strideW, long strideCz,
    const float* __restrict__ qt, const float* __restrict__ kt,
    float* __restrict__ ai, float* __restrict__ aj) {
  __shared__ __align__(16) ushort_t As[64 * 64];
  __shared__ __align__(16) ushort_t Ws[128 * 64];
  const int tid = threadIdx.x;
  const int wave = tid >> 6, lane = tid & 63;
  const int m0 = blockIdx.x * 64;
  const int kbase = blockIdx.y * kChunk;
  const ushort_t* Wz = W + (long)blockIdx.z * strideW;

  f32x4 acc[8];
#pragma unroll
  for (int n = 0; n < 8; ++n) acc[n] = (f32x4){0.f, 0.f, 0.f, 0.f};

  for (int k0 = kbase; k0 < kbase + kChunk; k0 += 64) {
    __syncthreads();
#pragma unroll
    for (int q = 0; q < 2; ++q) {
      int s = q * 256 + tid;
      int row = s >> 3, ch = s & 7;
      int sch = ch ^ (row & 7);
      const ushort_t* g = A + (long)(m0 + row) * Kp + k0 + sch * 8;
      __builtin_amdgcn_global_load_lds(
          (const __attribute__((address_space(1))) unsigned int*)g,
          (__attribute__((address_space(3))) unsigned int*)(As + s * 8), 16, 0, 0);
    }
#pragma unroll
    for (int q = 0; q < 4; ++q) {
      int s = q * 256 + tid;
      int row = s >> 3, ch = s & 7;
      int sch = ch ^ (row & 7);
      const ushort_t* g = Wz + (long)row * Kp + k0 + sch * 8;
      __builtin_amdgcn_global_load_lds(
          (const __attribute__((address_space(1))) unsigned int*)g,
          (__attribute__((address_space(3))) unsigned int*)(Ws + s * 8), 16, 0, 0);
    }
    __syncthreads();
#pragma unroll
    for (int kk = 0; kk < 2; ++kk) {
      const int arow = wave * 16 + (lane & 15);
      const int ach = (kk * 4 + (lane >> 4)) ^ (arow & 7);
      short8 afrag = *reinterpret_cast<const short8*>(As + arow * 64 + ach * 8);
#pragma unroll
      for (int n = 0; n < 8; ++n) {
        const int brow = n * 16 + (lane & 15);
        const int bch = (kk * 4 + (lane >> 4)) ^ (brow & 7);
        short8 bfrag = *reinterpret_cast<const short8*>(Ws + brow * 64 + bch * 8);
        acc[n] = __builtin_amdgcn_mfma_f32_16x16x32_bf16(afrag, bfrag, acc[n], 0, 0, 0);
      }
    }
  }
  const int rbase = m0 + wave * 16 + (lane >> 4) * 4;
  const int cb = lane & 15;
  if (SPLIT) {
#pragma unroll
    for (int n = 0; n < 8; ++n) {
      int col = n * 16 + cb;
#pragma unroll
      for (int r = 0; r < 4; ++r)
        atomicAdd(&Cacc[(long)(rbase + r) * 128 + col], acc[n][r]);
    }
  } else {
    ushort_t* Cz = Cb + (long)blockIdx.z * strideCz;
#pragma unroll
    for (int n = 0; n < 8; ++n) {
      int col = n * 16 + cb;
#pragma unroll
      for (int r = 0; r < 4; ++r)
        Cz[(long)(rbase + r) * 128 + col] = f2b(acc[n][r]);
    }
  }
  if (TABLES) {
    float aq[4][4], ak[4][4];
#pragma unroll
    for (int r = 0; r < 4; ++r)
#pragma unroll
      for (int h = 0; h < 4; ++h) { aq[r][h] = 0.f; ak[r][h] = 0.f; }
#pragma unroll
    for (int n = 0; n < 8; ++n) {
      int col = n * 16 + cb;
      float4 qv = *reinterpret_cast<const float4*>(qt + (long)col * 4);
      float4 kv = *reinterpret_cast<const float4*>(kt + (long)col * 4);
#pragma unroll
      for (int r = 0; r < 4; ++r) {
        float x = acc[n][r];
        aq[r][0] += x * qv.x; aq[r][1] += x * qv.y;
        aq[r][2] += x * qv.z; aq[r][3] += x * qv.w;
        ak[r][0] += x * kv.x; ak[r][1] += x * kv.y;
        ak[r][2] += x * kv.z; ak[r][3] += x * kv.w;
      }
    }
#pragma unroll
    for (int mk = 1; mk < 16; mk <<= 1) {
#pragma unroll
      for (int r = 0; r < 4; ++r)
#pragma unroll
        for (int h = 0; h < 4; ++h) {
          aq[r][h] += __shfl_xor(aq[r][h], mk);
          ak[r][h] += __shfl_xor(ak[r][h], mk);
        }
    }
    int rr = cb >> 2, hh = cb & 3;
    long row = (long)blockIdx.z * N_NODES + rbase + rr;
    ai[row * 4 + hh] = aq[rr][hh];
    aj[row * 4 + hh] = ak[rr][hh];
  }
}

// ---------------------------------------------------------------------------
__global__ void fill_f32(float* __restrict__ p, long n, float v) {
  long i = blockIdx.x * (long)blockDim.x + threadIdx.x;
  long stride = (long)gridDim.x * blockDim.x;
  for (; i < n; i += stride) p[i] = v;
}

// wTb[r,o,i] = bf16( sum_b comp[r,b] * basis[b,i,o] )
__global__ void compute_wT_b(const float* __restrict__ comp,
                             const float* __restrict__ basis,
                             ushort_t* __restrict__ wTb) {
  int idx = blockIdx.x * blockDim.x + threadIdx.x;
  if (idx >= R_REL * 128 * 128) return;
  int r = idx >> 14;
  int rem = idx & 16383;
  int o = rem >> 7;
  int i = rem & 127;
  float s = 0.f;
#pragma unroll
  for (int b = 0; b < B_BASES; ++b)
    s += comp[r * B_BASES + b] * basis[((b << 7) + i) * 128 + o];
  wTb[((long)(r << 7) + o) * 128 + i] = f2b(s);
}

// ---------------------------------------------------------------------------
// CSR build keyed by (dst*6 + rel): count -> hierarchical scan -> scatter.
// ---------------------------------------------------------------------------
__global__ void count_key(const int* __restrict__ dst, const int* __restrict__ et,
                          int* __restrict__ cnt, int E) {
  int e = blockIdx.x * blockDim.x + threadIdx.x;
  if (e < E) atomicAdd(&cnt[dst[e] * R_REL + et[e]], 1);
}

__global__ __launch_bounds__(256) void scan_block(const int* __restrict__ cnt,
                                                  int* __restrict__ start,
                                                  int* __restrict__ blockSums) {
  __shared__ int sm[256];
  const int t = threadIdx.x;
  const int i = blockIdx.x * 256 + t;
  int v = cnt[i];
  sm[t] = v;
  __syncthreads();
  for (int off = 1; off < 256; off <<= 1) {
    int u = (t >= off) ? sm[t - off] : 0;
    __syncthreads();
    sm[t] += u;
    __syncthreads();
  }
  start[i] = sm[t] - v;  // exclusive
  if (t == 255) blockSums[blockIdx.x] = sm[255];
}

__global__ __launch_bounds__(SCAN_BLOCKS) void scan_sums(int* __restrict__ blockSums) {
  __shared__ int sm[SCAN_BLOCKS];
  const int t = threadIdx.x;
  int v = blockSums[t];
  sm[t] = v;
  __syncthreads();
  for (int off = 1; off < SCAN_BLOCKS; off <<= 1) {
    int u = (t >= off) ? sm[t - off] : 0;
    __syncthreads();
    sm[t] += u;
    __syncthreads();
  }
  blockSums[t] = sm[t] - v;  // exclusive
}

__global__ __launch_bounds__(256) void add_offsets(int* __restrict__ start,
                                                   const int* __restrict__ blockSums) {
  int i = blockIdx.x * 256 + threadIdx.x;
  start[i] += blockSums[blockIdx.x];
  if (i == 0) start[NK] = E_EDGES;
}

__global__ void scatter_edges(const int* __restrict__ src, const int* __restrict__ dst,
                              const int* __restrict__ et, const int* __restrict__ start,
                              int* __restrict__ cursor, int* __restrict__ recs, int E) {
  int e = blockIdx.x * blockDim.x + threadIdx.x;
  if (e >= E) return;
  int key = dst[e] * R_REL + et[e];
  int pos = start[key] + atomicAdd(&cursor[key], 1);
  recs[pos] = src[e] | (et[e] << 16);
}

// ---------------------------------------------------------------------------
// seg_softmax: one thread per (dst,rel) segment -> per-edge coef[h*E + pos].
// ---------------------------------------------------------------------------
__global__ __launch_bounds__(256) void seg_softmax(
    const int* __restrict__ rstart, const int* __restrict__ recs,
    const float* __restrict__ ai, const float* __restrict__ aj,
    float* __restrict__ coef) {
  int seg = blockIdx.x * blockDim.x + threadIdx.x;
  if (seg >= NK) return;
  int p0 = rstart[seg], p1 = rstart[seg + 1];
  if (p0 == p1) return;
  int d = seg / R_REL, r = seg - d * R_REL;
  float4 av = *reinterpret_cast<const float4*>(ai + ((long)r * N_NODES + d) * 4);
  float degf = (float)(rstart[(d + 1) * R_REL] - rstart[d * R_REL]);
  float m[4] = {-INFINITY, -INFINITY, -INFINITY, -INFINITY};
  float sum[4] = {0.f, 0.f, 0.f, 0.f};
  for (int p = p0; p < p1; ++p) {
    int s = recs[p] & 0xFFFF;
    float4 bv = *reinterpret_cast<const float4*>(aj + ((long)r * N_NODES + s) * 4);
    float al[4] = {lrelu(av.x + bv.x), lrelu(av.y + bv.y),
                   lrelu(av.z + bv.z), lrelu(av.w + bv.w)};
#pragma unroll
    for (int h = 0; h < 4; ++h) {
      float nm = fmaxf(m[h], al[h]);
      sum[h] = sum[h] * __expf(m[h] - nm) + __expf(al[h] - nm);
      m[h] = nm;
    }
  }
  float rs[4];
#pragma unroll
  for (int h = 0; h < 4; ++h) rs[h] = degf / (sum[h] + 1e-16f);
  for (int p = p0; p < p1; ++p) {
    int s = recs[p] & 0xFFFF;
    float4 bv = *reinterpret_cast<const float4*>(aj + ((long)r * N_NODES + s) * 4);
    float al[4] = {lrelu(av.x + bv.x), lrelu(av.y + bv.y),
                   lrelu(av.z + bv.z), lrelu(av.w + bv.w)};
#pragma unroll
    for (int h = 0; h < 4; ++h)
      coef[(long)h * E_EDGES + p] = __expf(al[h] - m[h]) * rs[h];
  }
}

// ---------------------------------------------------------------------------
// fused_agg: one wave per dst node; pure gather-accumulate over xwb.
// lane handles channels {2*lane, 2*lane+1}; head = lane>>4 (output channel).
// ---------------------------------------------------------------------------
__global__ __launch_bounds__(256) void fused_agg(
    const int* __restrict__ rstart, const int* __restrict__ recs,
    const float* __restrict__ coef, const ushort_t* __restrict__ xwb,
    ushort_t* __restrict__ xb_out, float* __restrict__ fout) {
  const int wave = threadIdx.x >> 6, lane = threadIdx.x & 63;
  const int d = blockIdx.x * 4 + wave;
  const int s0 = rstart[d * R_REL], s1 = rstart[(d + 1) * R_REL];
  const float* cfp = coef + (long)(lane >> 4) * E_EDGES;
  float acc0 = 0.f, acc1 = 0.f;
#pragma unroll 4
  for (int pos = s0; pos < s1; ++pos) {
    int rec = recs[pos];
    float cf = cfp[pos];
    int s = rec & 0xFFFF, r = rec >> 16;
    unsigned int pk = *reinterpret_cast<const unsigned int*>(
        xwb + (((long)r * N_NODES + s) << 7) + 2 * lane);
    acc0 += cf * b2f((ushort_t)(pk & 0xFFFF));
    acc1 += cf * b2f((ushort_t)(pk >> 16));
  }
  if (xb_out) {
    unsigned int po = ((unsigned int)f2b(acc1) << 16) | (unsigned int)f2b(acc0);
    *reinterpret_cast<unsigned int*>(xb_out + ((long)d << 7) + 2 * lane) = po;
  }
  if (fout) {
    *reinterpret_cast<float2*>(fout + ((long)d << 7) + 2 * lane) =
        make_float2(acc0, acc1);
  }
}

__global__ void final_linear(const float* __restrict__ x, const float* __restrict__ Wc,
                             const float* __restrict__ bc, float* __restrict__ out) {
  __shared__ float wcs[4 * 384];
  for (int t = threadIdx.x; t < 4 * 384; t += blockDim.x) wcs[t] = Wc[t];
  __syncthreads();
  int i = blockIdx.x * blockDim.x + threadIdx.x;
  if (i >= NPV) return;
  float acc[4] = {0.f, 0.f, 0.f, 0.f};
  for (int v = 0; v < 3; ++v) {
    const float* xr = x + ((long)v * NPV + i) * 128;
    for (int c = 0; c < 128; c += 4) {
      float4 xv = *reinterpret_cast<const float4*>(xr + c);
#pragma unroll
      for (int l = 0; l < 4; ++l) {
        const float* w = wcs + l * 384 + v * 128 + c;
        acc[l] += xv.x * w[0] + xv.y * w[1] + xv.z * w[2] + xv.w * w[3];
      }
    }
  }
#pragma unroll
  for (int l = 0; l < 4; ++l) out[(long)i * 4 + l] = acc[l] + bc[l];
}

// ---------------------------------------------------------------------------
static void run_layer(const ushort_t* xb_in, ushort_t* xb_out, float* fout,
                      const float* basis, const float* comp, const float* q,
                      const float* k, ushort_t* xwb, ushort_t* wTb, float* ai,
                      float* aj, float* coef, const int* rstart, const int* recs,
                      hipStream_t stream) {
  compute_wT_b<<<(R_REL * 128 * 128 + 255) / 256, 256, 0, stream>>>(comp, basis, wTb);
  mfma_gemm_nt<false, true><<<dim3(N_NODES / 64, 1, R_REL), 256, 0, stream>>>(
      xb_in, wTb, nullptr, xwb, 128, 128, 128 * 128, (long)N_NODES * 128,
      q, k, ai, aj);
  seg_softmax<<<(NK + 255) / 256, 256, 0, stream>>>(rstart, recs, ai, aj, coef);
  fused_agg<<<N_NODES / 4, 256, 0, stream>>>(rstart, recs, coef, xwb, xb_out, fout);
}

extern "C" void kernel_launch(void* const* d_in, const int* in_sizes, int n_in,
                              void* d_out, int out_size, void* d_ws, size_t ws_size,
                              hipStream_t stream) {
  const float* x0 = (const float*)d_in[0];
  const float* x1 = (const float*)d_in[1];
  const float* x2 = (const float*)d_in[2];
  const int* edge_index = (const int*)d_in[3];
  const int* edge_type = (const int*)d_in[4];
  const float* Wp0 = (const float*)d_in[5];
  const float* bp0 = (const float*)d_in[6];
  const float* Wp1 = (const float*)d_in[7];
  const float* bp1 = (const float*)d_in[8];
  const float* Wp2 = (const float*)d_in[9];
  const float* bp2 = (const float*)d_in[10];
  const float* basis0 = (const float*)d_in[11];
  const float* comp0 = (const float*)d_in[12];
  const float* q0 = (const float*)d_in[13];
  const float* k0 = (const float*)d_in[14];
  const float* basis1 = (const float*)d_in[15];
  const float* comp1 = (const float*)d_in[16];
  const float* q1 = (const float*)d_in[17];
  const float* k1 = (const float*)d_in[18];
  const float* Wc = (const float*)d_in[19];
  const float* bc = (const float*)d_in[20];

  const int* src = edge_index;
  const int* dst = edge_index + E_EDGES;

  // ---- workspace layout ----
  char* w = (char*)d_ws;
  auto alloc = [&](long bytes) {
    char* p = w;
    w += (bytes + 255) & ~255L;
    return p;
  };
  ushort_t* xbA  = (ushort_t*)alloc((long)NX * 2);
  ushort_t* xbB  = (ushort_t*)alloc((long)NX * 2);
  ushort_t* xwb  = (ushort_t*)alloc((long)R_REL * NX * 2);
  ushort_t* wTb  = (ushort_t*)alloc((long)R_REL * 128 * 128 * 2);
  float* Cacc    = (float*)alloc((long)NX * 4);
  float* ai      = (float*)alloc((long)R_REL * N_NODES * 4 * 4);
  float* aj      = (float*)alloc((long)R_REL * N_NODES * 4 * 4);
  float* coef    = (float*)alloc((long)HEADS * E_EDGES * 4);
  int* cnt       = (int*)alloc((long)NK * 4);
  int* cursor    = (int*)alloc((long)NK * 4);
  int* rstart    = (int*)alloc((long)(NK + 1) * 4);
  int* recs      = (int*)alloc((long)E_EDGES * 4);
  int* blockSums = (int*)alloc((long)SCAN_BLOCKS * 4);

  // ---- projections: one fused dispatch, f32 in -> bf16 xbA out
  gemm_proj<<<dim3(NPV / 64, 3), 256, 0, stream>>>(
      x0, x1, x2, Wp0, Wp1, Wp2, bp0, bp1, bp2, xbA);

  // ---- CSR build keyed by (dst,rel) (once; shared by both layers)
  fill_f32<<<96, 256, 0, stream>>>((float*)cnt, 2L * NK, 0.f);  // cnt+cursor adjacent
  count_key<<<E_EDGES / 256, 256, 0, stream>>>(dst, edge_type, cnt, E_EDGES);
  scan_block<<<SCAN_BLOCKS, 256, 0, stream>>>(cnt, rstart, blockSums);
  scan_sums<<<1, SCAN_BLOCKS, 0, stream>>>(blockSums);
  add_offsets<<<SCAN_BLOCKS, 256, 0, stream>>>(rstart, blockSums);
  scatter_edges<<<E_EDGES / 256, 256, 0, stream>>>(src, dst, edge_type, rstart,
                                                   cursor, recs, E_EDGES);

  // ---- layer 0: xbA -> xbB (bf16)
  run_layer(xbA, xbB, nullptr, basis0, comp0, q0, k0, xwb, wTb, ai, aj, coef,
            rstart, recs, stream);
  // ---- layer 1: xbB -> Cacc (f32 only)
  run_layer(xbB, nullptr, Cacc, basis1, comp1, q1, k1, xwb, wTb, ai, aj, coef,
            rstart, recs, stream);

  final_linear<<<(NPV + 255) / 256, 256, 0, stream>>>(Cacc, Wc, bc, (float*)d_out);
}

// Round 9
// 278.511 us; speedup vs baseline: 4.7179x; 1.1339x over previous
//
#include <hip/hip_runtime.h>
#include <hip/hip_bf16.h>
#include <math.h>

#define N_NODES 24576
#define NPV 8192
#define E_EDGES 393216
#define R_REL 6
#define B_BASES 8
#define HEADS 4
#define NEG_SLOPE 0.2f
#define NX (N_NODES * 128)
#define NK (N_NODES * R_REL)
#define SCAN_BLOCKS (NK / 256)  // 576

typedef unsigned short ushort_t;
using short8 = __attribute__((ext_vector_type(8))) short;
using f32x4 = __attribute__((ext_vector_type(4))) float;

__device__ __forceinline__ float lrelu(float x) { return x >= 0.f ? x : NEG_SLOPE * x; }
__device__ __forceinline__ float b2f(ushort_t u) {
  unsigned int v = ((unsigned int)u) << 16;
  float f;
  __builtin_memcpy(&f, &v, 4);
  return f;
}
__device__ __forceinline__ ushort_t f2b(float f) {
  __hip_bfloat16 h = __float2bfloat16(f);
  ushort_t u;
  __builtin_memcpy(&u, &h, 2);
  return u;
}

// ---------------------------------------------------------------------------
// gemm_proj_split: split-K projection, NO atomics.
// grid (NPV/64, 9): z -> (view, K-chunk). Partial f32 tiles to Ppart[z].
// f32->bf16 conversion fused into reg staging (no padded copies).
// ---------------------------------------------------------------------------
__global__ __launch_bounds__(256) void gemm_proj_split(
    const float* __restrict__ x0, const float* __restrict__ x1,
    const float* __restrict__ x2, const float* __restrict__ w0,
    const float* __restrict__ w1, const float* __restrict__ w2,
    float* __restrict__ Ppart) {
  __shared__ __align__(16) ushort_t As[64 * 64];
  __shared__ __align__(16) ushort_t Ws[128 * 64];
  const int z = blockIdx.y;
  const float* A;
  const float* W;
  int K, kstart, ksteps;
  if (z < 4)      { A = x0; W = w0; K = 2000; kstart = z * 512;       ksteps = 8; }
  else if (z < 7) { A = x1; W = w1; K = 1500; kstart = (z - 4) * 512; ksteps = 8; }
  else            { A = x2; W = w2; K = 500;  kstart = (z - 7) * 256; ksteps = 4; }
  const int tid = threadIdx.x;
  const int wave = tid >> 6, lane = tid & 63;
  const int m0 = blockIdx.x * 64;

  f32x4 acc[8];
#pragma unroll
  for (int n = 0; n < 8; ++n) acc[n] = (f32x4){0.f, 0.f, 0.f, 0.f};

  for (int step = 0; step < ksteps; ++step) {
    const int k0 = kstart + (step << 6);
    __syncthreads();
    // stage A tile (64 rows x 64 k), XOR-swizzled chunk order
#pragma unroll
    for (int q = 0; q < 2; ++q) {
      int s = q * 256 + tid;
      int row = s >> 3, ch = s & 7;
      int gk = k0 + ((ch ^ (row & 7)) << 3);
      const float* gp = A + (long)(m0 + row) * K + gk;
      short8 o;
      if (gk + 8 <= K) {
        float4 a = *reinterpret_cast<const float4*>(gp);
        float4 b = *reinterpret_cast<const float4*>(gp + 4);
        o[0] = (short)f2b(a.x); o[1] = (short)f2b(a.y);
        o[2] = (short)f2b(a.z); o[3] = (short)f2b(a.w);
        o[4] = (short)f2b(b.x); o[5] = (short)f2b(b.y);
        o[6] = (short)f2b(b.z); o[7] = (short)f2b(b.w);
      } else {
#pragma unroll
        for (int j = 0; j < 8; ++j)
          o[j] = (gk + j < K) ? (short)f2b(gp[j]) : (short)0;
      }
      *reinterpret_cast<short8*>(As + s * 8) = o;
    }
    // stage W tile (128 rows x 64 k)
#pragma unroll
    for (int q = 0; q < 4; ++q) {
      int s = q * 256 + tid;
      int row = s >> 3, ch = s & 7;
      int gk = k0 + ((ch ^ (row & 7)) << 3);
      const float* gp = W + (long)row * K + gk;
      short8 o;
      if (gk + 8 <= K) {
        float4 a = *reinterpret_cast<const float4*>(gp);
        float4 b = *reinterpret_cast<const float4*>(gp + 4);
        o[0] = (short)f2b(a.x); o[1] = (short)f2b(a.y);
        o[2] = (short)f2b(a.z); o[3] = (short)f2b(a.w);
        o[4] = (short)f2b(b.x); o[5] = (short)f2b(b.y);
        o[6] = (short)f2b(b.z); o[7] = (short)f2b(b.w);
      } else {
#pragma unroll
        for (int j = 0; j < 8; ++j)
          o[j] = (gk + j < K) ? (short)f2b(gp[j]) : (short)0;
      }
      *reinterpret_cast<short8*>(Ws + s * 8) = o;
    }
    __syncthreads();
#pragma unroll
    for (int kk = 0; kk < 2; ++kk) {
      const int arow = wave * 16 + (lane & 15);
      const int ach = (kk * 4 + (lane >> 4)) ^ (arow & 7);
      short8 afrag = *reinterpret_cast<const short8*>(As + arow * 64 + ach * 8);
#pragma unroll
      for (int n = 0; n < 8; ++n) {
        const int brow = n * 16 + (lane & 15);
        const int bch = (kk * 4 + (lane >> 4)) ^ (brow & 7);
        short8 bfrag = *reinterpret_cast<const short8*>(Ws + brow * 64 + bch * 8);
        acc[n] = __builtin_amdgcn_mfma_f32_16x16x32_bf16(afrag, bfrag, acc[n], 0, 0, 0);
      }
    }
  }
  const int rbase = m0 + wave * 16 + (lane >> 4) * 4;
  const int cb = lane & 15;
  float* out = Ppart + (long)z * NPV * 128;
#pragma unroll
  for (int n = 0; n < 8; ++n) {
    int col = n * 16 + cb;
#pragma unroll
    for (int r = 0; r < 4; ++r)
      out[(long)(rbase + r) * 128 + col] = acc[n][r];
  }
}

// proj_reduce: xb[n, c] = bf16(relu(sum_z Ppart[z][m, c] + bias_v[c]))
__global__ __launch_bounds__(256) void proj_reduce(
    const float* __restrict__ Ppart, const float* __restrict__ b0,
    const float* __restrict__ b1, const float* __restrict__ b2,
    ushort_t* __restrict__ xb) {
  int t = blockIdx.x * blockDim.x + threadIdx.x;
  if (t >= N_NODES * 16) return;
  int n = t >> 4, c0 = (t & 15) * 8;
  int v = n >> 13, m = n & (NPV - 1);
  int zb, zc;
  const float* bias;
  if (v == 0) { zb = 0; zc = 4; bias = b0; }
  else if (v == 1) { zb = 4; zc = 3; bias = b1; }
  else { zb = 7; zc = 2; bias = b2; }
  float s[8];
#pragma unroll
  for (int j = 0; j < 8; ++j) s[j] = bias[c0 + j];
  for (int zz = 0; zz < zc; ++zz) {
    const float* p = Ppart + ((long)(zb + zz) * NPV + m) * 128 + c0;
    float4 a = *reinterpret_cast<const float4*>(p);
    float4 b = *reinterpret_cast<const float4*>(p + 4);
    s[0] += a.x; s[1] += a.y; s[2] += a.z; s[3] += a.w;
    s[4] += b.x; s[5] += b.y; s[6] += b.z; s[7] += b.w;
  }
  short8 o;
#pragma unroll
  for (int j = 0; j < 8; ++j) {
    float vv = s[j] > 0.f ? s[j] : 0.f;
    o[j] = (short)f2b(vv);
  }
  *reinterpret_cast<short8*>(xb + (long)n * 128 + c0) = o;
}

// ---------------------------------------------------------------------------
// xw GEMM: xwb[r][M,128] = bf16(xb[M,128] @ w_r[128,128]^T), plus fused
// attention tables ai/aj = (xb@w_r) @ q / @ k from the f32 accumulators.
// ---------------------------------------------------------------------------
template <bool SPLIT, bool TABLES>
__global__ __launch_bounds__(256) void mfma_gemm_nt(
    const ushort_t* __restrict__ A, const ushort_t* __restrict__ W,
    float* __restrict__ Cacc, ushort_t* __restrict__ Cb,
    int Kp, int kChunk, long strideW, long strideCz,
    const float* __restrict__ qt, const float* __restrict__ kt,
    float* __restrict__ ai, float* __restrict__ aj) {
  __shared__ __align__(16) ushort_t As[64 * 64];
  __shared__ __align__(16) ushort_t Ws[128 * 64];
  const int tid = threadIdx.x;
  const int wave = tid >> 6, lane = tid & 63;
  const int m0 = blockIdx.x * 64;
  const int kbase = blockIdx.y * kChunk;
  const ushort_t* Wz = W + (long)blockIdx.z * strideW;

  f32x4 acc[8];
#pragma unroll
  for (int n = 0; n < 8; ++n) acc[n] = (f32x4){0.f, 0.f, 0.f, 0.f};

  for (int k0 = kbase; k0 < kbase + kChunk; k0 += 64) {
    __syncthreads();
#pragma unroll
    for (int q = 0; q < 2; ++q) {
      int s = q * 256 + tid;
      int row = s >> 3, ch = s & 7;
      int sch = ch ^ (row & 7);
      const ushort_t* g = A + (long)(m0 + row) * Kp + k0 + sch * 8;
      __builtin_amdgcn_global_load_lds(
          (const __attribute__((address_space(1))) unsigned int*)g,
          (__attribute__((address_space(3))) unsigned int*)(As + s * 8), 16, 0, 0);
    }
#pragma unroll
    for (int q = 0; q < 4; ++q) {
      int s = q * 256 + tid;
      int row = s >> 3, ch = s & 7;
      int sch = ch ^ (row & 7);
      const ushort_t* g = Wz + (long)row * Kp + k0 + sch * 8;
      __builtin_amdgcn_global_load_lds(
          (const __attribute__((address_space(1))) unsigned int*)g,
          (__attribute__((address_space(3))) unsigned int*)(Ws + s * 8), 16, 0, 0);
    }
    __syncthreads();
#pragma unroll
    for (int kk = 0; kk < 2; ++kk) {
      const int arow = wave * 16 + (lane & 15);
      const int ach = (kk * 4 + (lane >> 4)) ^ (arow & 7);
      short8 afrag = *reinterpret_cast<const short8*>(As + arow * 64 + ach * 8);
#pragma unroll
      for (int n = 0; n < 8; ++n) {
        const int brow = n * 16 + (lane & 15);
        const int bch = (kk * 4 + (lane >> 4)) ^ (brow & 7);
        short8 bfrag = *reinterpret_cast<const short8*>(Ws + brow * 64 + bch * 8);
        acc[n] = __builtin_amdgcn_mfma_f32_16x16x32_bf16(afrag, bfrag, acc[n], 0, 0, 0);
      }
    }
  }
  const int rbase = m0 + wave * 16 + (lane >> 4) * 4;
  const int cb = lane & 15;
  if (SPLIT) {
#pragma unroll
    for (int n = 0; n < 8; ++n) {
      int col = n * 16 + cb;
#pragma unroll
      for (int r = 0; r < 4; ++r)
        atomicAdd(&Cacc[(long)(rbase + r) * 128 + col], acc[n][r]);
    }
  } else {
    ushort_t* Cz = Cb + (long)blockIdx.z * strideCz;
#pragma unroll
    for (int n = 0; n < 8; ++n) {
      int col = n * 16 + cb;
#pragma unroll
      for (int r = 0; r < 4; ++r)
        Cz[(long)(rbase + r) * 128 + col] = f2b(acc[n][r]);
    }
  }
  if (TABLES) {
    float aq[4][4], ak[4][4];
#pragma unroll
    for (int r = 0; r < 4; ++r)
#pragma unroll
      for (int h = 0; h < 4; ++h) { aq[r][h] = 0.f; ak[r][h] = 0.f; }
#pragma unroll
    for (int n = 0; n < 8; ++n) {
      int col = n * 16 + cb;
      float4 qv = *reinterpret_cast<const float4*>(qt + (long)col * 4);
      float4 kv = *reinterpret_cast<const float4*>(kt + (long)col * 4);
#pragma unroll
      for (int r = 0; r < 4; ++r) {
        float x = acc[n][r];
        aq[r][0] += x * qv.x; aq[r][1] += x * qv.y;
        aq[r][2] += x * qv.z; aq[r][3] += x * qv.w;
        ak[r][0] += x * kv.x; ak[r][1] += x * kv.y;
        ak[r][2] += x * kv.z; ak[r][3] += x * kv.w;
      }
    }
#pragma unroll
    for (int mk = 1; mk < 16; mk <<= 1) {
#pragma unroll
      for (int r = 0; r < 4; ++r)
#pragma unroll
        for (int h = 0; h < 4; ++h) {
          aq[r][h] += __shfl_xor(aq[r][h], mk);
          ak[r][h] += __shfl_xor(ak[r][h], mk);
        }
    }
    int rr = cb >> 2, hh = cb & 3;
    long row = (long)blockIdx.z * N_NODES + rbase + rr;
    ai[row * 4 + hh] = aq[rr][hh];
    aj[row * 4 + hh] = ak[rr][hh];
  }
}

// ---------------------------------------------------------------------------
__global__ void fill_f32(float* __restrict__ p, long n, float v) {
  long i = blockIdx.x * (long)blockDim.x + threadIdx.x;
  long stride = (long)gridDim.x * blockDim.x;
  for (; i < n; i += stride) p[i] = v;
}

// wTb[r,o,i] = bf16( sum_b comp[r,b] * basis[b,i,o] )
__global__ void compute_wT_b(const float* __restrict__ comp,
                             const float* __restrict__ basis,
                             ushort_t* __restrict__ wTb) {
  int idx = blockIdx.x * blockDim.x + threadIdx.x;
  if (idx >= R_REL * 128 * 128) return;
  int r = idx >> 14;
  int rem = idx & 16383;
  int o = rem >> 7;
  int i = rem & 127;
  float s = 0.f;
#pragma unroll
  for (int b = 0; b < B_BASES; ++b)
    s += comp[r * B_BASES + b] * basis[((b << 7) + i) * 128 + o];
  wTb[((long)(r << 7) + o) * 128 + i] = f2b(s);
}

// ---------------------------------------------------------------------------
// CSR build keyed by (dst*6 + rel): count -> hierarchical scan -> scatter.
// ---------------------------------------------------------------------------
__global__ void count_key(const int* __restrict__ dst, const int* __restrict__ et,
                          int* __restrict__ cnt, int E) {
  int e = blockIdx.x * blockDim.x + threadIdx.x;
  if (e < E) atomicAdd(&cnt[dst[e] * R_REL + et[e]], 1);
}

__global__ __launch_bounds__(256) void scan_block(const int* __restrict__ cnt,
                                                  int* __restrict__ start,
                                                  int* __restrict__ blockSums) {
  __shared__ int sm[256];
  const int t = threadIdx.x;
  const int i = blockIdx.x * 256 + t;
  int v = cnt[i];
  sm[t] = v;
  __syncthreads();
  for (int off = 1; off < 256; off <<= 1) {
    int u = (t >= off) ? sm[t - off] : 0;
    __syncthreads();
    sm[t] += u;
    __syncthreads();
  }
  start[i] = sm[t] - v;  // exclusive
  if (t == 255) blockSums[blockIdx.x] = sm[255];
}

__global__ __launch_bounds__(SCAN_BLOCKS) void scan_sums(int* __restrict__ blockSums) {
  __shared__ int sm[SCAN_BLOCKS];
  const int t = threadIdx.x;
  int v = blockSums[t];
  sm[t] = v;
  __syncthreads();
  for (int off = 1; off < SCAN_BLOCKS; off <<= 1) {
    int u = (t >= off) ? sm[t - off] : 0;
    __syncthreads();
    sm[t] += u;
    __syncthreads();
  }
  blockSums[t] = sm[t] - v;  // exclusive
}

__global__ __launch_bounds__(256) void add_offsets(int* __restrict__ start,
                                                   const int* __restrict__ blockSums) {
  int i = blockIdx.x * 256 + threadIdx.x;
  start[i] += blockSums[blockIdx.x];
  if (i == 0) start[NK] = E_EDGES;
}

__global__ void scatter_edges(const int* __restrict__ src, const int* __restrict__ dst,
                              const int* __restrict__ et, const int* __restrict__ start,
                              int* __restrict__ cursor, int* __restrict__ recs, int E) {
  int e = blockIdx.x * blockDim.x + threadIdx.x;
  if (e >= E) return;
  int key = dst[e] * R_REL + et[e];
  int pos = start[key] + atomicAdd(&cursor[key], 1);
  recs[pos] = src[e] | (et[e] << 16);
}

// ---------------------------------------------------------------------------
// seg_softmax: one thread per (dst,rel) segment -> per-edge coef[h*E + pos].
// ---------------------------------------------------------------------------
__global__ __launch_bounds__(256) void seg_softmax(
    const int* __restrict__ rstart, const int* __restrict__ recs,
    const float* __restrict__ ai, const float* __restrict__ aj,
    float* __restrict__ coef) {
  int seg = blockIdx.x * blockDim.x + threadIdx.x;
  if (seg >= NK) return;
  int p0 = rstart[seg], p1 = rstart[seg + 1];
  if (p0 == p1) return;
  int d = seg / R_REL, r = seg - d * R_REL;
  float4 av = *reinterpret_cast<const float4*>(ai + ((long)r * N_NODES + d) * 4);
  float degf = (float)(rstart[(d + 1) * R_REL] - rstart[d * R_REL]);
  float m[4] = {-INFINITY, -INFINITY, -INFINITY, -INFINITY};
  float sum[4] = {0.f, 0.f, 0.f, 0.f};
  for (int p = p0; p < p1; ++p) {
    int s = recs[p] & 0xFFFF;
    float4 bv = *reinterpret_cast<const float4*>(aj + ((long)r * N_NODES + s) * 4);
    float al[4] = {lrelu(av.x + bv.x), lrelu(av.y + bv.y),
                   lrelu(av.z + bv.z), lrelu(av.w + bv.w)};
#pragma unroll
    for (int h = 0; h < 4; ++h) {
      float nm = fmaxf(m[h], al[h]);
      sum[h] = sum[h] * __expf(m[h] - nm) + __expf(al[h] - nm);
      m[h] = nm;
    }
  }
  float rs[4];
#pragma unroll
  for (int h = 0; h < 4; ++h) rs[h] = degf / (sum[h] + 1e-16f);
  for (int p = p0; p < p1; ++p) {
    int s = recs[p] & 0xFFFF;
    float4 bv = *reinterpret_cast<const float4*>(aj + ((long)r * N_NODES + s) * 4);
    float al[4] = {lrelu(av.x + bv.x), lrelu(av.y + bv.y),
                   lrelu(av.z + bv.z), lrelu(av.w + bv.w)};
#pragma unroll
    for (int h = 0; h < 4; ++h)
      coef[(long)h * E_EDGES + p] = __expf(al[h] - m[h]) * rs[h];
  }
}

// ---------------------------------------------------------------------------
// fused_agg: one wave per dst node; pure gather-accumulate over xwb.
// ---------------------------------------------------------------------------
__global__ __launch_bounds__(256) void fused_agg(
    const int* __restrict__ rstart, const int* __restrict__ recs,
    const float* __restrict__ coef, const ushort_t* __restrict__ xwb,
    ushort_t* __restrict__ xb_out, float* __restrict__ fout) {
  const int wave = threadIdx.x >> 6, lane = threadIdx.x & 63;
  const int d = blockIdx.x * 4 + wave;
  const int s0 = rstart[d * R_REL], s1 = rstart[(d + 1) * R_REL];
  const float* cfp = coef + (long)(lane >> 4) * E_EDGES;
  float acc0 = 0.f, acc1 = 0.f;
#pragma unroll 4
  for (int pos = s0; pos < s1; ++pos) {
    int rec = recs[pos];
    float cf = cfp[pos];
    int s = rec & 0xFFFF, r = rec >> 16;
    unsigned int pk = *reinterpret_cast<const unsigned int*>(
        xwb + (((long)r * N_NODES + s) << 7) + 2 * lane);
    acc0 += cf * b2f((ushort_t)(pk & 0xFFFF));
    acc1 += cf * b2f((ushort_t)(pk >> 16));
  }
  if (xb_out) {
    unsigned int po = ((unsigned int)f2b(acc1) << 16) | (unsigned int)f2b(acc0);
    *reinterpret_cast<unsigned int*>(xb_out + ((long)d << 7) + 2 * lane) = po;
  }
  if (fout) {
    *reinterpret_cast<float2*>(fout + ((long)d << 7) + 2 * lane) =
        make_float2(acc0, acc1);
  }
}

__global__ void final_linear(const float* __restrict__ x, const float* __restrict__ Wc,
                             const float* __restrict__ bc, float* __restrict__ out) {
  __shared__ float wcs[4 * 384];
  for (int t = threadIdx.x; t < 4 * 384; t += blockDim.x) wcs[t] = Wc[t];
  __syncthreads();
  int i = blockIdx.x * blockDim.x + threadIdx.x;
  if (i >= NPV) return;
  float acc[4] = {0.f, 0.f, 0.f, 0.f};
  for (int v = 0; v < 3; ++v) {
    const float* xr = x + ((long)v * NPV + i) * 128;
    for (int c = 0; c < 128; c += 4) {
      float4 xv = *reinterpret_cast<const float4*>(xr + c);
#pragma unroll
      for (int l = 0; l < 4; ++l) {
        const float* w = wcs + l * 384 + v * 128 + c;
        acc[l] += xv.x * w[0] + xv.y * w[1] + xv.z * w[2] + xv.w * w[3];
      }
    }
  }
#pragma unroll
  for (int l = 0; l < 4; ++l) out[(long)i * 4 + l] = acc[l] + bc[l];
}

// ---------------------------------------------------------------------------
static void run_layer(const ushort_t* xb_in, ushort_t* xb_out, float* fout,
                      const float* basis, const float* comp, const float* q,
                      const float* k, ushort_t* xwb, ushort_t* wTb, float* ai,
                      float* aj, float* coef, const int* rstart, const int* recs,
                      hipStream_t stream) {
  compute_wT_b<<<(R_REL * 128 * 128 + 255) / 256, 256, 0, stream>>>(comp, basis, wTb);
  mfma_gemm_nt<false, true><<<dim3(N_NODES / 64, 1, R_REL), 256, 0, stream>>>(
      xb_in, wTb, nullptr, xwb, 128, 128, 128 * 128, (long)N_NODES * 128,
      q, k, ai, aj);
  seg_softmax<<<(NK + 255) / 256, 256, 0, stream>>>(rstart, recs, ai, aj, coef);
  fused_agg<<<N_NODES / 4, 256, 0, stream>>>(rstart, recs, coef, xwb, xb_out, fout);
}

extern "C" void kernel_launch(void* const* d_in, const int* in_sizes, int n_in,
                              void* d_out, int out_size, void* d_ws, size_t ws_size,
                              hipStream_t stream) {
  const float* x0 = (const float*)d_in[0];
  const float* x1 = (const float*)d_in[1];
  const float* x2 = (const float*)d_in[2];
  const int* edge_index = (const int*)d_in[3];
  const int* edge_type = (const int*)d_in[4];
  const float* Wp0 = (const float*)d_in[5];
  const float* bp0 = (const float*)d_in[6];
  const float* Wp1 = (const float*)d_in[7];
  const float* bp1 = (const float*)d_in[8];
  const float* Wp2 = (const float*)d_in[9];
  const float* bp2 = (const float*)d_in[10];
  const float* basis0 = (const float*)d_in[11];
  const float* comp0 = (const float*)d_in[12];
  const float* q0 = (const float*)d_in[13];
  const float* k0 = (const float*)d_in[14];
  const float* basis1 = (const float*)d_in[15];
  const float* comp1 = (const float*)d_in[16];
  const float* q1 = (const float*)d_in[17];
  const float* k1 = (const float*)d_in[18];
  const float* Wc = (const float*)d_in[19];
  const float* bc = (const float*)d_in[20];

  const int* src = edge_index;
  const int* dst = edge_index + E_EDGES;

  // ---- workspace layout ----
  char* w = (char*)d_ws;
  auto alloc = [&](long bytes) {
    char* p = w;
    w += (bytes + 255) & ~255L;
    return p;
  };
  ushort_t* xbA  = (ushort_t*)alloc((long)NX * 2);
  ushort_t* xbB  = (ushort_t*)alloc((long)NX * 2);
  ushort_t* xwb  = (ushort_t*)alloc(9L * NPV * 128 * 4);  // aliased: Ppart (f32, 37.7MB) then xwb (bf16, 37.7MB)
  ushort_t* wTb  = (ushort_t*)alloc((long)R_REL * 128 * 128 * 2);
  float* Cacc    = (float*)alloc((long)NX * 4);
  float* ai      = (float*)alloc((long)R_REL * N_NODES * 4 * 4);
  float* aj      = (float*)alloc((long)R_REL * N_NODES * 4 * 4);
  float* coef    = (float*)alloc((long)HEADS * E_EDGES * 4);
  int* cnt       = (int*)alloc((long)NK * 4);
  int* cursor    = (int*)alloc((long)NK * 4);
  int* rstart    = (int*)alloc((long)(NK + 1) * 4);
  int* recs      = (int*)alloc((long)E_EDGES * 4);
  int* blockSums = (int*)alloc((long)SCAN_BLOCKS * 4);
  float* Ppart   = (float*)xwb;  // alias: projection partials die before xwb is written

  // ---- projections: split-K (no atomics) -> partials -> reduce+bias+relu
  gemm_proj_split<<<dim3(NPV / 64, 9), 256, 0, stream>>>(
      x0, x1, x2, Wp0, Wp1, Wp2, Ppart);
  proj_reduce<<<(N_NODES * 16 + 255) / 256, 256, 0, stream>>>(
      Ppart, bp0, bp1, bp2, xbA);

  // ---- CSR build keyed by (dst,rel) (once; shared by both layers)
  fill_f32<<<96, 256, 0, stream>>>((float*)cnt, 2L * NK, 0.f);  // cnt+cursor adjacent
  count_key<<<E_EDGES / 256, 256, 0, stream>>>(dst, edge_type, cnt, E_EDGES);
  scan_block<<<SCAN_BLOCKS, 256, 0, stream>>>(cnt, rstart, blockSums);
  scan_sums<<<1, SCAN_BLOCKS, 0, stream>>>(blockSums);
  add_offsets<<<SCAN_BLOCKS, 256, 0, stream>>>(rstart, blockSums);
  scatter_edges<<<E_EDGES / 256, 256, 0, stream>>>(src, dst, edge_type, rstart,
                                                   cursor, recs, E_EDGES);

  // ---- layer 0: xbA -> xbB (bf16)
  run_layer(xbA, xbB, nullptr, basis0, comp0, q0, k0, xwb, wTb, ai, aj, coef,
            rstart, recs, stream);
  // ---- layer 1: xbB -> Cacc (f32 only)
  run_layer(xbB, nullptr, Cacc, basis1, comp1, q1, k1, xwb, wTb, ai, aj, coef,
            rstart, recs, stream);

  final_linear<<<(NPV + 255) / 256, 256, 0, stream>>>(Cacc, Wc, bc, (float*)d_out);
}

// Round 10
// 278.041 us; speedup vs baseline: 4.7259x; 1.0017x over previous
//
#include <hip/hip_runtime.h>
#include <hip/hip_bf16.h>
#include <math.h>

#define N_NODES 24576
#define NPV 8192
#define E_EDGES 393216
#define R_REL 6
#define B_BASES 8
#define HEADS 4
#define NEG_SLOPE 0.2f
#define NX (N_NODES * 128)
#define NK (N_NODES * R_REL)
#define SCAN_BLOCKS (NK / 256)  // 576

typedef unsigned short ushort_t;
using short8 = __attribute__((ext_vector_type(8))) short;
using f32x4 = __attribute__((ext_vector_type(4))) float;

__device__ __forceinline__ float lrelu(float x) { return x >= 0.f ? x : NEG_SLOPE * x; }
__device__ __forceinline__ float b2f(ushort_t u) {
  unsigned int v = ((unsigned int)u) << 16;
  float f;
  __builtin_memcpy(&f, &v, 4);
  return f;
}
__device__ __forceinline__ ushort_t f2b(float f) {
  __hip_bfloat16 h = __float2bfloat16(f);
  ushort_t u;
  __builtin_memcpy(&u, &h, 2);
  return u;
}

// ---------------------------------------------------------------------------
// gemm_proj_split: split-K projection, NO atomics, software-pipelined:
// loads for step t+1 issued before MFMA of step t; vmcnt-wait + cvt + LDS
// write deferred to after the MFMA (double-buffered LDS, 1 barrier/iter).
// grid (NPV/64, 9): z -> (view, K-chunk). Partial f32 tiles to Ppart[z].
// ---------------------------------------------------------------------------
__global__ __launch_bounds__(256) void gemm_proj_split(
    const float* __restrict__ x0, const float* __restrict__ x1,
    const float* __restrict__ x2, const float* __restrict__ w0,
    const float* __restrict__ w1, const float* __restrict__ w2,
    float* __restrict__ Ppart) {
  __shared__ __align__(16) ushort_t As[2][64 * 64];
  __shared__ __align__(16) ushort_t Ws[2][128 * 64];
  const int z = blockIdx.y;
  const float* A;
  const float* W;
  int K, kstart, ksteps;
  if (z < 4)      { A = x0; W = w0; K = 2000; kstart = z * 512;       ksteps = 8; }
  else if (z < 7) { A = x1; W = w1; K = 1500; kstart = (z - 4) * 512; ksteps = 8; }
  else            { A = x2; W = w2; K = 500;  kstart = (z - 7) * 256; ksteps = 4; }
  const int tid = threadIdx.x;
  const int wave = tid >> 6, lane = tid & 63;
  const int m0 = blockIdx.x * 64;

  f32x4 acc[8];
#pragma unroll
  for (int n = 0; n < 8; ++n) acc[n] = (f32x4){0.f, 0.f, 0.f, 0.f};

  float4 ra[4];  // in-flight A tile (2 chunks x 32B)
  float4 rw[8];  // in-flight W tile (4 chunks x 32B)

  auto LOADR = [&](int k0) {
#pragma unroll
    for (int q = 0; q < 2; ++q) {
      int s = q * 256 + tid;
      int row = s >> 3, ch = s & 7;
      int gk = k0 + ((ch ^ (row & 7)) << 3);
      const float* gp = A + (long)(m0 + row) * K + gk;
      if (gk + 8 <= K) {
        ra[2 * q]     = *reinterpret_cast<const float4*>(gp);
        ra[2 * q + 1] = *reinterpret_cast<const float4*>(gp + 4);
      } else {
        float t[8];
#pragma unroll
        for (int j = 0; j < 8; ++j) t[j] = (gk + j < K) ? gp[j] : 0.f;
        ra[2 * q]     = make_float4(t[0], t[1], t[2], t[3]);
        ra[2 * q + 1] = make_float4(t[4], t[5], t[6], t[7]);
      }
    }
#pragma unroll
    for (int q = 0; q < 4; ++q) {
      int s = q * 256 + tid;
      int row = s >> 3, ch = s & 7;
      int gk = k0 + ((ch ^ (row & 7)) << 3);
      const float* gp = W + (long)row * K + gk;
      if (gk + 8 <= K) {
        rw[2 * q]     = *reinterpret_cast<const float4*>(gp);
        rw[2 * q + 1] = *reinterpret_cast<const float4*>(gp + 4);
      } else {
        float t[8];
#pragma unroll
        for (int j = 0; j < 8; ++j) t[j] = (gk + j < K) ? gp[j] : 0.f;
        rw[2 * q]     = make_float4(t[0], t[1], t[2], t[3]);
        rw[2 * q + 1] = make_float4(t[4], t[5], t[6], t[7]);
      }
    }
  };

  auto WRITELDS = [&](int buf) {
#pragma unroll
    for (int q = 0; q < 2; ++q) {
      int s = q * 256 + tid;
      short8 o;
      o[0] = (short)f2b(ra[2 * q].x); o[1] = (short)f2b(ra[2 * q].y);
      o[2] = (short)f2b(ra[2 * q].z); o[3] = (short)f2b(ra[2 * q].w);
      o[4] = (short)f2b(ra[2 * q + 1].x); o[5] = (short)f2b(ra[2 * q + 1].y);
      o[6] = (short)f2b(ra[2 * q + 1].z); o[7] = (short)f2b(ra[2 * q + 1].w);
      *reinterpret_cast<short8*>(As[buf] + s * 8) = o;
    }
#pragma unroll
    for (int q = 0; q < 4; ++q) {
      int s = q * 256 + tid;
      short8 o;
      o[0] = (short)f2b(rw[2 * q].x); o[1] = (short)f2b(rw[2 * q].y);
      o[2] = (short)f2b(rw[2 * q].z); o[3] = (short)f2b(rw[2 * q].w);
      o[4] = (short)f2b(rw[2 * q + 1].x); o[5] = (short)f2b(rw[2 * q + 1].y);
      o[6] = (short)f2b(rw[2 * q + 1].z); o[7] = (short)f2b(rw[2 * q + 1].w);
      *reinterpret_cast<short8*>(Ws[buf] + s * 8) = o;
    }
  };

  auto MFMA = [&](int buf) {
#pragma unroll
    for (int kk = 0; kk < 2; ++kk) {
      const int arow = wave * 16 + (lane & 15);
      const int ach = (kk * 4 + (lane >> 4)) ^ (arow & 7);
      short8 afrag = *reinterpret_cast<const short8*>(As[buf] + arow * 64 + ach * 8);
#pragma unroll
      for (int n = 0; n < 8; ++n) {
        const int brow = n * 16 + (lane & 15);
        const int bch = (kk * 4 + (lane >> 4)) ^ (brow & 7);
        short8 bfrag = *reinterpret_cast<const short8*>(Ws[buf] + brow * 64 + bch * 8);
        acc[n] = __builtin_amdgcn_mfma_f32_16x16x32_bf16(afrag, bfrag, acc[n], 0, 0, 0);
      }
    }
  };

  // prologue: fill buffer 0
  LOADR(kstart);
  WRITELDS(0);
  __syncthreads();
  int cur = 0;
  for (int step = 0; step < ksteps; ++step) {
    bool more = (step + 1 < ksteps);
    if (more) LOADR(kstart + ((step + 1) << 6));  // issue next-tile loads
    MFMA(cur);                                    // compute while loads fly
    if (more) {
      WRITELDS(cur ^ 1);                          // vmcnt wait + cvt + write
      __syncthreads();
    }
    cur ^= 1;
  }

  const int rbase = m0 + wave * 16 + (lane >> 4) * 4;
  const int cb = lane & 15;
  float* out = Ppart + (long)z * NPV * 128;
#pragma unroll
  for (int n = 0; n < 8; ++n) {
    int col = n * 16 + cb;
#pragma unroll
    for (int r = 0; r < 4; ++r)
      out[(long)(rbase + r) * 128 + col] = acc[n][r];
  }
}

// proj_reduce: xb[n, c] = bf16(relu(sum_z Ppart[z][m, c] + bias_v[c]))
__global__ __launch_bounds__(256) void proj_reduce(
    const float* __restrict__ Ppart, const float* __restrict__ b0,
    const float* __restrict__ b1, const float* __restrict__ b2,
    ushort_t* __restrict__ xb) {
  int t = blockIdx.x * blockDim.x + threadIdx.x;
  if (t >= N_NODES * 16) return;
  int n = t >> 4, c0 = (t & 15) * 8;
  int v = n >> 13, m = n & (NPV - 1);
  int zb, zc;
  const float* bias;
  if (v == 0) { zb = 0; zc = 4; bias = b0; }
  else if (v == 1) { zb = 4; zc = 3; bias = b1; }
  else { zb = 7; zc = 2; bias = b2; }
  float s[8];
#pragma unroll
  for (int j = 0; j < 8; ++j) s[j] = bias[c0 + j];
  for (int zz = 0; zz < zc; ++zz) {
    const float* p = Ppart + ((long)(zb + zz) * NPV + m) * 128 + c0;
    float4 a = *reinterpret_cast<const float4*>(p);
    float4 b = *reinterpret_cast<const float4*>(p + 4);
    s[0] += a.x; s[1] += a.y; s[2] += a.z; s[3] += a.w;
    s[4] += b.x; s[5] += b.y; s[6] += b.z; s[7] += b.w;
  }
  short8 o;
#pragma unroll
  for (int j = 0; j < 8; ++j) {
    float vv = s[j] > 0.f ? s[j] : 0.f;
    o[j] = (short)f2b(vv);
  }
  *reinterpret_cast<short8*>(xb + (long)n * 128 + c0) = o;
}

// ---------------------------------------------------------------------------
// xw GEMM: xwb[r][M,128] = bf16(xb[M,128] @ w_r[128,128]^T), plus fused
// attention tables ai/aj = (xb@w_r) @ q / @ k from the f32 accumulators.
// ---------------------------------------------------------------------------
template <bool SPLIT, bool TABLES>
__global__ __launch_bounds__(256) void mfma_gemm_nt(
    const ushort_t* __restrict__ A, const ushort_t* __restrict__ W,
    float* __restrict__ Cacc, ushort_t* __restrict__ Cb,
    int Kp, int kChunk, long strideW, long strideCz,
    const float* __restrict__ qt, const float* __restrict__ kt,
    float* __restrict__ ai, float* __restrict__ aj) {
  __shared__ __align__(16) ushort_t As[64 * 64];
  __shared__ __align__(16) ushort_t Ws[128 * 64];
  const int tid = threadIdx.x;
  const int wave = tid >> 6, lane = tid & 63;
  const int m0 = blockIdx.x * 64;
  const int kbase = blockIdx.y * kChunk;
  const ushort_t* Wz = W + (long)blockIdx.z * strideW;

  f32x4 acc[8];
#pragma unroll
  for (int n = 0; n < 8; ++n) acc[n] = (f32x4){0.f, 0.f, 0.f, 0.f};

  for (int k0 = kbase; k0 < kbase + kChunk; k0 += 64) {
    __syncthreads();
#pragma unroll
    for (int q = 0; q < 2; ++q) {
      int s = q * 256 + tid;
      int row = s >> 3, ch = s & 7;
      int sch = ch ^ (row & 7);
      const ushort_t* g = A + (long)(m0 + row) * Kp + k0 + sch * 8;
      __builtin_amdgcn_global_load_lds(
          (const __attribute__((address_space(1))) unsigned int*)g,
          (__attribute__((address_space(3))) unsigned int*)(As + s * 8), 16, 0, 0);
    }
#pragma unroll
    for (int q = 0; q < 4; ++q) {
      int s = q * 256 + tid;
      int row = s >> 3, ch = s & 7;
      int sch = ch ^ (row & 7);
      const ushort_t* g = Wz + (long)row * Kp + k0 + sch * 8;
      __builtin_amdgcn_global_load_lds(
          (const __attribute__((address_space(1))) unsigned int*)g,
          (__attribute__((address_space(3))) unsigned int*)(Ws + s * 8), 16, 0, 0);
    }
    __syncthreads();
#pragma unroll
    for (int kk = 0; kk < 2; ++kk) {
      const int arow = wave * 16 + (lane & 15);
      const int ach = (kk * 4 + (lane >> 4)) ^ (arow & 7);
      short8 afrag = *reinterpret_cast<const short8*>(As + arow * 64 + ach * 8);
#pragma unroll
      for (int n = 0; n < 8; ++n) {
        const int brow = n * 16 + (lane & 15);
        const int bch = (kk * 4 + (lane >> 4)) ^ (brow & 7);
        short8 bfrag = *reinterpret_cast<const short8*>(Ws + brow * 64 + bch * 8);
        acc[n] = __builtin_amdgcn_mfma_f32_16x16x32_bf16(afrag, bfrag, acc[n], 0, 0, 0);
      }
    }
  }
  const int rbase = m0 + wave * 16 + (lane >> 4) * 4;
  const int cb = lane & 15;
  if (SPLIT) {
#pragma unroll
    for (int n = 0; n < 8; ++n) {
      int col = n * 16 + cb;
#pragma unroll
      for (int r = 0; r < 4; ++r)
        atomicAdd(&Cacc[(long)(rbase + r) * 128 + col], acc[n][r]);
    }
  } else {
    ushort_t* Cz = Cb + (long)blockIdx.z * strideCz;
#pragma unroll
    for (int n = 0; n < 8; ++n) {
      int col = n * 16 + cb;
#pragma unroll
      for (int r = 0; r < 4; ++r)
        Cz[(long)(rbase + r) * 128 + col] = f2b(acc[n][r]);
    }
  }
  if (TABLES) {
    float aq[4][4], ak[4][4];
#pragma unroll
    for (int r = 0; r < 4; ++r)
#pragma unroll
      for (int h = 0; h < 4; ++h) { aq[r][h] = 0.f; ak[r][h] = 0.f; }
#pragma unroll
    for (int n = 0; n < 8; ++n) {
      int col = n * 16 + cb;
      float4 qv = *reinterpret_cast<const float4*>(qt + (long)col * 4);
      float4 kv = *reinterpret_cast<const float4*>(kt + (long)col * 4);
#pragma unroll
      for (int r = 0; r < 4; ++r) {
        float x = acc[n][r];
        aq[r][0] += x * qv.x; aq[r][1] += x * qv.y;
        aq[r][2] += x * qv.z; aq[r][3] += x * qv.w;
        ak[r][0] += x * kv.x; ak[r][1] += x * kv.y;
        ak[r][2] += x * kv.z; ak[r][3] += x * kv.w;
      }
    }
#pragma unroll
    for (int mk = 1; mk < 16; mk <<= 1) {
#pragma unroll
      for (int r = 0; r < 4; ++r)
#pragma unroll
        for (int h = 0; h < 4; ++h) {
          aq[r][h] += __shfl_xor(aq[r][h], mk);
          ak[r][h] += __shfl_xor(ak[r][h], mk);
        }
    }
    int rr = cb >> 2, hh = cb & 3;
    long row = (long)blockIdx.z * N_NODES + rbase + rr;
    ai[row * 4 + hh] = aq[rr][hh];
    aj[row * 4 + hh] = ak[rr][hh];
  }
}

// ---------------------------------------------------------------------------
__global__ void fill_f32(float* __restrict__ p, long n, float v) {
  long i = blockIdx.x * (long)blockDim.x + threadIdx.x;
  long stride = (long)gridDim.x * blockDim.x;
  for (; i < n; i += stride) p[i] = v;
}

// wTb[r,o,i] = bf16( sum_b comp[r,b] * basis[b,i,o] )
__global__ void compute_wT_b(const float* __restrict__ comp,
                             const float* __restrict__ basis,
                             ushort_t* __restrict__ wTb) {
  int idx = blockIdx.x * blockDim.x + threadIdx.x;
  if (idx >= R_REL * 128 * 128) return;
  int r = idx >> 14;
  int rem = idx & 16383;
  int o = rem >> 7;
  int i = rem & 127;
  float s = 0.f;
#pragma unroll
  for (int b = 0; b < B_BASES; ++b)
    s += comp[r * B_BASES + b] * basis[((b << 7) + i) * 128 + o];
  wTb[((long)(r << 7) + o) * 128 + i] = f2b(s);
}

// ---------------------------------------------------------------------------
// CSR build keyed by (dst*6 + rel): count -> hierarchical scan -> scatter.
// ---------------------------------------------------------------------------
__global__ void count_key(const int* __restrict__ dst, const int* __restrict__ et,
                          int* __restrict__ cnt, int E) {
  int e = blockIdx.x * blockDim.x + threadIdx.x;
  if (e < E) atomicAdd(&cnt[dst[e] * R_REL + et[e]], 1);
}

__global__ __launch_bounds__(256) void scan_block(const int* __restrict__ cnt,
                                                  int* __restrict__ start,
                                                  int* __restrict__ blockSums) {
  __shared__ int sm[256];
  const int t = threadIdx.x;
  const int i = blockIdx.x * 256 + t;
  int v = cnt[i];
  sm[t] = v;
  __syncthreads();
  for (int off = 1; off < 256; off <<= 1) {
    int u = (t >= off) ? sm[t - off] : 0;
    __syncthreads();
    sm[t] += u;
    __syncthreads();
  }
  start[i] = sm[t] - v;  // exclusive
  if (t == 255) blockSums[blockIdx.x] = sm[255];
}

__global__ __launch_bounds__(SCAN_BLOCKS) void scan_sums(int* __restrict__ blockSums) {
  __shared__ int sm[SCAN_BLOCKS];
  const int t = threadIdx.x;
  int v = blockSums[t];
  sm[t] = v;
  __syncthreads();
  for (int off = 1; off < SCAN_BLOCKS; off <<= 1) {
    int u = (t >= off) ? sm[t - off] : 0;
    __syncthreads();
    sm[t] += u;
    __syncthreads();
  }
  blockSums[t] = sm[t] - v;  // exclusive
}

__global__ __launch_bounds__(256) void add_offsets(int* __restrict__ start,
                                                   const int* __restrict__ blockSums) {
  int i = blockIdx.x * 256 + threadIdx.x;
  start[i] += blockSums[blockIdx.x];
  if (i == 0) start[NK] = E_EDGES;
}

__global__ void scatter_edges(const int* __restrict__ src, const int* __restrict__ dst,
                              const int* __restrict__ et, const int* __restrict__ start,
                              int* __restrict__ cursor, int* __restrict__ recs, int E) {
  int e = blockIdx.x * blockDim.x + threadIdx.x;
  if (e >= E) return;
  int key = dst[e] * R_REL + et[e];
  int pos = start[key] + atomicAdd(&cursor[key], 1);
  recs[pos] = src[e] | (et[e] << 16);
}

// ---------------------------------------------------------------------------
// seg_softmax: one thread per (dst,rel) segment -> per-edge coef[h*E + pos].
// ---------------------------------------------------------------------------
__global__ __launch_bounds__(256) void seg_softmax(
    const int* __restrict__ rstart, const int* __restrict__ recs,
    const float* __restrict__ ai, const float* __restrict__ aj,
    float* __restrict__ coef) {
  int seg = blockIdx.x * blockDim.x + threadIdx.x;
  if (seg >= NK) return;
  int p0 = rstart[seg], p1 = rstart[seg + 1];
  if (p0 == p1) return;
  int d = seg / R_REL, r = seg - d * R_REL;
  float4 av = *reinterpret_cast<const float4*>(ai + ((long)r * N_NODES + d) * 4);
  float degf = (float)(rstart[(d + 1) * R_REL] - rstart[d * R_REL]);
  float m[4] = {-INFINITY, -INFINITY, -INFINITY, -INFINITY};
  float sum[4] = {0.f, 0.f, 0.f, 0.f};
  for (int p = p0; p < p1; ++p) {
    int s = recs[p] & 0xFFFF;
    float4 bv = *reinterpret_cast<const float4*>(aj + ((long)r * N_NODES + s) * 4);
    float al[4] = {lrelu(av.x + bv.x), lrelu(av.y + bv.y),
                   lrelu(av.z + bv.z), lrelu(av.w + bv.w)};
#pragma unroll
    for (int h = 0; h < 4; ++h) {
      float nm = fmaxf(m[h], al[h]);
      sum[h] = sum[h] * __expf(m[h] - nm) + __expf(al[h] - nm);
      m[h] = nm;
    }
  }
  float rs[4];
#pragma unroll
  for (int h = 0; h < 4; ++h) rs[h] = degf / (sum[h] + 1e-16f);
  for (int p = p0; p < p1; ++p) {
    int s = recs[p] & 0xFFFF;
    float4 bv = *reinterpret_cast<const float4*>(aj + ((long)r * N_NODES + s) * 4);
    float al[4] = {lrelu(av.x + bv.x), lrelu(av.y + bv.y),
                   lrelu(av.z + bv.z), lrelu(av.w + bv.w)};
#pragma unroll
    for (int h = 0; h < 4; ++h)
      coef[(long)h * E_EDGES + p] = __expf(al[h] - m[h]) * rs[h];
  }
}

// ---------------------------------------------------------------------------
// fused_agg: one wave per dst node; pure gather-accumulate over xwb.
// ---------------------------------------------------------------------------
__global__ __launch_bounds__(256) void fused_agg(
    const int* __restrict__ rstart, const int* __restrict__ recs,
    const float* __restrict__ coef, const ushort_t* __restrict__ xwb,
    ushort_t* __restrict__ xb_out, float* __restrict__ fout) {
  const int wave = threadIdx.x >> 6, lane = threadIdx.x & 63;
  const int d = blockIdx.x * 4 + wave;
  const int s0 = rstart[d * R_REL], s1 = rstart[(d + 1) * R_REL];
  const float* cfp = coef + (long)(lane >> 4) * E_EDGES;
  float acc0 = 0.f, acc1 = 0.f;
#pragma unroll 4
  for (int pos = s0; pos < s1; ++pos) {
    int rec = recs[pos];
    float cf = cfp[pos];
    int s = rec & 0xFFFF, r = rec >> 16;
    unsigned int pk = *reinterpret_cast<const unsigned int*>(
        xwb + (((long)r * N_NODES + s) << 7) + 2 * lane);
    acc0 += cf * b2f((ushort_t)(pk & 0xFFFF));
    acc1 += cf * b2f((ushort_t)(pk >> 16));
  }
  if (xb_out) {
    unsigned int po = ((unsigned int)f2b(acc1) << 16) | (unsigned int)f2b(acc0);
    *reinterpret_cast<unsigned int*>(xb_out + ((long)d << 7) + 2 * lane) = po;
  }
  if (fout) {
    *reinterpret_cast<float2*>(fout + ((long)d << 7) + 2 * lane) =
        make_float2(acc0, acc1);
  }
}

__global__ void final_linear(const float* __restrict__ x, const float* __restrict__ Wc,
                             const float* __restrict__ bc, float* __restrict__ out) {
  __shared__ float wcs[4 * 384];
  for (int t = threadIdx.x; t < 4 * 384; t += blockDim.x) wcs[t] = Wc[t];
  __syncthreads();
  int i = blockIdx.x * blockDim.x + threadIdx.x;
  if (i >= NPV) return;
  float acc[4] = {0.f, 0.f, 0.f, 0.f};
  for (int v = 0; v < 3; ++v) {
    const float* xr = x + ((long)v * NPV + i) * 128;
    for (int c = 0; c < 128; c += 4) {
      float4 xv = *reinterpret_cast<const float4*>(xr + c);
#pragma unroll
      for (int l = 0; l < 4; ++l) {
        const float* w = wcs + l * 384 + v * 128 + c;
        acc[l] += xv.x * w[0] + xv.y * w[1] + xv.z * w[2] + xv.w * w[3];
      }
    }
  }
#pragma unroll
  for (int l = 0; l < 4; ++l) out[(long)i * 4 + l] = acc[l] + bc[l];
}

// ---------------------------------------------------------------------------
static void run_layer(const ushort_t* xb_in, ushort_t* xb_out, float* fout,
                      const float* basis, const float* comp, const float* q,
                      const float* k, ushort_t* xwb, ushort_t* wTb, float* ai,
                      float* aj, float* coef, const int* rstart, const int* recs,
                      hipStream_t stream) {
  compute_wT_b<<<(R_REL * 128 * 128 + 255) / 256, 256, 0, stream>>>(comp, basis, wTb);
  mfma_gemm_nt<false, true><<<dim3(N_NODES / 64, 1, R_REL), 256, 0, stream>>>(
      xb_in, wTb, nullptr, xwb, 128, 128, 128 * 128, (long)N_NODES * 128,
      q, k, ai, aj);
  seg_softmax<<<(NK + 255) / 256, 256, 0, stream>>>(rstart, recs, ai, aj, coef);
  fused_agg<<<N_NODES / 4, 256, 0, stream>>>(rstart, recs, coef, xwb, xb_out, fout);
}

extern "C" void kernel_launch(void* const* d_in, const int* in_sizes, int n_in,
                              void* d_out, int out_size, void* d_ws, size_t ws_size,
                              hipStream_t stream) {
  const float* x0 = (const float*)d_in[0];
  const float* x1 = (const float*)d_in[1];
  const float* x2 = (const float*)d_in[2];
  const int* edge_index = (const int*)d_in[3];
  const int* edge_type = (const int*)d_in[4];
  const float* Wp0 = (const float*)d_in[5];
  const float* bp0 = (const float*)d_in[6];
  const float* Wp1 = (const float*)d_in[7];
  const float* bp1 = (const float*)d_in[8];
  const float* Wp2 = (const float*)d_in[9];
  const float* bp2 = (const float*)d_in[10];
  const float* basis0 = (const float*)d_in[11];
  const float* comp0 = (const float*)d_in[12];
  const float* q0 = (const float*)d_in[13];
  const float* k0 = (const float*)d_in[14];
  const float* basis1 = (const float*)d_in[15];
  const float* comp1 = (const float*)d_in[16];
  const float* q1 = (const float*)d_in[17];
  const float* k1 = (const float*)d_in[18];
  const float* Wc = (const float*)d_in[19];
  const float* bc = (const float*)d_in[20];

  const int* src = edge_index;
  const int* dst = edge_index + E_EDGES;

  // ---- workspace layout ----
  char* w = (char*)d_ws;
  auto alloc = [&](long bytes) {
    char* p = w;
    w += (bytes + 255) & ~255L;
    return p;
  };
  ushort_t* xbA  = (ushort_t*)alloc((long)NX * 2);
  ushort_t* xbB  = (ushort_t*)alloc((long)NX * 2);
  ushort_t* xwb  = (ushort_t*)alloc(9L * NPV * 128 * 4);  // aliased: Ppart (f32) then xwb (bf16)
  ushort_t* wTb  = (ushort_t*)alloc((long)R_REL * 128 * 128 * 2);
  float* Cacc    = (float*)alloc((long)NX * 4);
  float* ai      = (float*)alloc((long)R_REL * N_NODES * 4 * 4);
  float* aj      = (float*)alloc((long)R_REL * N_NODES * 4 * 4);
  float* coef    = (float*)alloc((long)HEADS * E_EDGES * 4);
  int* cnt       = (int*)alloc((long)NK * 4);
  int* cursor    = (int*)alloc((long)NK * 4);
  int* rstart    = (int*)alloc((long)(NK + 1) * 4);
  int* recs      = (int*)alloc((long)E_EDGES * 4);
  int* blockSums = (int*)alloc((long)SCAN_BLOCKS * 4);
  float* Ppart   = (float*)xwb;  // alias: projection partials die before xwb is written

  // ---- projections: pipelined split-K (no atomics) -> partials -> reduce
  gemm_proj_split<<<dim3(NPV / 64, 9), 256, 0, stream>>>(
      x0, x1, x2, Wp0, Wp1, Wp2, Ppart);
  proj_reduce<<<(N_NODES * 16 + 255) / 256, 256, 0, stream>>>(
      Ppart, bp0, bp1, bp2, xbA);

  // ---- CSR build keyed by (dst,rel) (once; shared by both layers)
  fill_f32<<<96, 256, 0, stream>>>((float*)cnt, 2L * NK, 0.f);  // cnt+cursor adjacent
  count_key<<<E_EDGES / 256, 256, 0, stream>>>(dst, edge_type, cnt, E_EDGES);
  scan_block<<<SCAN_BLOCKS, 256, 0, stream>>>(cnt, rstart, blockSums);
  scan_sums<<<1, SCAN_BLOCKS, 0, stream>>>(blockSums);
  add_offsets<<<SCAN_BLOCKS, 256, 0, stream>>>(rstart, blockSums);
  scatter_edges<<<E_EDGES / 256, 256, 0, stream>>>(src, dst, edge_type, rstart,
                                                   cursor, recs, E_EDGES);

  // ---- layer 0: xbA -> xbB (bf16)
  run_layer(xbA, xbB, nullptr, basis0, comp0, q0, k0, xwb, wTb, ai, aj, coef,
            rstart, recs, stream);
  // ---- layer 1: xbB -> Cacc (f32 only)
  run_layer(xbB, nullptr, Cacc, basis1, comp1, q1, k1, xwb, wTb, ai, aj, coef,
            rstart, recs, stream);

  final_linear<<<(NPV + 255) / 256, 256, 0, stream>>>(Cacc, Wc, bc, (float*)d_out);
}